// Round 1
// baseline (4718.587 us; speedup 1.0000x reference)
//
#include <hip/hip_runtime.h>
#include <hip/hip_bf16.h>

// ---------------------------------------------------------------------------
// CLUTRR transformer: B=64 S=512 H=256 L=4 NH=8 DH=32 F=1024 V=50265 K=8 R=25
// Round 0: correct fp32 baseline. GEMMs: 64x64 LDS tiles, 4x4 reg blocking.
// Attention: flash-style online softmax, 64-query tiles per (b,h).
// ---------------------------------------------------------------------------

#define S_LEN 512
#define H_DIM 256
#define NHEAD 8
#define DHEAD 32
#define FFN   1024
#define NTOK  (64 * 512)   // B*S = 32768

// ---------------- embedding gather ----------------
__global__ __launch_bounds__(256) void embed_kernel(
    const int* __restrict__ ids, const float* __restrict__ emb,
    float* __restrict__ X) {
  size_t i4 = (size_t)blockIdx.x * 256 + threadIdx.x;   // float4 index
  int tok = (int)(i4 >> 6);                             // 64 float4 per row
  int d4  = (int)(i4 & 63);
  const float4* src = (const float4*)&emb[(size_t)ids[tok] * H_DIM + d4 * 4];
  *(float4*)&X[i4 * 4] = *src;
}

// ---------------- fp32 tiled GEMM: C = A[M,K] @ W[K,N] + bias ----------------
template<bool RELU>
__global__ __launch_bounds__(256) void sgemm_kernel(
    const float* __restrict__ A, const float* __restrict__ W,
    const float* __restrict__ bias, float* __restrict__ C,
    int M, int N, int K) {
  __shared__ float As[16][68];   // [k][m], pad 68 -> 2-way conflicts only
  __shared__ float Bs[16][68];   // [k][n]
  const int tid = threadIdx.x;
  const int tx = tid & 15, ty = tid >> 4;
  const int m0 = blockIdx.y * 64, n0 = blockIdx.x * 64;
  const int la_k = tid & 15, la_m = tid >> 4;   // A loader
  const int lb_n = tid & 63, lb_k = tid >> 6;   // B loader
  float acc[4][4] = {};
  for (int k0 = 0; k0 < K; k0 += 16) {
#pragma unroll
    for (int e = 0; e < 4; ++e) {
      As[la_k][la_m + e * 16] =
          A[(size_t)(m0 + la_m + e * 16) * K + k0 + la_k];
      Bs[lb_k + e * 4][lb_n] =
          W[(size_t)(k0 + lb_k + e * 4) * N + n0 + lb_n];
    }
    __syncthreads();
#pragma unroll
    for (int k = 0; k < 16; ++k) {
      float4 av = *(const float4*)&As[k][ty * 4];
      float4 bv = *(const float4*)&Bs[k][tx * 4];
      float a4[4] = {av.x, av.y, av.z, av.w};
      float b4[4] = {bv.x, bv.y, bv.z, bv.w};
#pragma unroll
      for (int i = 0; i < 4; ++i)
#pragma unroll
        for (int j = 0; j < 4; ++j)
          acc[i][j] += a4[i] * b4[j];
    }
    __syncthreads();
  }
  const float4 bb = *(const float4*)&bias[n0 + tx * 4];
  const float bias4[4] = {bb.x, bb.y, bb.z, bb.w};
#pragma unroll
  for (int i = 0; i < 4; ++i) {
    float4 vo;
    vo.x = acc[i][0] + bias4[0];
    vo.y = acc[i][1] + bias4[1];
    vo.z = acc[i][2] + bias4[2];
    vo.w = acc[i][3] + bias4[3];
    if (RELU) {
      vo.x = fmaxf(vo.x, 0.f); vo.y = fmaxf(vo.y, 0.f);
      vo.z = fmaxf(vo.z, 0.f); vo.w = fmaxf(vo.w, 0.f);
    }
    *(float4*)&C[(size_t)(m0 + ty * 4 + i) * N + n0 + tx * 4] = vo;
  }
}

// ---------------- flash attention (fp32), 64-query tile per block ----------
// QKV layout: [b, s, 768] with Q at +0, K at +256, V at +512; head h at h*32.
// O layout: [b, s, 256] head-merged.
__global__ __launch_bounds__(256) void attn_kernel(
    const float* __restrict__ QKV, const int* __restrict__ amask,
    float* __restrict__ O) {
  const int b = blockIdx.z, h = blockIdx.y;
  const int q0 = blockIdx.x * 64;
  const int tid = threadIdx.x;
  const int tx = tid & 15, ty = tid >> 4;
  __shared__ float Qs[32][68];   // d-major [d][q]
  __shared__ float Ks[32][68];   // d-major [d][k]
  __shared__ float Vs[64][34];   // [k][d]
  __shared__ float Ps[64][68];   // [q][k]
  __shared__ float mb_s[64];
  const size_t base = (size_t)b * S_LEN * 768 + (size_t)h * DHEAD;

  for (int idx = tid; idx < 2048; idx += 256) {
    int s = idx >> 5, d = idx & 31;
    Qs[d][s] = QKV[base + (size_t)(q0 + s) * 768 + d];
  }
  float accO[4][2] = {{0, 0}, {0, 0}, {0, 0}, {0, 0}};
  float mrun[4] = {-1e30f, -1e30f, -1e30f, -1e30f};
  float lrun[4] = {0.f, 0.f, 0.f, 0.f};
  const float scale = 0.17677669529663687f;   // 1/sqrt(32)

  for (int k0 = 0; k0 < S_LEN; k0 += 64) {
    for (int idx = tid; idx < 2048; idx += 256) {
      int s = idx >> 5, d = idx & 31;
      Ks[d][s] = QKV[base + 256 + (size_t)(k0 + s) * 768 + d];
      Vs[s][d] = QKV[base + 512 + (size_t)(k0 + s) * 768 + d];
    }
    if (tid < 64) mb_s[tid] = (amask[b * S_LEN + k0 + tid] != 0) ? 0.f : -1e9f;
    __syncthreads();

    float s4[4][4] = {};
#pragma unroll
    for (int d = 0; d < 32; ++d) {
      float4 qv = *(const float4*)&Qs[d][ty * 4];
      float4 kv = *(const float4*)&Ks[d][tx * 4];
      float qa[4] = {qv.x, qv.y, qv.z, qv.w};
      float kb[4] = {kv.x, kv.y, kv.z, kv.w};
#pragma unroll
      for (int i = 0; i < 4; ++i)
#pragma unroll
        for (int j = 0; j < 4; ++j)
          s4[i][j] += qa[i] * kb[j];
    }
    const float mreg[4] = {mb_s[tx * 4], mb_s[tx * 4 + 1],
                           mb_s[tx * 4 + 2], mb_s[tx * 4 + 3]};
#pragma unroll
    for (int i = 0; i < 4; ++i) {
      float mx = -1e30f;
#pragma unroll
      for (int j = 0; j < 4; ++j) {
        s4[i][j] = s4[i][j] * scale + mreg[j];
        mx = fmaxf(mx, s4[i][j]);
      }
      mx = fmaxf(mx, __shfl_xor(mx, 1));
      mx = fmaxf(mx, __shfl_xor(mx, 2));
      mx = fmaxf(mx, __shfl_xor(mx, 4));
      mx = fmaxf(mx, __shfl_xor(mx, 8));
      float mnew = fmaxf(mrun[i], mx);
      float corr = __expf(mrun[i] - mnew);
      float ps = 0.f;
#pragma unroll
      for (int j = 0; j < 4; ++j) {
        float p = __expf(s4[i][j] - mnew);
        s4[i][j] = p;
        ps += p;
      }
      ps += __shfl_xor(ps, 1);
      ps += __shfl_xor(ps, 2);
      ps += __shfl_xor(ps, 4);
      ps += __shfl_xor(ps, 8);
      lrun[i] = lrun[i] * corr + ps;
      mrun[i] = mnew;
      accO[i][0] *= corr;
      accO[i][1] *= corr;
      *(float4*)&Ps[ty * 4 + i][tx * 4] =
          make_float4(s4[i][0], s4[i][1], s4[i][2], s4[i][3]);
    }
    __syncthreads();
    for (int k = 0; k < 64; ++k) {
      float2 vv = *(const float2*)&Vs[k][tx * 2];
#pragma unroll
      for (int i = 0; i < 4; ++i) {
        float p = Ps[ty * 4 + i][k];
        accO[i][0] += p * vv.x;
        accO[i][1] += p * vv.y;
      }
    }
    __syncthreads();
  }
#pragma unroll
  for (int i = 0; i < 4; ++i) {
    float inv = 1.f / lrun[i];
    int q = q0 + ty * 4 + i;
    float2 ov;
    ov.x = accO[i][0] * inv;
    ov.y = accO[i][1] * inv;
    *(float2*)&O[((size_t)b * S_LEN + q) * H_DIM + h * DHEAD + tx * 2] = ov;
  }
}

// ---------------- residual + layernorm (in place on X) ----------------
template<bool HAS_RES>
__global__ __launch_bounds__(256) void ln_kernel(
    float* __restrict__ X, const float* __restrict__ Y,
    const float* __restrict__ g, const float* __restrict__ bt) {
  const int i = blockIdx.x, t = threadIdx.x;
  const size_t idx = (size_t)i * H_DIM + t;
  float v = X[idx];
  if (HAS_RES) v += Y[idx];
  __shared__ float red[8];
  float s = v;
#pragma unroll
  for (int off = 32; off >= 1; off >>= 1) s += __shfl_down(s, off);
  if ((t & 63) == 0) red[t >> 6] = s;
  __syncthreads();
  float mu = (red[0] + red[1] + red[2] + red[3]) * (1.0f / 256.0f);
  float d = v - mu;
  float sq = d * d;
#pragma unroll
  for (int off = 32; off >= 1; off >>= 1) sq += __shfl_down(sq, off);
  if ((t & 63) == 0) red[4 + (t >> 6)] = sq;
  __syncthreads();
  float var = (red[4] + red[5] + red[6] + red[7]) * (1.0f / 256.0f);
  X[idx] = d * rsqrtf(var + 1e-5f) * g[t] + bt[t];
}

// ---------------- pooling: sub/obj gather-mean + story masked-mean ---------
__global__ __launch_bounds__(256) void pool_kernel(
    const float* __restrict__ X, const int* __restrict__ amask,
    const int* __restrict__ sub_idx, const int* __restrict__ sub_cnt,
    const int* __restrict__ obj_idx, const int* __restrict__ obj_cnt,
    float* __restrict__ feat) {
  const int b = blockIdx.x, t = threadIdx.x;
  const float* xb = X + (size_t)b * S_LEN * H_DIM;
  // sub
  {
    float s = 0.f;
    int c = sub_cnt[b];
    for (int j = 0; j < c; ++j) s += xb[(size_t)sub_idx[b * 8 + j] * H_DIM + t];
    feat[(size_t)b * 768 + t] = (c > 0) ? s / (float)c : 0.f;
  }
  // obj
  {
    float s = 0.f;
    int c = obj_cnt[b];
    for (int j = 0; j < c; ++j) s += xb[(size_t)obj_idx[b * 8 + j] * H_DIM + t];
    feat[(size_t)b * 768 + 256 + t] = (c > 0) ? s / (float)c : 0.f;
  }
  // story (lengths >= 16, so always > 0)
  {
    float s = 0.f, len = 0.f;
    for (int k = 0; k < S_LEN; ++k) {
      if (amask[b * S_LEN + k]) {
        s += xb[(size_t)k * H_DIM + t];
        len += 1.f;
      }
    }
    feat[(size_t)b * 768 + 512 + t] = s / len;
  }
}

// ---------------- classifier: relu(feat@mW1+mb1)@mW2+mb2 ----------------
__global__ __launch_bounds__(256) void cls_kernel(
    const float* __restrict__ feat, const float* __restrict__ mW1,
    const float* __restrict__ mb1, const float* __restrict__ mW2,
    const float* __restrict__ mb2, float* __restrict__ out) {
  const int b = blockIdx.x, t = threadIdx.x;
  __shared__ float fs[768];
  __shared__ float hid[256];
#pragma unroll
  for (int e = 0; e < 3; ++e) fs[t + e * 256] = feat[(size_t)b * 768 + t + e * 256];
  __syncthreads();
  float acc = mb1[t];
  for (int k = 0; k < 768; ++k) acc += fs[k] * mW1[(size_t)k * 256 + t];
  hid[t] = fmaxf(acc, 0.f);
  __syncthreads();
  if (t < 25) {
    float o = mb2[t];
    for (int j = 0; j < 256; ++j) o += hid[j] * mW2[j * 25 + t];
    out[b * 25 + t] = o;
  }
}

// ---------------------------------------------------------------------------
extern "C" void kernel_launch(void* const* d_in, const int* in_sizes, int n_in,
                              void* d_out, int out_size, void* d_ws, size_t ws_size,
                              hipStream_t stream) {
  const int*   input_ids = (const int*)d_in[0];
  const int*   amask     = (const int*)d_in[1];
  const int*   sub_idx   = (const int*)d_in[2];
  const int*   sub_cnt   = (const int*)d_in[3];
  const int*   obj_idx   = (const int*)d_in[4];
  const int*   obj_cnt   = (const int*)d_in[5];
  const float* emb  = (const float*)d_in[6];
  const float* Wqkv = (const float*)d_in[7];
  const float* bqkv = (const float*)d_in[8];
  const float* Wo   = (const float*)d_in[9];
  const float* bo   = (const float*)d_in[10];
  const float* ln1g = (const float*)d_in[11];
  const float* ln1b = (const float*)d_in[12];
  const float* ln2g = (const float*)d_in[13];
  const float* ln2b = (const float*)d_in[14];
  const float* W1   = (const float*)d_in[15];
  const float* b1   = (const float*)d_in[16];
  const float* W2   = (const float*)d_in[17];
  const float* b2   = (const float*)d_in[18];
  const float* lnfg = (const float*)d_in[19];
  const float* lnfb = (const float*)d_in[20];
  const float* mW1  = (const float*)d_in[21];
  const float* mb1  = (const float*)d_in[22];
  const float* mW2  = (const float*)d_in[23];
  const float* mb2  = (const float*)d_in[24];
  float* out = (float*)d_out;

  float* ws = (float*)d_ws;
  float* X    = ws;                          // 8.39M floats
  float* QKV  = X + (size_t)NTOK * 256;      // 25.17M floats
  float* O    = QKV + (size_t)NTOK * 768;    // 8.39M floats
  float* Y    = O + (size_t)NTOK * 256;      // 8.39M floats
  float* Hid  = QKV;                         // aliases [QKV,O] = 33.55M floats
  float* feat = Y + (size_t)NTOK * 256;      // 49152 floats

  // embedding
  embed_kernel<<<NTOK * 64 / 256, 256, 0, stream>>>(input_ids, emb, X);

  for (int l = 0; l < 4; ++l) {
    const float* Wqkv_l = Wqkv + (size_t)l * 256 * 768;
    const float* bqkv_l = bqkv + (size_t)l * 768;
    const float* Wo_l   = Wo + (size_t)l * 256 * 256;
    const float* bo_l   = bo + (size_t)l * 256;
    const float* W1_l   = W1 + (size_t)l * 256 * 1024;
    const float* b1_l   = b1 + (size_t)l * 1024;
    const float* W2_l   = W2 + (size_t)l * 1024 * 256;
    const float* b2_l   = b2 + (size_t)l * 256;

    sgemm_kernel<false><<<dim3(12, 512), 256, 0, stream>>>(
        X, Wqkv_l, bqkv_l, QKV, NTOK, 768, 256);
    attn_kernel<<<dim3(8, 8, 64), 256, 0, stream>>>(QKV, amask, O);
    sgemm_kernel<false><<<dim3(4, 512), 256, 0, stream>>>(
        O, Wo_l, bo_l, Y, NTOK, 256, 256);
    ln_kernel<true><<<NTOK, 256, 0, stream>>>(X, Y, ln1g + l * 256, ln1b + l * 256);
    sgemm_kernel<true><<<dim3(16, 512), 256, 0, stream>>>(
        X, W1_l, b1_l, Hid, NTOK, 1024, 256);
    sgemm_kernel<false><<<dim3(4, 512), 256, 0, stream>>>(
        Hid, W2_l, b2_l, Y, NTOK, 256, 1024);
    ln_kernel<true><<<NTOK, 256, 0, stream>>>(X, Y, ln2g + l * 256, ln2b + l * 256);
  }
  ln_kernel<false><<<NTOK, 256, 0, stream>>>(X, nullptr, lnfg, lnfb);
  pool_kernel<<<64, 256, 0, stream>>>(X, amask, sub_idx, sub_cnt,
                                      obj_idx, obj_cnt, feat);
  cls_kernel<<<64, 256, 0, stream>>>(feat, mW1, mb1, mW2, mb2, out);
}

// Round 2
// 1239.738 us; speedup vs baseline: 3.8061x; 3.8061x over previous
//
#include <hip/hip_runtime.h>
#include <hip/hip_bf16.h>

// ---------------------------------------------------------------------------
// CLUTRR transformer: B=64 S=512 H=256 L=4 NH=8 DH=32 F=1024 V=50265 K=8 R=25
// Round 2: bf16 MFMA GEMMs (m97-style 128x128xBK32, global_load_lds) +
// bf16 MFMA flash attention (swizzled V via pre-swizzled global layout).
// fp32 residual/LN path preserved for accuracy.
// ---------------------------------------------------------------------------

typedef __hip_bfloat16 bf16;
typedef __attribute__((ext_vector_type(8))) short short8;
typedef __attribute__((ext_vector_type(4))) float f32x4;

#define S_LEN 512
#define H_DIM 256
#define NTOK  32768      // B*S

__device__ __forceinline__ void gload_lds16(const void* g, void* l) {
  __builtin_amdgcn_global_load_lds(
      (const __attribute__((address_space(1))) unsigned int*)g,
      (__attribute__((address_space(3))) unsigned int*)l, 16, 0, 0);
}

__device__ __forceinline__ unsigned short f2bu(float x) {
  bf16 t = __float2bfloat16(x);
  return *reinterpret_cast<unsigned short*>(&t);
}

// ---------------- weight cast + transpose: out[N][K] = bf16(in[K][N]) -------
__global__ __launch_bounds__(256) void tcast_kernel(
    const float* __restrict__ in, bf16* __restrict__ out, int K, int N) {
  const int l = blockIdx.z;
  in  += (size_t)l * K * N;
  out += (size_t)l * K * N;
  __shared__ float t[32][33];
  const int n0 = blockIdx.x * 32, k0 = blockIdx.y * 32;
  const int c = threadIdx.x & 31, r = threadIdx.x >> 5;
#pragma unroll
  for (int rr = r; rr < 32; rr += 8)
    t[rr][c] = in[(size_t)(k0 + rr) * N + n0 + c];
  __syncthreads();
#pragma unroll
  for (int rr = r; rr < 32; rr += 8)
    out[(size_t)(n0 + rr) * K + k0 + c] = __float2bfloat16(t[c][rr]);
}

// ---------------- embedding gather: X fp32 + Xb bf16 ----------------
__global__ __launch_bounds__(256) void embed_kernel(
    const int* __restrict__ ids, const float* __restrict__ emb,
    float* __restrict__ X, bf16* __restrict__ Xb) {
  size_t i4 = (size_t)blockIdx.x * 256 + threadIdx.x;   // float4 index
  int tok = (int)(i4 >> 6);
  int d4  = (int)(i4 & 63);
  float4 v = *(const float4*)&emb[(size_t)ids[tok] * H_DIM + d4 * 4];
  *(float4*)&X[i4 * 4] = v;
  ushort4 pk;
  pk.x = f2bu(v.x); pk.y = f2bu(v.y); pk.z = f2bu(v.z); pk.w = f2bu(v.w);
  *(ushort4*)&Xb[i4 * 4] = pk;
}

// ---------------- bf16 MFMA GEMM: C = A[M,K] @ Bt[N,K]^T + bias -------------
// MODE 0: fp32 out Cf; MODE 1: bf16 out Cb (w/ optional relu);
// MODE 2: QKV split — n<512 -> Cb[m][768], n>=512 -> Vt[b,h,d,s^swz] bf16.
template<int MODE, bool RELU>
__global__ __launch_bounds__(256) void hgemm_kernel(
    const bf16* __restrict__ A, const bf16* __restrict__ Bt,
    const float* __restrict__ bias, float* __restrict__ Cf,
    bf16* __restrict__ Cb, bf16* __restrict__ Vt,
    int M, int N, int K) {
  __shared__ __align__(16) bf16 As[4096];   // [128][32]
  __shared__ __align__(16) bf16 Bs[4096];   // [128][32]
  const int tid = threadIdx.x;
  const int wv = tid >> 6, ln = tid & 63;
  const int fr = ln & 15, g4 = ln >> 4;
  const int wr = wv >> 1, wc = wv & 1;
  const int m0 = blockIdx.y * 128, n0 = blockIdx.x * 128;
  const int lr = tid >> 2, lk = (tid & 3) * 8;   // staging row / k-offset

  f32x4 acc[4][4];
#pragma unroll
  for (int i = 0; i < 4; ++i)
#pragma unroll
    for (int j = 0; j < 4; ++j)
      acc[i][j] = (f32x4){0.f, 0.f, 0.f, 0.f};

  for (int k0 = 0; k0 < K; k0 += 32) {
    gload_lds16(A  + (size_t)(m0 + lr) * K + k0 + lk,       &As[wv * 512]);
    gload_lds16(A  + (size_t)(m0 + 64 + lr) * K + k0 + lk,  &As[2048 + wv * 512]);
    gload_lds16(Bt + (size_t)(n0 + lr) * K + k0 + lk,       &Bs[wv * 512]);
    gload_lds16(Bt + (size_t)(n0 + 64 + lr) * K + k0 + lk,  &Bs[2048 + wv * 512]);
    __syncthreads();
    short8 af[4], bfv[4];
#pragma unroll
    for (int i = 0; i < 4; ++i)
      af[i] = *(const short8*)&As[(wr * 64 + i * 16 + fr) * 32 + g4 * 8];
#pragma unroll
    for (int j = 0; j < 4; ++j)
      bfv[j] = *(const short8*)&Bs[(wc * 64 + j * 16 + fr) * 32 + g4 * 8];
#pragma unroll
    for (int i = 0; i < 4; ++i)
#pragma unroll
      for (int j = 0; j < 4; ++j)
        acc[i][j] = __builtin_amdgcn_mfma_f32_16x16x32_bf16(
            af[i], bfv[j], acc[i][j], 0, 0, 0);
    __syncthreads();
  }

  const int crow = g4 * 4, ccol = fr;
#pragma unroll
  for (int j = 0; j < 4; ++j) {
    const int n = n0 + wc * 64 + j * 16 + ccol;
    const float bv = bias[n];
#pragma unroll
    for (int i = 0; i < 4; ++i) {
      const int mbase = m0 + wr * 64 + i * 16 + crow;
#pragma unroll
      for (int r = 0; r < 4; ++r) {
        float o = acc[i][j][r] + bv;
        if (RELU) o = fmaxf(o, 0.f);
        const int m = mbase + r;
        if (MODE == 0) {
          Cf[(size_t)m * N + n] = o;
        } else if (MODE == 1) {
          Cb[(size_t)m * N + n] = __float2bfloat16(o);
        } else {
          if (n < 512) {
            Cb[(size_t)m * 768 + n] = __float2bfloat16(o);
          } else {
            const int hd = n - 512, hh = hd >> 5, dd = hd & 31;
            const int bb = m >> 9, ss = m & 511;
            const int ssw = (ss & ~63) | ((ss & 63) ^ ((dd & 7) << 3));
            Vt[(((size_t)bb * 8 + hh) * 32 + dd) * 512 + ssw] =
                __float2bfloat16(o);
          }
        }
      }
    }
  }
}

// ---------------- bf16 MFMA flash attention ----------------
// QKVb: [32768][768] bf16 (Q cols 0-255, K cols 256-511, V unused here)
// Vt:   [(b*8+h)*32+d][512] bf16, s pre-swizzled: s' = s ^ ((d&7)<<3) in 64-blk
// Ob:   [32768][256] bf16
__global__ __launch_bounds__(256) void attn_mfma_kernel(
    const bf16* __restrict__ QKVb, const bf16* __restrict__ Vt,
    const int* __restrict__ amask, bf16* __restrict__ Ob) {
  const int b = blockIdx.z, h = blockIdx.y, q0 = blockIdx.x * 64;
  const int tid = threadIdx.x;
  const int wv = tid >> 6, ln = tid & 63;
  const int fr = ln & 15, g4 = ln >> 4;
  const int bh32 = (b * 8 + h) * 32;
  __shared__ __align__(16) bf16 Qs[2048];   // [64][32]
  __shared__ __align__(16) bf16 Ks[2048];   // [64][32]
  __shared__ __align__(16) bf16 Vs[2048];   // [32][64] (swizzled)
  __shared__ __align__(16) bf16 Ps[4096];   // per-wave [16][64] (swizzled)
  __shared__ float Ms[64];

  // stage Q once
  gload_lds16(QKVb + (size_t)(b * S_LEN + q0 + (tid >> 2)) * 768 + h * 32 +
                  (tid & 3) * 8,
              &Qs[wv * 512]);

  f32x4 accO[2];
  accO[0] = (f32x4){0.f, 0.f, 0.f, 0.f};
  accO[1] = (f32x4){0.f, 0.f, 0.f, 0.f};
  float mrun[4] = {-1e30f, -1e30f, -1e30f, -1e30f};
  float lrun[4] = {0.f, 0.f, 0.f, 0.f};
  const float scale = 0.17677669529663687f;   // 1/sqrt(32)

  for (int k0 = 0; k0 < S_LEN; k0 += 64) {
    gload_lds16(QKVb + (size_t)(b * S_LEN + k0 + (tid >> 2)) * 768 + 256 +
                    h * 32 + (tid & 3) * 8,
                &Ks[wv * 512]);
    gload_lds16(Vt + (size_t)(bh32 + (tid >> 3)) * 512 + k0 + (tid & 7) * 8,
                &Vs[wv * 512]);
    if (tid < 64) Ms[tid] = (amask[b * S_LEN + k0 + tid] != 0) ? 0.f : -1e9f;
    __syncthreads();

    // QK^T: wave's 16 q-rows x 64 keys
    short8 aq = *(const short8*)&Qs[(wv * 16 + fr) * 32 + g4 * 8];
    f32x4 sfr[4];
#pragma unroll
    for (int kb = 0; kb < 4; ++kb) {
      short8 bk = *(const short8*)&Ks[(kb * 16 + fr) * 32 + g4 * 8];
      f32x4 z = (f32x4){0.f, 0.f, 0.f, 0.f};
      sfr[kb] = __builtin_amdgcn_mfma_f32_16x16x32_bf16(aq, bk, z, 0, 0, 0);
    }
    float mb[4];
#pragma unroll
    for (int kb = 0; kb < 4; ++kb) mb[kb] = Ms[kb * 16 + fr];

    float p[4][4];   // [r][kb]
#pragma unroll
    for (int r = 0; r < 4; ++r) {
      float mx = -1e30f;
#pragma unroll
      for (int kb = 0; kb < 4; ++kb) {
        float v = sfr[kb][r] * scale + mb[kb];
        p[r][kb] = v;
        mx = fmaxf(mx, v);
      }
      mx = fmaxf(mx, __shfl_xor(mx, 1));
      mx = fmaxf(mx, __shfl_xor(mx, 2));
      mx = fmaxf(mx, __shfl_xor(mx, 4));
      mx = fmaxf(mx, __shfl_xor(mx, 8));
      const float mnew = fmaxf(mrun[r], mx);
      const float corr = __expf(mrun[r] - mnew);
      float ps = 0.f;
#pragma unroll
      for (int kb = 0; kb < 4; ++kb) {
        float e = __expf(p[r][kb] - mnew);
        p[r][kb] = e;
        ps += e;
      }
      ps += __shfl_xor(ps, 1);
      ps += __shfl_xor(ps, 2);
      ps += __shfl_xor(ps, 4);
      ps += __shfl_xor(ps, 8);
      lrun[r] = lrun[r] * corr + ps;
      mrun[r] = mnew;
      accO[0][r] *= corr;
      accO[1][r] *= corr;
    }

    // write P (bf16, swizzled) to this wave's LDS region
#pragma unroll
    for (int r = 0; r < 4; ++r) {
      const int q = g4 * 4 + r;
      const int sw = (q & 7) << 3;
#pragma unroll
      for (int kb = 0; kb < 4; ++kb)
        Ps[wv * 1024 + q * 64 + ((kb * 16 + fr) ^ sw)] =
            __float2bfloat16(p[r][kb]);
    }

    // PV: O[q][d] += P[16x32k] @ V[32k x 16d]
#pragma unroll
    for (int kk = 0; kk < 2; ++kk) {
      short8 pa = *(const short8*)
          &Ps[wv * 1024 + fr * 64 + ((kk * 32 + g4 * 8) ^ ((fr & 7) << 3))];
#pragma unroll
      for (int df = 0; df < 2; ++df) {
        short8 vb = *(const short8*)
            &Vs[(df * 16 + fr) * 64 + ((kk * 32 + g4 * 8) ^ ((fr & 7) << 3))];
        accO[df] = __builtin_amdgcn_mfma_f32_16x16x32_bf16(
            pa, vb, accO[df], 0, 0, 0);
      }
    }
    __syncthreads();
  }

#pragma unroll
  for (int r = 0; r < 4; ++r) {
    const float inv = 1.0f / lrun[r];
    const int q = q0 + wv * 16 + g4 * 4 + r;
    const size_t orow = ((size_t)b * S_LEN + q) * H_DIM + h * 32;
    Ob[orow + fr]      = __float2bfloat16(accO[0][r] * inv);
    Ob[orow + 16 + fr] = __float2bfloat16(accO[1][r] * inv);
  }
}

// ---------------- residual + layernorm, wave-per-token ----------------
template<bool HAS_RES, bool WRITE_BF>
__global__ __launch_bounds__(256) void ln4_kernel(
    const float* __restrict__ Xin, const float* __restrict__ Yres,
    float* __restrict__ Xout, bf16* __restrict__ Xbout,
    const float* __restrict__ g, const float* __restrict__ bt) {
  const int tid = threadIdx.x, wv = tid >> 6, ln = tid & 63;
  const size_t tok = (size_t)blockIdx.x * 4 + wv;
  float4 v = ((const float4*)Xin)[tok * 64 + ln];
  if (HAS_RES) {
    float4 y = ((const float4*)Yres)[tok * 64 + ln];
    v.x += y.x; v.y += y.y; v.z += y.z; v.w += y.w;
  }
  float s = v.x + v.y + v.z + v.w;
#pragma unroll
  for (int off = 1; off < 64; off <<= 1) s += __shfl_xor(s, off);
  const float mu = s * (1.0f / 256.0f);
  const float dx = v.x - mu, dy = v.y - mu, dz = v.z - mu, dw = v.w - mu;
  float sq = dx * dx + dy * dy + dz * dz + dw * dw;
#pragma unroll
  for (int off = 1; off < 64; off <<= 1) sq += __shfl_xor(sq, off);
  const float rstd = rsqrtf(sq * (1.0f / 256.0f) + 1e-5f);
  const float4 gg = ((const float4*)g)[ln];
  const float4 bb = ((const float4*)bt)[ln];
  float4 o;
  o.x = dx * rstd * gg.x + bb.x;
  o.y = dy * rstd * gg.y + bb.y;
  o.z = dz * rstd * gg.z + bb.z;
  o.w = dw * rstd * gg.w + bb.w;
  ((float4*)Xout)[tok * 64 + ln] = o;
  if (WRITE_BF) {
    ushort4 pk;
    pk.x = f2bu(o.x); pk.y = f2bu(o.y); pk.z = f2bu(o.z); pk.w = f2bu(o.w);
    *(ushort4*)&Xbout[tok * 256 + ln * 4] = pk;
  }
}

// ---------------- pooling ----------------
__global__ __launch_bounds__(256) void pool_kernel(
    const float* __restrict__ X, const int* __restrict__ amask,
    const int* __restrict__ sub_idx, const int* __restrict__ sub_cnt,
    const int* __restrict__ obj_idx, const int* __restrict__ obj_cnt,
    float* __restrict__ feat) {
  const int b = blockIdx.x, t = threadIdx.x;
  const float* xb = X + (size_t)b * S_LEN * H_DIM;
  {
    float s = 0.f;
    int c = sub_cnt[b];
    for (int j = 0; j < c; ++j) s += xb[(size_t)sub_idx[b * 8 + j] * H_DIM + t];
    feat[(size_t)b * 768 + t] = (c > 0) ? s / (float)c : 0.f;
  }
  {
    float s = 0.f;
    int c = obj_cnt[b];
    for (int j = 0; j < c; ++j) s += xb[(size_t)obj_idx[b * 8 + j] * H_DIM + t];
    feat[(size_t)b * 768 + 256 + t] = (c > 0) ? s / (float)c : 0.f;
  }
  {
    float s = 0.f, len = 0.f;
    for (int k = 0; k < S_LEN; ++k) {
      if (amask[b * S_LEN + k]) {
        s += xb[(size_t)k * H_DIM + t];
        len += 1.f;
      }
    }
    feat[(size_t)b * 768 + 512 + t] = s / len;
  }
}

// ---------------- classifier ----------------
__global__ __launch_bounds__(256) void cls_kernel(
    const float* __restrict__ feat, const float* __restrict__ mW1,
    const float* __restrict__ mb1, const float* __restrict__ mW2,
    const float* __restrict__ mb2, float* __restrict__ out) {
  const int b = blockIdx.x, t = threadIdx.x;
  __shared__ float fs[768];
  __shared__ float hid[256];
#pragma unroll
  for (int e = 0; e < 3; ++e) fs[t + e * 256] = feat[(size_t)b * 768 + t + e * 256];
  __syncthreads();
  float acc = mb1[t];
  for (int k = 0; k < 768; ++k) acc += fs[k] * mW1[(size_t)k * 256 + t];
  hid[t] = fmaxf(acc, 0.f);
  __syncthreads();
  if (t < 25) {
    float o = mb2[t];
    for (int j = 0; j < 256; ++j) o += hid[j] * mW2[j * 25 + t];
    out[b * 25 + t] = o;
  }
}

// ---------------------------------------------------------------------------
extern "C" void kernel_launch(void* const* d_in, const int* in_sizes, int n_in,
                              void* d_out, int out_size, void* d_ws, size_t ws_size,
                              hipStream_t stream) {
  const int*   input_ids = (const int*)d_in[0];
  const int*   amask     = (const int*)d_in[1];
  const int*   sub_idx   = (const int*)d_in[2];
  const int*   sub_cnt   = (const int*)d_in[3];
  const int*   obj_idx   = (const int*)d_in[4];
  const int*   obj_cnt   = (const int*)d_in[5];
  const float* emb  = (const float*)d_in[6];
  const float* Wqkv = (const float*)d_in[7];
  const float* bqkv = (const float*)d_in[8];
  const float* Wo   = (const float*)d_in[9];
  const float* bo   = (const float*)d_in[10];
  const float* ln1g = (const float*)d_in[11];
  const float* ln1b = (const float*)d_in[12];
  const float* ln2g = (const float*)d_in[13];
  const float* ln2b = (const float*)d_in[14];
  const float* W1   = (const float*)d_in[15];
  const float* b1   = (const float*)d_in[16];
  const float* W2   = (const float*)d_in[17];
  const float* b2   = (const float*)d_in[18];
  const float* lnfg = (const float*)d_in[19];
  const float* lnfb = (const float*)d_in[20];
  const float* mW1  = (const float*)d_in[21];
  const float* mb1  = (const float*)d_in[22];
  const float* mW2  = (const float*)d_in[23];
  const float* mb2  = (const float*)d_in[24];
  float* out = (float*)d_out;

  // workspace layout (bytes)
  char* w = (char*)d_ws;
  float* X    = (float*)w;                         w += (size_t)NTOK * 256 * 4;  // 33.5MB
  bf16*  Xb   = (bf16*)w;                          w += (size_t)NTOK * 256 * 2;  // 16.8MB
  bf16*  QKVb = (bf16*)w;                          w += (size_t)NTOK * 768 * 2;  // 50.3MB
  bf16*  Vtg  = (bf16*)w;                          w += (size_t)NTOK * 256 * 2;  // 16.8MB
  bf16*  Ob   = (bf16*)w;                          w += (size_t)NTOK * 256 * 2;  // 16.8MB
  float* Y    = (float*)w;                         w += (size_t)NTOK * 256 * 4;  // 33.5MB
  bf16*  Wqkvt= (bf16*)w;                          w += (size_t)4 * 768 * 256 * 2;
  bf16*  Wot  = (bf16*)w;                          w += (size_t)4 * 256 * 256 * 2;
  bf16*  W1t  = (bf16*)w;                          w += (size_t)4 * 1024 * 256 * 2;
  bf16*  W2t  = (bf16*)w;                          w += (size_t)4 * 256 * 1024 * 2;
  float* feat = (float*)w;                         w += (size_t)64 * 768 * 4;
  bf16*  Hb   = QKVb;   // aliases [QKVb, Vtg] = 67.1MB >= 32768*1024*2

  // weight cast+transpose (4 launches cover all layers)
  tcast_kernel<<<dim3(24, 8, 4), 256, 0, stream>>>(Wqkv, Wqkvt, 256, 768);
  tcast_kernel<<<dim3(8, 8, 4), 256, 0, stream>>>(Wo, Wot, 256, 256);
  tcast_kernel<<<dim3(32, 8, 4), 256, 0, stream>>>(W1, W1t, 256, 1024);
  tcast_kernel<<<dim3(8, 32, 4), 256, 0, stream>>>(W2, W2t, 1024, 256);

  embed_kernel<<<8192, 256, 0, stream>>>(input_ids, emb, X, Xb);

  for (int l = 0; l < 4; ++l) {
    const bf16* Wqkvt_l = Wqkvt + (size_t)l * 768 * 256;
    const bf16* Wot_l   = Wot + (size_t)l * 256 * 256;
    const bf16* W1t_l   = W1t + (size_t)l * 1024 * 256;
    const bf16* W2t_l   = W2t + (size_t)l * 256 * 1024;

    hgemm_kernel<2, false><<<dim3(6, 256), 256, 0, stream>>>(
        Xb, Wqkvt_l, bqkv + (size_t)l * 768, nullptr, QKVb, Vtg, NTOK, 768, 256);
    attn_mfma_kernel<<<dim3(8, 8, 64), 256, 0, stream>>>(QKVb, Vtg, amask, Ob);
    hgemm_kernel<0, false><<<dim3(2, 256), 256, 0, stream>>>(
        Ob, Wot_l, bo + (size_t)l * 256, Y, nullptr, nullptr, NTOK, 256, 256);
    ln4_kernel<true, true><<<8192, 256, 0, stream>>>(
        X, Y, X, Xb, ln1g + l * 256, ln1b + l * 256);
    hgemm_kernel<1, true><<<dim3(8, 256), 256, 0, stream>>>(
        Xb, W1t_l, b1 + (size_t)l * 1024, nullptr, Hb, nullptr, NTOK, 1024, 256);
    hgemm_kernel<0, false><<<dim3(2, 256), 256, 0, stream>>>(
        Hb, W2t_l, b2 + (size_t)l * 256, Y, nullptr, nullptr, NTOK, 256, 1024);
    ln4_kernel<true, true><<<8192, 256, 0, stream>>>(
        X, Y, X, Xb, ln2g + l * 256, ln2b + l * 256);
  }
  ln4_kernel<false, false><<<8192, 256, 0, stream>>>(
      X, nullptr, X, nullptr, lnfg, lnfb);
  pool_kernel<<<64, 256, 0, stream>>>(X, amask, sub_idx, sub_cnt,
                                      obj_idx, obj_cnt, feat);
  cls_kernel<<<64, 256, 0, stream>>>(feat, mW1, mb1, mW2, mb2, out);
}

// Round 3
// 1066.247 us; speedup vs baseline: 4.4254x; 1.1627x over previous
//
#include <hip/hip_runtime.h>
#include <hip/hip_bf16.h>

// ---------------------------------------------------------------------------
// CLUTRR transformer: B=64 S=512 H=256 L=4 NH=8 DH=32 F=1024 V=50265 K=8 R=25
// Round 3: + parallel pool kernel (1024 thr), + fused GEMM/residual/LN/bf16
// epilogue for the two N=256 GEMMs (Wo-proj, FFN2). Y buffer eliminated.
// ---------------------------------------------------------------------------

typedef __hip_bfloat16 bf16;
typedef __attribute__((ext_vector_type(8))) short short8;
typedef __attribute__((ext_vector_type(4))) float f32x4;

#define S_LEN 512
#define H_DIM 256
#define NTOK  32768      // B*S

__device__ __forceinline__ void gload_lds16(const void* g, void* l) {
  __builtin_amdgcn_global_load_lds(
      (const __attribute__((address_space(1))) unsigned int*)g,
      (__attribute__((address_space(3))) unsigned int*)l, 16, 0, 0);
}

__device__ __forceinline__ unsigned short f2bu(float x) {
  bf16 t = __float2bfloat16(x);
  return *reinterpret_cast<unsigned short*>(&t);
}

// ---------------- weight cast + transpose: out[N][K] = bf16(in[K][N]) -------
__global__ __launch_bounds__(256) void tcast_kernel(
    const float* __restrict__ in, bf16* __restrict__ out, int K, int N) {
  const int l = blockIdx.z;
  in  += (size_t)l * K * N;
  out += (size_t)l * K * N;
  __shared__ float t[32][33];
  const int n0 = blockIdx.x * 32, k0 = blockIdx.y * 32;
  const int c = threadIdx.x & 31, r = threadIdx.x >> 5;
#pragma unroll
  for (int rr = r; rr < 32; rr += 8)
    t[rr][c] = in[(size_t)(k0 + rr) * N + n0 + c];
  __syncthreads();
#pragma unroll
  for (int rr = r; rr < 32; rr += 8)
    out[(size_t)(n0 + rr) * K + k0 + c] = __float2bfloat16(t[c][rr]);
}

// ---------------- embedding gather: X fp32 + Xb bf16 ----------------
__global__ __launch_bounds__(256) void embed_kernel(
    const int* __restrict__ ids, const float* __restrict__ emb,
    float* __restrict__ X, bf16* __restrict__ Xb) {
  size_t i4 = (size_t)blockIdx.x * 256 + threadIdx.x;   // float4 index
  int tok = (int)(i4 >> 6);
  int d4  = (int)(i4 & 63);
  float4 v = *(const float4*)&emb[(size_t)ids[tok] * H_DIM + d4 * 4];
  *(float4*)&X[i4 * 4] = v;
  ushort4 pk;
  pk.x = f2bu(v.x); pk.y = f2bu(v.y); pk.z = f2bu(v.z); pk.w = f2bu(v.w);
  *(ushort4*)&Xb[i4 * 4] = pk;
}

// ---------------- bf16 MFMA GEMM: C = A[M,K] @ Bt[N,K]^T + bias -------------
// MODE 1: bf16 out Cb (w/ optional relu);
// MODE 2: QKV split — n<512 -> Cb[m][768], n>=512 -> Vt[b,h,d,s^swz] bf16.
template<int MODE, bool RELU>
__global__ __launch_bounds__(256) void hgemm_kernel(
    const bf16* __restrict__ A, const bf16* __restrict__ Bt,
    const float* __restrict__ bias, float* __restrict__ Cf,
    bf16* __restrict__ Cb, bf16* __restrict__ Vt,
    int M, int N, int K) {
  __shared__ __align__(16) bf16 As[4096];   // [128][32]
  __shared__ __align__(16) bf16 Bs[4096];   // [128][32]
  const int tid = threadIdx.x;
  const int wv = tid >> 6, ln = tid & 63;
  const int fr = ln & 15, g4 = ln >> 4;
  const int wr = wv >> 1, wc = wv & 1;
  const int m0 = blockIdx.y * 128, n0 = blockIdx.x * 128;
  const int lr = tid >> 2, lk = (tid & 3) * 8;   // staging row / k-offset

  f32x4 acc[4][4];
#pragma unroll
  for (int i = 0; i < 4; ++i)
#pragma unroll
    for (int j = 0; j < 4; ++j)
      acc[i][j] = (f32x4){0.f, 0.f, 0.f, 0.f};

  for (int k0 = 0; k0 < K; k0 += 32) {
    gload_lds16(A  + (size_t)(m0 + lr) * K + k0 + lk,       &As[wv * 512]);
    gload_lds16(A  + (size_t)(m0 + 64 + lr) * K + k0 + lk,  &As[2048 + wv * 512]);
    gload_lds16(Bt + (size_t)(n0 + lr) * K + k0 + lk,       &Bs[wv * 512]);
    gload_lds16(Bt + (size_t)(n0 + 64 + lr) * K + k0 + lk,  &Bs[2048 + wv * 512]);
    __syncthreads();
    short8 af[4], bfv[4];
#pragma unroll
    for (int i = 0; i < 4; ++i)
      af[i] = *(const short8*)&As[(wr * 64 + i * 16 + fr) * 32 + g4 * 8];
#pragma unroll
    for (int j = 0; j < 4; ++j)
      bfv[j] = *(const short8*)&Bs[(wc * 64 + j * 16 + fr) * 32 + g4 * 8];
#pragma unroll
    for (int i = 0; i < 4; ++i)
#pragma unroll
      for (int j = 0; j < 4; ++j)
        acc[i][j] = __builtin_amdgcn_mfma_f32_16x16x32_bf16(
            af[i], bfv[j], acc[i][j], 0, 0, 0);
    __syncthreads();
  }

  const int crow = g4 * 4, ccol = fr;
#pragma unroll
  for (int j = 0; j < 4; ++j) {
    const int n = n0 + wc * 64 + j * 16 + ccol;
    const float bv = bias[n];
#pragma unroll
    for (int i = 0; i < 4; ++i) {
      const int mbase = m0 + wr * 64 + i * 16 + crow;
#pragma unroll
      for (int r = 0; r < 4; ++r) {
        float o = acc[i][j][r] + bv;
        if (RELU) o = fmaxf(o, 0.f);
        const int m = mbase + r;
        if (MODE == 1) {
          Cb[(size_t)m * N + n] = __float2bfloat16(o);
        } else {
          if (n < 512) {
            Cb[(size_t)m * 768 + n] = __float2bfloat16(o);
          } else {
            const int hd = n - 512, hh = hd >> 5, dd = hd & 31;
            const int bb = m >> 9, ss = m & 511;
            const int ssw = (ss & ~63) | ((ss & 63) ^ ((dd & 7) << 3));
            Vt[(((size_t)bb * 8 + hh) * 32 + dd) * 512 + ssw] =
                __float2bfloat16(o);
          }
        }
      }
    }
  }
}

// ---------------- fused GEMM + bias + residual + LayerNorm + bf16 ----------
// C = A[M,K] @ Bt[256,K]^T + bias; v = C + X; X = LN(v)*g+b; Xb = bf16(X).
// BM=64, BN=256 (full row), 4 waves each own a 64-col strip.
__global__ __launch_bounds__(256) void hgemm_ln_kernel(
    const bf16* __restrict__ A, const bf16* __restrict__ Bt,
    const float* __restrict__ bias, float* __restrict__ X,
    bf16* __restrict__ Xb, const float* __restrict__ g,
    const float* __restrict__ bt, int K) {
  __shared__ __align__(16) bf16 As[2048];   // [64][32]
  __shared__ __align__(16) bf16 Bs[8192];   // [256][32]
  __shared__ float rsum[4][64];
  __shared__ float rsq[4][64];
  const int tid = threadIdx.x;
  const int wv = tid >> 6;
  const int ln = tid & 63;
  const int fr = ln & 15, g4 = ln >> 4;
  const int m0 = blockIdx.x * 64;

  f32x4 acc[4][4];   // [row frag i][col frag j]
#pragma unroll
  for (int i = 0; i < 4; ++i)
#pragma unroll
    for (int j = 0; j < 4; ++j)
      acc[i][j] = (f32x4){0.f, 0.f, 0.f, 0.f};

  for (int k0 = 0; k0 < K; k0 += 32) {
    gload_lds16(A + (size_t)(m0 + (tid >> 2)) * K + k0 + (tid & 3) * 8,
                &As[wv * 512]);
#pragma unroll
    for (int e = 0; e < 4; ++e) {
      const int vt = e * 256 + tid;
      gload_lds16(Bt + (size_t)(vt >> 2) * K + k0 + (vt & 3) * 8,
                  &Bs[e * 2048 + wv * 512]);
    }
    __syncthreads();
    short8 af[4], bfv[4];
#pragma unroll
    for (int i = 0; i < 4; ++i)
      af[i] = *(const short8*)&As[(i * 16 + fr) * 32 + g4 * 8];
#pragma unroll
    for (int j = 0; j < 4; ++j)
      bfv[j] = *(const short8*)&Bs[(wv * 64 + j * 16 + fr) * 32 + g4 * 8];
#pragma unroll
    for (int i = 0; i < 4; ++i)
#pragma unroll
      for (int j = 0; j < 4; ++j)
        acc[i][j] = __builtin_amdgcn_mfma_f32_16x16x32_bf16(
            af[i], bfv[j], acc[i][j], 0, 0, 0);
    __syncthreads();
  }

  // epilogue: bias + residual, then LN stats
  float gj[4], bj[4], bsj[4];
#pragma unroll
  for (int j = 0; j < 4; ++j) {
    const int n = wv * 64 + j * 16 + fr;
    gj[j] = g[n]; bj[j] = bt[n]; bsj[j] = bias[n];
  }
#pragma unroll
  for (int i = 0; i < 4; ++i) {
#pragma unroll
    for (int r = 0; r < 4; ++r) {
      const int m = m0 + i * 16 + g4 * 4 + r;
#pragma unroll
      for (int j = 0; j < 4; ++j)
        acc[i][j][r] += bsj[j] + X[(size_t)m * 256 + wv * 64 + j * 16 + fr];
    }
  }
#pragma unroll
  for (int i = 0; i < 4; ++i) {
#pragma unroll
    for (int r = 0; r < 4; ++r) {
      float sp = acc[i][0][r] + acc[i][1][r] + acc[i][2][r] + acc[i][3][r];
      float qp = acc[i][0][r] * acc[i][0][r] + acc[i][1][r] * acc[i][1][r] +
                 acc[i][2][r] * acc[i][2][r] + acc[i][3][r] * acc[i][3][r];
#pragma unroll
      for (int off = 1; off < 16; off <<= 1) {
        sp += __shfl_xor(sp, off);
        qp += __shfl_xor(qp, off);
      }
      if (fr == 0) {
        const int ri = i * 16 + g4 * 4 + r;
        rsum[wv][ri] = sp;
        rsq[wv][ri] = qp;
      }
    }
  }
  __syncthreads();
#pragma unroll
  for (int i = 0; i < 4; ++i) {
#pragma unroll
    for (int r = 0; r < 4; ++r) {
      const int ri = i * 16 + g4 * 4 + r;
      const float tot = rsum[0][ri] + rsum[1][ri] + rsum[2][ri] + rsum[3][ri];
      const float tq = rsq[0][ri] + rsq[1][ri] + rsq[2][ri] + rsq[3][ri];
      const float mu = tot * (1.0f / 256.0f);
      const float var = tq * (1.0f / 256.0f) - mu * mu;
      const float rstd = rsqrtf(var + 1e-5f);
      const int m = m0 + ri;
#pragma unroll
      for (int j = 0; j < 4; ++j) {
        const float o = (acc[i][j][r] - mu) * rstd * gj[j] + bj[j];
        const size_t idx = (size_t)m * 256 + wv * 64 + j * 16 + fr;
        X[idx] = o;
        Xb[idx] = __float2bfloat16(o);
      }
    }
  }
}

// ---------------- bf16 MFMA flash attention ----------------
__global__ __launch_bounds__(256) void attn_mfma_kernel(
    const bf16* __restrict__ QKVb, const bf16* __restrict__ Vt,
    const int* __restrict__ amask, bf16* __restrict__ Ob) {
  const int b = blockIdx.z, h = blockIdx.y, q0 = blockIdx.x * 64;
  const int tid = threadIdx.x;
  const int wv = tid >> 6, ln = tid & 63;
  const int fr = ln & 15, g4 = ln >> 4;
  const int bh32 = (b * 8 + h) * 32;
  __shared__ __align__(16) bf16 Qs[2048];   // [64][32]
  __shared__ __align__(16) bf16 Ks[2048];   // [64][32]
  __shared__ __align__(16) bf16 Vs[2048];   // [32][64] (swizzled)
  __shared__ __align__(16) bf16 Ps[4096];   // per-wave [16][64] (swizzled)
  __shared__ float Ms[64];

  gload_lds16(QKVb + (size_t)(b * S_LEN + q0 + (tid >> 2)) * 768 + h * 32 +
                  (tid & 3) * 8,
              &Qs[wv * 512]);

  f32x4 accO[2];
  accO[0] = (f32x4){0.f, 0.f, 0.f, 0.f};
  accO[1] = (f32x4){0.f, 0.f, 0.f, 0.f};
  float mrun[4] = {-1e30f, -1e30f, -1e30f, -1e30f};
  float lrun[4] = {0.f, 0.f, 0.f, 0.f};
  const float scale = 0.17677669529663687f;   // 1/sqrt(32)

  for (int k0 = 0; k0 < S_LEN; k0 += 64) {
    gload_lds16(QKVb + (size_t)(b * S_LEN + k0 + (tid >> 2)) * 768 + 256 +
                    h * 32 + (tid & 3) * 8,
                &Ks[wv * 512]);
    gload_lds16(Vt + (size_t)(bh32 + (tid >> 3)) * 512 + k0 + (tid & 7) * 8,
                &Vs[wv * 512]);
    if (tid < 64) Ms[tid] = (amask[b * S_LEN + k0 + tid] != 0) ? 0.f : -1e9f;
    __syncthreads();

    short8 aq = *(const short8*)&Qs[(wv * 16 + fr) * 32 + g4 * 8];
    f32x4 sfr[4];
#pragma unroll
    for (int kb = 0; kb < 4; ++kb) {
      short8 bk = *(const short8*)&Ks[(kb * 16 + fr) * 32 + g4 * 8];
      f32x4 z = (f32x4){0.f, 0.f, 0.f, 0.f};
      sfr[kb] = __builtin_amdgcn_mfma_f32_16x16x32_bf16(aq, bk, z, 0, 0, 0);
    }
    float mb[4];
#pragma unroll
    for (int kb = 0; kb < 4; ++kb) mb[kb] = Ms[kb * 16 + fr];

    float p[4][4];   // [r][kb]
#pragma unroll
    for (int r = 0; r < 4; ++r) {
      float mx = -1e30f;
#pragma unroll
      for (int kb = 0; kb < 4; ++kb) {
        float v = sfr[kb][r] * scale + mb[kb];
        p[r][kb] = v;
        mx = fmaxf(mx, v);
      }
      mx = fmaxf(mx, __shfl_xor(mx, 1));
      mx = fmaxf(mx, __shfl_xor(mx, 2));
      mx = fmaxf(mx, __shfl_xor(mx, 4));
      mx = fmaxf(mx, __shfl_xor(mx, 8));
      const float mnew = fmaxf(mrun[r], mx);
      const float corr = __expf(mrun[r] - mnew);
      float ps = 0.f;
#pragma unroll
      for (int kb = 0; kb < 4; ++kb) {
        float e = __expf(p[r][kb] - mnew);
        p[r][kb] = e;
        ps += e;
      }
      ps += __shfl_xor(ps, 1);
      ps += __shfl_xor(ps, 2);
      ps += __shfl_xor(ps, 4);
      ps += __shfl_xor(ps, 8);
      lrun[r] = lrun[r] * corr + ps;
      mrun[r] = mnew;
      accO[0][r] *= corr;
      accO[1][r] *= corr;
    }

#pragma unroll
    for (int r = 0; r < 4; ++r) {
      const int q = g4 * 4 + r;
      const int sw = (q & 7) << 3;
#pragma unroll
      for (int kb = 0; kb < 4; ++kb)
        Ps[wv * 1024 + q * 64 + ((kb * 16 + fr) ^ sw)] =
            __float2bfloat16(p[r][kb]);
    }

#pragma unroll
    for (int kk = 0; kk < 2; ++kk) {
      short8 pa = *(const short8*)
          &Ps[wv * 1024 + fr * 64 + ((kk * 32 + g4 * 8) ^ ((fr & 7) << 3))];
#pragma unroll
      for (int df = 0; df < 2; ++df) {
        short8 vb = *(const short8*)
            &Vs[(df * 16 + fr) * 64 + ((kk * 32 + g4 * 8) ^ ((fr & 7) << 3))];
        accO[df] = __builtin_amdgcn_mfma_f32_16x16x32_bf16(
            pa, vb, accO[df], 0, 0, 0);
      }
    }
    __syncthreads();
  }

#pragma unroll
  for (int r = 0; r < 4; ++r) {
    const float inv = 1.0f / lrun[r];
    const int q = q0 + wv * 16 + g4 * 4 + r;
    const size_t orow = ((size_t)b * S_LEN + q) * H_DIM + h * 32;
    Ob[orow + fr]      = __float2bfloat16(accO[0][r] * inv);
    Ob[orow + 16 + fr] = __float2bfloat16(accO[1][r] * inv);
  }
}

// ---------------- final layernorm (no residual, fp32 only) ----------------
__global__ __launch_bounds__(256) void lnf_kernel(
    float* __restrict__ X, const float* __restrict__ g,
    const float* __restrict__ bt) {
  const int tid = threadIdx.x, wv = tid >> 6, ln = tid & 63;
  const size_t tok = (size_t)blockIdx.x * 4 + wv;
  float4 v = ((const float4*)X)[tok * 64 + ln];
  float s = v.x + v.y + v.z + v.w;
#pragma unroll
  for (int off = 1; off < 64; off <<= 1) s += __shfl_xor(s, off);
  const float mu = s * (1.0f / 256.0f);
  const float dx = v.x - mu, dy = v.y - mu, dz = v.z - mu, dw = v.w - mu;
  float sq = dx * dx + dy * dy + dz * dz + dw * dw;
#pragma unroll
  for (int off = 1; off < 64; off <<= 1) sq += __shfl_xor(sq, off);
  const float rstd = rsqrtf(sq * (1.0f / 256.0f) + 1e-5f);
  const float4 gg = ((const float4*)g)[ln];
  const float4 bb = ((const float4*)bt)[ln];
  float4 o;
  o.x = dx * rstd * gg.x + bb.x;
  o.y = dy * rstd * gg.y + bb.y;
  o.z = dz * rstd * gg.z + bb.z;
  o.w = dw * rstd * gg.w + bb.w;
  ((float4*)X)[tok * 64 + ln] = o;
}

// ---------------- pooling: 1024 threads, s-loop split 4 ways ---------------
__global__ __launch_bounds__(1024) void pool_kernel(
    const float* __restrict__ X, const int* __restrict__ amask,
    const int* __restrict__ sub_idx, const int* __restrict__ sub_cnt,
    const int* __restrict__ obj_idx, const int* __restrict__ obj_cnt,
    float* __restrict__ feat) {
  const int b = blockIdx.x;
  const int tid = threadIdx.x;
  const int c = tid & 255, sl = tid >> 8;   // channel, s-slice
  const float* xb = X + (size_t)b * S_LEN * H_DIM;
  __shared__ float part[4][256];
  __shared__ int cnts[4];
  float s = 0.f;
  int cnt = 0;
  for (int k = sl * 128; k < sl * 128 + 128; ++k) {
    if (amask[b * S_LEN + k]) {
      s += xb[(size_t)k * H_DIM + c];
      ++cnt;
    }
  }
  part[sl][c] = s;
  if (c == 0) cnts[sl] = cnt;
  __syncthreads();
  if (sl == 0) {
    const float tot = part[0][c] + part[1][c] + part[2][c] + part[3][c];
    const float len = (float)(cnts[0] + cnts[1] + cnts[2] + cnts[3]);
    feat[(size_t)b * 768 + 512 + c] = tot / len;   // lengths >= 16
  } else if (sl == 1) {
    const int cc = sub_cnt[b];
    float s2 = 0.f;
    for (int j = 0; j < cc; ++j)
      s2 += xb[(size_t)sub_idx[b * 8 + j] * H_DIM + c];
    feat[(size_t)b * 768 + c] = (cc > 0) ? s2 / (float)cc : 0.f;
  } else if (sl == 2) {
    const int cc = obj_cnt[b];
    float s2 = 0.f;
    for (int j = 0; j < cc; ++j)
      s2 += xb[(size_t)obj_idx[b * 8 + j] * H_DIM + c];
    feat[(size_t)b * 768 + 256 + c] = (cc > 0) ? s2 / (float)cc : 0.f;
  }
}

// ---------------- classifier ----------------
__global__ __launch_bounds__(256) void cls_kernel(
    const float* __restrict__ feat, const float* __restrict__ mW1,
    const float* __restrict__ mb1, const float* __restrict__ mW2,
    const float* __restrict__ mb2, float* __restrict__ out) {
  const int b = blockIdx.x, t = threadIdx.x;
  __shared__ float fs[768];
  __shared__ float hid[256];
#pragma unroll
  for (int e = 0; e < 3; ++e) fs[t + e * 256] = feat[(size_t)b * 768 + t + e * 256];
  __syncthreads();
  float acc = mb1[t];
  for (int k = 0; k < 768; ++k) acc += fs[k] * mW1[(size_t)k * 256 + t];
  hid[t] = fmaxf(acc, 0.f);
  __syncthreads();
  if (t < 25) {
    float o = mb2[t];
    for (int j = 0; j < 256; ++j) o += hid[j] * mW2[j * 25 + t];
    out[b * 25 + t] = o;
  }
}

// ---------------------------------------------------------------------------
extern "C" void kernel_launch(void* const* d_in, const int* in_sizes, int n_in,
                              void* d_out, int out_size, void* d_ws, size_t ws_size,
                              hipStream_t stream) {
  const int*   input_ids = (const int*)d_in[0];
  const int*   amask     = (const int*)d_in[1];
  const int*   sub_idx   = (const int*)d_in[2];
  const int*   sub_cnt   = (const int*)d_in[3];
  const int*   obj_idx   = (const int*)d_in[4];
  const int*   obj_cnt   = (const int*)d_in[5];
  const float* emb  = (const float*)d_in[6];
  const float* Wqkv = (const float*)d_in[7];
  const float* bqkv = (const float*)d_in[8];
  const float* Wo   = (const float*)d_in[9];
  const float* bo   = (const float*)d_in[10];
  const float* ln1g = (const float*)d_in[11];
  const float* ln1b = (const float*)d_in[12];
  const float* ln2g = (const float*)d_in[13];
  const float* ln2b = (const float*)d_in[14];
  const float* W1   = (const float*)d_in[15];
  const float* b1   = (const float*)d_in[16];
  const float* W2   = (const float*)d_in[17];
  const float* b2   = (const float*)d_in[18];
  const float* lnfg = (const float*)d_in[19];
  const float* lnfb = (const float*)d_in[20];
  const float* mW1  = (const float*)d_in[21];
  const float* mb1  = (const float*)d_in[22];
  const float* mW2  = (const float*)d_in[23];
  const float* mb2  = (const float*)d_in[24];
  float* out = (float*)d_out;

  // workspace layout (bytes)
  char* w = (char*)d_ws;
  float* X    = (float*)w;                         w += (size_t)NTOK * 256 * 4;  // 33.5MB
  bf16*  Xb   = (bf16*)w;                          w += (size_t)NTOK * 256 * 2;  // 16.8MB
  bf16*  QKVb = (bf16*)w;                          w += (size_t)NTOK * 768 * 2;  // 50.3MB
  bf16*  Vtg  = (bf16*)w;                          w += (size_t)NTOK * 256 * 2;  // 16.8MB
  bf16*  Ob   = (bf16*)w;                          w += (size_t)NTOK * 256 * 2;  // 16.8MB
  bf16*  Wqkvt= (bf16*)w;                          w += (size_t)4 * 768 * 256 * 2;
  bf16*  Wot  = (bf16*)w;                          w += (size_t)4 * 256 * 256 * 2;
  bf16*  W1t  = (bf16*)w;                          w += (size_t)4 * 1024 * 256 * 2;
  bf16*  W2t  = (bf16*)w;                          w += (size_t)4 * 256 * 1024 * 2;
  float* feat = (float*)w;                         w += (size_t)64 * 768 * 4;
  bf16*  Hb   = QKVb;   // aliases [QKVb, Vtg] = 67.1MB >= 32768*1024*2

  tcast_kernel<<<dim3(24, 8, 4), 256, 0, stream>>>(Wqkv, Wqkvt, 256, 768);
  tcast_kernel<<<dim3(8, 8, 4), 256, 0, stream>>>(Wo, Wot, 256, 256);
  tcast_kernel<<<dim3(32, 8, 4), 256, 0, stream>>>(W1, W1t, 256, 1024);
  tcast_kernel<<<dim3(8, 32, 4), 256, 0, stream>>>(W2, W2t, 1024, 256);

  embed_kernel<<<8192, 256, 0, stream>>>(input_ids, emb, X, Xb);

  for (int l = 0; l < 4; ++l) {
    const bf16* Wqkvt_l = Wqkvt + (size_t)l * 768 * 256;
    const bf16* Wot_l   = Wot + (size_t)l * 256 * 256;
    const bf16* W1t_l   = W1t + (size_t)l * 1024 * 256;
    const bf16* W2t_l   = W2t + (size_t)l * 256 * 1024;

    hgemm_kernel<2, false><<<dim3(6, 256), 256, 0, stream>>>(
        Xb, Wqkvt_l, bqkv + (size_t)l * 768, nullptr, QKVb, Vtg, NTOK, 768, 256);
    attn_mfma_kernel<<<dim3(8, 8, 64), 256, 0, stream>>>(QKVb, Vtg, amask, Ob);
    hgemm_ln_kernel<<<512, 256, 0, stream>>>(
        Ob, Wot_l, bo + (size_t)l * 256, X, Xb,
        ln1g + l * 256, ln1b + l * 256, 256);
    hgemm_kernel<1, true><<<dim3(8, 256), 256, 0, stream>>>(
        Xb, W1t_l, b1 + (size_t)l * 1024, nullptr, Hb, nullptr, NTOK, 1024, 256);
    hgemm_ln_kernel<<<512, 256, 0, stream>>>(
        Hb, W2t_l, b2 + (size_t)l * 256, X, Xb,
        ln2g + l * 256, ln2b + l * 256, 1024);
  }
  lnf_kernel<<<8192, 256, 0, stream>>>(X, lnfg, lnfb);
  pool_kernel<<<64, 1024, 0, stream>>>(X, amask, sub_idx, sub_cnt,
                                       obj_idx, obj_cnt, feat);
  cls_kernel<<<64, 256, 0, stream>>>(feat, mW1, mb1, mW2, mb2, out);
}

// Round 4
// 947.662 us; speedup vs baseline: 4.9792x; 1.1251x over previous
//
#include <hip/hip_runtime.h>
#include <hip/hip_bf16.h>

// ---------------------------------------------------------------------------
// CLUTRR transformer: B=64 S=512 H=256 L=4 NH=8 DH=32 F=1024 V=50265 K=8 R=25
// Round 4: swapped-QK^T attention (lane-local softmax rows), exp2-domain,
// b64 P-writes with row-XOR swizzle. GEMM/LN/pool path unchanged from R3.
// ---------------------------------------------------------------------------

typedef __hip_bfloat16 bf16;
typedef __attribute__((ext_vector_type(8))) short short8;
typedef __attribute__((ext_vector_type(4))) float f32x4;

#define S_LEN 512
#define H_DIM 256
#define NTOK  32768      // B*S

__device__ __forceinline__ void gload_lds16(const void* g, void* l) {
  __builtin_amdgcn_global_load_lds(
      (const __attribute__((address_space(1))) unsigned int*)g,
      (__attribute__((address_space(3))) unsigned int*)l, 16, 0, 0);
}

__device__ __forceinline__ unsigned short f2bu(float x) {
  bf16 t = __float2bfloat16(x);
  return *reinterpret_cast<unsigned short*>(&t);
}

// ---------------- weight cast + transpose: out[N][K] = bf16(in[K][N]) -------
__global__ __launch_bounds__(256) void tcast_kernel(
    const float* __restrict__ in, bf16* __restrict__ out, int K, int N) {
  const int l = blockIdx.z;
  in  += (size_t)l * K * N;
  out += (size_t)l * K * N;
  __shared__ float t[32][33];
  const int n0 = blockIdx.x * 32, k0 = blockIdx.y * 32;
  const int c = threadIdx.x & 31, r = threadIdx.x >> 5;
#pragma unroll
  for (int rr = r; rr < 32; rr += 8)
    t[rr][c] = in[(size_t)(k0 + rr) * N + n0 + c];
  __syncthreads();
#pragma unroll
  for (int rr = r; rr < 32; rr += 8)
    out[(size_t)(n0 + rr) * K + k0 + c] = __float2bfloat16(t[c][rr]);
}

// ---------------- embedding gather: X fp32 + Xb bf16 ----------------
__global__ __launch_bounds__(256) void embed_kernel(
    const int* __restrict__ ids, const float* __restrict__ emb,
    float* __restrict__ X, bf16* __restrict__ Xb) {
  size_t i4 = (size_t)blockIdx.x * 256 + threadIdx.x;   // float4 index
  int tok = (int)(i4 >> 6);
  int d4  = (int)(i4 & 63);
  float4 v = *(const float4*)&emb[(size_t)ids[tok] * H_DIM + d4 * 4];
  *(float4*)&X[i4 * 4] = v;
  ushort4 pk;
  pk.x = f2bu(v.x); pk.y = f2bu(v.y); pk.z = f2bu(v.z); pk.w = f2bu(v.w);
  *(ushort4*)&Xb[i4 * 4] = pk;
}

// ---------------- bf16 MFMA GEMM: C = A[M,K] @ Bt[N,K]^T + bias -------------
// MODE 1: bf16 out Cb (w/ optional relu);
// MODE 2: QKV split — n<512 -> Cb[m][768], n>=512 -> Vt[b,h,d,s^swz] bf16.
template<int MODE, bool RELU>
__global__ __launch_bounds__(256) void hgemm_kernel(
    const bf16* __restrict__ A, const bf16* __restrict__ Bt,
    const float* __restrict__ bias, float* __restrict__ Cf,
    bf16* __restrict__ Cb, bf16* __restrict__ Vt,
    int M, int N, int K) {
  __shared__ __align__(16) bf16 As[4096];   // [128][32]
  __shared__ __align__(16) bf16 Bs[4096];   // [128][32]
  const int tid = threadIdx.x;
  const int wv = tid >> 6, ln = tid & 63;
  const int fr = ln & 15, g4 = ln >> 4;
  const int wr = wv >> 1, wc = wv & 1;
  const int m0 = blockIdx.y * 128, n0 = blockIdx.x * 128;
  const int lr = tid >> 2, lk = (tid & 3) * 8;   // staging row / k-offset

  f32x4 acc[4][4];
#pragma unroll
  for (int i = 0; i < 4; ++i)
#pragma unroll
    for (int j = 0; j < 4; ++j)
      acc[i][j] = (f32x4){0.f, 0.f, 0.f, 0.f};

  for (int k0 = 0; k0 < K; k0 += 32) {
    gload_lds16(A  + (size_t)(m0 + lr) * K + k0 + lk,       &As[wv * 512]);
    gload_lds16(A  + (size_t)(m0 + 64 + lr) * K + k0 + lk,  &As[2048 + wv * 512]);
    gload_lds16(Bt + (size_t)(n0 + lr) * K + k0 + lk,       &Bs[wv * 512]);
    gload_lds16(Bt + (size_t)(n0 + 64 + lr) * K + k0 + lk,  &Bs[2048 + wv * 512]);
    __syncthreads();
    short8 af[4], bfv[4];
#pragma unroll
    for (int i = 0; i < 4; ++i)
      af[i] = *(const short8*)&As[(wr * 64 + i * 16 + fr) * 32 + g4 * 8];
#pragma unroll
    for (int j = 0; j < 4; ++j)
      bfv[j] = *(const short8*)&Bs[(wc * 64 + j * 16 + fr) * 32 + g4 * 8];
#pragma unroll
    for (int i = 0; i < 4; ++i)
#pragma unroll
      for (int j = 0; j < 4; ++j)
        acc[i][j] = __builtin_amdgcn_mfma_f32_16x16x32_bf16(
            af[i], bfv[j], acc[i][j], 0, 0, 0);
    __syncthreads();
  }

  const int crow = g4 * 4, ccol = fr;
#pragma unroll
  for (int j = 0; j < 4; ++j) {
    const int n = n0 + wc * 64 + j * 16 + ccol;
    const float bv = bias[n];
#pragma unroll
    for (int i = 0; i < 4; ++i) {
      const int mbase = m0 + wr * 64 + i * 16 + crow;
#pragma unroll
      for (int r = 0; r < 4; ++r) {
        float o = acc[i][j][r] + bv;
        if (RELU) o = fmaxf(o, 0.f);
        const int m = mbase + r;
        if (MODE == 1) {
          Cb[(size_t)m * N + n] = __float2bfloat16(o);
        } else {
          if (n < 512) {
            Cb[(size_t)m * 768 + n] = __float2bfloat16(o);
          } else {
            const int hd = n - 512, hh = hd >> 5, dd = hd & 31;
            const int bb = m >> 9, ss = m & 511;
            const int ssw = (ss & ~63) | ((ss & 63) ^ ((dd & 7) << 3));
            Vt[(((size_t)bb * 8 + hh) * 32 + dd) * 512 + ssw] =
                __float2bfloat16(o);
          }
        }
      }
    }
  }
}

// ---------------- fused GEMM + bias + residual + LayerNorm + bf16 ----------
__global__ __launch_bounds__(256) void hgemm_ln_kernel(
    const bf16* __restrict__ A, const bf16* __restrict__ Bt,
    const float* __restrict__ bias, float* __restrict__ X,
    bf16* __restrict__ Xb, const float* __restrict__ g,
    const float* __restrict__ bt, int K) {
  __shared__ __align__(16) bf16 As[2048];   // [64][32]
  __shared__ __align__(16) bf16 Bs[8192];   // [256][32]
  __shared__ float rsum[4][64];
  __shared__ float rsq[4][64];
  const int tid = threadIdx.x;
  const int wv = tid >> 6;
  const int ln = tid & 63;
  const int fr = ln & 15, g4 = ln >> 4;
  const int m0 = blockIdx.x * 64;

  f32x4 acc[4][4];   // [row frag i][col frag j]
#pragma unroll
  for (int i = 0; i < 4; ++i)
#pragma unroll
    for (int j = 0; j < 4; ++j)
      acc[i][j] = (f32x4){0.f, 0.f, 0.f, 0.f};

  for (int k0 = 0; k0 < K; k0 += 32) {
    gload_lds16(A + (size_t)(m0 + (tid >> 2)) * K + k0 + (tid & 3) * 8,
                &As[wv * 512]);
#pragma unroll
    for (int e = 0; e < 4; ++e) {
      const int vt = e * 256 + tid;
      gload_lds16(Bt + (size_t)(vt >> 2) * K + k0 + (vt & 3) * 8,
                  &Bs[e * 2048 + wv * 512]);
    }
    __syncthreads();
    short8 af[4], bfv[4];
#pragma unroll
    for (int i = 0; i < 4; ++i)
      af[i] = *(const short8*)&As[(i * 16 + fr) * 32 + g4 * 8];
#pragma unroll
    for (int j = 0; j < 4; ++j)
      bfv[j] = *(const short8*)&Bs[(wv * 64 + j * 16 + fr) * 32 + g4 * 8];
#pragma unroll
    for (int i = 0; i < 4; ++i)
#pragma unroll
      for (int j = 0; j < 4; ++j)
        acc[i][j] = __builtin_amdgcn_mfma_f32_16x16x32_bf16(
            af[i], bfv[j], acc[i][j], 0, 0, 0);
    __syncthreads();
  }

  float gj[4], bj[4], bsj[4];
#pragma unroll
  for (int j = 0; j < 4; ++j) {
    const int n = wv * 64 + j * 16 + fr;
    gj[j] = g[n]; bj[j] = bt[n]; bsj[j] = bias[n];
  }
#pragma unroll
  for (int i = 0; i < 4; ++i) {
#pragma unroll
    for (int r = 0; r < 4; ++r) {
      const int m = m0 + i * 16 + g4 * 4 + r;
#pragma unroll
      for (int j = 0; j < 4; ++j)
        acc[i][j][r] += bsj[j] + X[(size_t)m * 256 + wv * 64 + j * 16 + fr];
    }
  }
#pragma unroll
  for (int i = 0; i < 4; ++i) {
#pragma unroll
    for (int r = 0; r < 4; ++r) {
      float sp = acc[i][0][r] + acc[i][1][r] + acc[i][2][r] + acc[i][3][r];
      float qp = acc[i][0][r] * acc[i][0][r] + acc[i][1][r] * acc[i][1][r] +
                 acc[i][2][r] * acc[i][2][r] + acc[i][3][r] * acc[i][3][r];
#pragma unroll
      for (int off = 1; off < 16; off <<= 1) {
        sp += __shfl_xor(sp, off);
        qp += __shfl_xor(qp, off);
      }
      if (fr == 0) {
        const int ri = i * 16 + g4 * 4 + r;
        rsum[wv][ri] = sp;
        rsq[wv][ri] = qp;
      }
    }
  }
  __syncthreads();
#pragma unroll
  for (int i = 0; i < 4; ++i) {
#pragma unroll
    for (int r = 0; r < 4; ++r) {
      const int ri = i * 16 + g4 * 4 + r;
      const float tot = rsum[0][ri] + rsum[1][ri] + rsum[2][ri] + rsum[3][ri];
      const float tq = rsq[0][ri] + rsq[1][ri] + rsq[2][ri] + rsq[3][ri];
      const float mu = tot * (1.0f / 256.0f);
      const float var = tq * (1.0f / 256.0f) - mu * mu;
      const float rstd = rsqrtf(var + 1e-5f);
      const int m = m0 + ri;
#pragma unroll
      for (int j = 0; j < 4; ++j) {
        const float o = (acc[i][j][r] - mu) * rstd * gj[j] + bj[j];
        const size_t idx = (size_t)m * 256 + wv * 64 + j * 16 + fr;
        X[idx] = o;
        Xb[idx] = __float2bfloat16(o);
      }
    }
  }
}

// ---------------- bf16 MFMA flash attention (swapped QK^T) ----------------
// QKVb: [32768][768] bf16 (Q cols 0-255, K cols 256-511)
// Vt:   [(b*8+h)*32+d][512] bf16, s pre-swizzled: s' = s ^ ((d&7)<<3) in 64-blk
// Ob:   [32768][256] bf16
// Wave wv owns q-rows wv*16..+15; lane's q = fr. Scores computed as S^T =
// mfma(K, Q): lane holds 16 k-values (kb*16 + g4*4 + rr) for its single q.
__global__ __launch_bounds__(256) void attn_mfma_kernel(
    const bf16* __restrict__ QKVb, const bf16* __restrict__ Vt,
    const int* __restrict__ amask, bf16* __restrict__ Ob) {
  const int b = blockIdx.z, h = blockIdx.y, q0 = blockIdx.x * 64;
  const int tid = threadIdx.x;
  const int wv = tid >> 6, ln = tid & 63;
  const int fr = ln & 15, g4 = ln >> 4;
  const int f8 = (fr & 7) << 3;
  const int bh32 = (b * 8 + h) * 32;
  __shared__ __align__(16) bf16 Qs[2048];   // [64][32]
  __shared__ __align__(16) bf16 Ks[2048];   // [64][32]
  __shared__ __align__(16) bf16 Vs[2048];   // [32 d][64 k] (swizzled)
  __shared__ __align__(16) bf16 Ps[4096];   // per-wave [16 q][64 k] (swizzled)
  __shared__ __align__(16) float Ms[64];

  gload_lds16(QKVb + (size_t)(b * S_LEN + q0 + (tid >> 2)) * 768 + h * 32 +
                  (tid & 3) * 8,
              &Qs[wv * 512]);
  __syncthreads();
  // B-operand fragment of Q^T: lane holds col q=fr, d-rows g4*8..+7. Hoisted.
  const short8 qb = *(const short8*)&Qs[(wv * 16 + fr) * 32 + g4 * 8];

  f32x4 accO[2];
  accO[0] = (f32x4){0.f, 0.f, 0.f, 0.f};
  accO[1] = (f32x4){0.f, 0.f, 0.f, 0.f};
  float mrun = -1e30f, lrun = 0.f;   // per-lane state for q = fr (log2 domain)
  // 1/sqrt(32) * log2(e)
  const float SC2 = 0.17677669529663687f * 1.4426950408889634f;
  const int srcq = 20 * g4;   // shfl src base: lane 16*g4 + (4*g4 + rr)

  for (int k0 = 0; k0 < S_LEN; k0 += 64) {
    gload_lds16(QKVb + (size_t)(b * S_LEN + k0 + (tid >> 2)) * 768 + 256 +
                    h * 32 + (tid & 3) * 8,
                &Ks[wv * 512]);
    gload_lds16(Vt + (size_t)(bh32 + (tid >> 3)) * 512 + k0 + (tid & 7) * 8,
                &Vs[wv * 512]);
    if (tid < 64) Ms[tid] = (amask[b * S_LEN + k0 + tid] != 0) ? 0.f : -1e9f;
    __syncthreads();

    // S^T = K @ Q^T : 4 MFMAs cover 64 k x 16 q
    f32x4 st[4];
#pragma unroll
    for (int kb = 0; kb < 4; ++kb) {
      const short8 kf = *(const short8*)&Ks[(kb * 16 + fr) * 32 + g4 * 8];
      f32x4 z = (f32x4){0.f, 0.f, 0.f, 0.f};
      st[kb] = __builtin_amdgcn_mfma_f32_16x16x32_bf16(kf, qb, z, 0, 0, 0);
    }

    // scale + mask (broadcast float4 per (kb,g4)), in-lane max over 16
    float p[16];
    float mx = -1e30f;
#pragma unroll
    for (int kb = 0; kb < 4; ++kb) {
      const f32x4 mv = ((const f32x4*)Ms)[kb * 4 + g4];
#pragma unroll
      for (int rr = 0; rr < 4; ++rr) {
        const float v = st[kb][rr] * SC2 + mv[rr];
        p[kb * 4 + rr] = v;
        mx = fmaxf(mx, v);
      }
    }
    mx = fmaxf(mx, __shfl_xor(mx, 16));
    mx = fmaxf(mx, __shfl_xor(mx, 32));
    const float mnew = fmaxf(mrun, mx);
    const float corr = exp2f(mrun - mnew);
    float ps = 0.f;
#pragma unroll
    for (int i = 0; i < 16; ++i) {
      const float e = exp2f(p[i] - mnew);
      p[i] = e;
      ps += e;
    }
    ps += __shfl_xor(ps, 16);
    ps += __shfl_xor(ps, 32);
    lrun = lrun * corr + ps;
    mrun = mnew;

    // redistribute corr (q=fr layout) to accumulator layout (q = 4*g4+rr)
#pragma unroll
    for (int rr = 0; rr < 4; ++rr) {
      const float cs = __shfl(corr, srcq + rr);
      accO[0][rr] *= cs;
      accO[1][rr] *= cs;
    }

    // write P rows: lane writes 4 shorts per kb at k = kb*16 + g4*4, XOR-swz
#pragma unroll
    for (int kb = 0; kb < 4; ++kb) {
      ushort4 w4;
      w4.x = f2bu(p[kb * 4 + 0]);
      w4.y = f2bu(p[kb * 4 + 1]);
      w4.z = f2bu(p[kb * 4 + 2]);
      w4.w = f2bu(p[kb * 4 + 3]);
      *(ushort4*)&Ps[wv * 1024 + fr * 64 + ((kb * 16 + g4 * 4) ^ f8)] = w4;
    }

    // PV: O[q][d] += P[16q x 32k] @ V[32k x 16d], per-wave (no barrier)
#pragma unroll
    for (int kk = 0; kk < 2; ++kk) {
      const short8 pa = *(const short8*)
          &Ps[wv * 1024 + fr * 64 + ((kk * 32 + g4 * 8) ^ f8)];
#pragma unroll
      for (int df = 0; df < 2; ++df) {
        const short8 vb = *(const short8*)
            &Vs[(df * 16 + fr) * 64 + ((kk * 32 + g4 * 8) ^ f8)];
        accO[df] = __builtin_amdgcn_mfma_f32_16x16x32_bf16(
            pa, vb, accO[df], 0, 0, 0);
      }
    }
    __syncthreads();
  }

  const float inv = 1.0f / lrun;   // q = fr layout
#pragma unroll
  for (int rr = 0; rr < 4; ++rr) {
    const float iv = __shfl(inv, srcq + rr);
    const int q = q0 + wv * 16 + g4 * 4 + rr;
    const size_t orow = ((size_t)b * S_LEN + q) * H_DIM + h * 32;
    Ob[orow + fr]      = __float2bfloat16(accO[0][rr] * iv);
    Ob[orow + 16 + fr] = __float2bfloat16(accO[1][rr] * iv);
  }
}

// ---------------- final layernorm (no residual, fp32 only) ----------------
__global__ __launch_bounds__(256) void lnf_kernel(
    float* __restrict__ X, const float* __restrict__ g,
    const float* __restrict__ bt) {
  const int tid = threadIdx.x, wv = tid >> 6, ln = tid & 63;
  const size_t tok = (size_t)blockIdx.x * 4 + wv;
  float4 v = ((const float4*)X)[tok * 64 + ln];
  float s = v.x + v.y + v.z + v.w;
#pragma unroll
  for (int off = 1; off < 64; off <<= 1) s += __shfl_xor(s, off);
  const float mu = s * (1.0f / 256.0f);
  const float dx = v.x - mu, dy = v.y - mu, dz = v.z - mu, dw = v.w - mu;
  float sq = dx * dx + dy * dy + dz * dz + dw * dw;
#pragma unroll
  for (int off = 1; off < 64; off <<= 1) sq += __shfl_xor(sq, off);
  const float rstd = rsqrtf(sq * (1.0f / 256.0f) + 1e-5f);
  const float4 gg = ((const float4*)g)[ln];
  const float4 bb = ((const float4*)bt)[ln];
  float4 o;
  o.x = dx * rstd * gg.x + bb.x;
  o.y = dy * rstd * gg.y + bb.y;
  o.z = dz * rstd * gg.z + bb.z;
  o.w = dw * rstd * gg.w + bb.w;
  ((float4*)X)[tok * 64 + ln] = o;
}

// ---------------- pooling: 1024 threads, s-loop split 4 ways ---------------
__global__ __launch_bounds__(1024) void pool_kernel(
    const float* __restrict__ X, const int* __restrict__ amask,
    const int* __restrict__ sub_idx, const int* __restrict__ sub_cnt,
    const int* __restrict__ obj_idx, const int* __restrict__ obj_cnt,
    float* __restrict__ feat) {
  const int b = blockIdx.x;
  const int tid = threadIdx.x;
  const int c = tid & 255, sl = tid >> 8;   // channel, s-slice
  const float* xb = X + (size_t)b * S_LEN * H_DIM;
  __shared__ float part[4][256];
  __shared__ int cnts[4];
  float s = 0.f;
  int cnt = 0;
  for (int k = sl * 128; k < sl * 128 + 128; ++k) {
    if (amask[b * S_LEN + k]) {
      s += xb[(size_t)k * H_DIM + c];
      ++cnt;
    }
  }
  part[sl][c] = s;
  if (c == 0) cnts[sl] = cnt;
  __syncthreads();
  if (sl == 0) {
    const float tot = part[0][c] + part[1][c] + part[2][c] + part[3][c];
    const float len = (float)(cnts[0] + cnts[1] + cnts[2] + cnts[3]);
    feat[(size_t)b * 768 + 512 + c] = tot / len;   // lengths >= 16
  } else if (sl == 1) {
    const int cc = sub_cnt[b];
    float s2 = 0.f;
    for (int j = 0; j < cc; ++j)
      s2 += xb[(size_t)sub_idx[b * 8 + j] * H_DIM + c];
    feat[(size_t)b * 768 + c] = (cc > 0) ? s2 / (float)cc : 0.f;
  } else if (sl == 2) {
    const int cc = obj_cnt[b];
    float s2 = 0.f;
    for (int j = 0; j < cc; ++j)
      s2 += xb[(size_t)obj_idx[b * 8 + j] * H_DIM + c];
    feat[(size_t)b * 768 + 256 + c] = (cc > 0) ? s2 / (float)cc : 0.f;
  }
}

// ---------------- classifier ----------------
__global__ __launch_bounds__(256) void cls_kernel(
    const float* __restrict__ feat, const float* __restrict__ mW1,
    const float* __restrict__ mb1, const float* __restrict__ mW2,
    const float* __restrict__ mb2, float* __restrict__ out) {
  const int b = blockIdx.x, t = threadIdx.x;
  __shared__ float fs[768];
  __shared__ float hid[256];
#pragma unroll
  for (int e = 0; e < 3; ++e) fs[t + e * 256] = feat[(size_t)b * 768 + t + e * 256];
  __syncthreads();
  float acc = mb1[t];
  for (int k = 0; k < 768; ++k) acc += fs[k] * mW1[(size_t)k * 256 + t];
  hid[t] = fmaxf(acc, 0.f);
  __syncthreads();
  if (t < 25) {
    float o = mb2[t];
    for (int j = 0; j < 256; ++j) o += hid[j] * mW2[j * 25 + t];
    out[b * 25 + t] = o;
  }
}

// ---------------------------------------------------------------------------
extern "C" void kernel_launch(void* const* d_in, const int* in_sizes, int n_in,
                              void* d_out, int out_size, void* d_ws, size_t ws_size,
                              hipStream_t stream) {
  const int*   input_ids = (const int*)d_in[0];
  const int*   amask     = (const int*)d_in[1];
  const int*   sub_idx   = (const int*)d_in[2];
  const int*   sub_cnt   = (const int*)d_in[3];
  const int*   obj_idx   = (const int*)d_in[4];
  const int*   obj_cnt   = (const int*)d_in[5];
  const float* emb  = (const float*)d_in[6];
  const float* Wqkv = (const float*)d_in[7];
  const float* bqkv = (const float*)d_in[8];
  const float* Wo   = (const float*)d_in[9];
  const float* bo   = (const float*)d_in[10];
  const float* ln1g = (const float*)d_in[11];
  const float* ln1b = (const float*)d_in[12];
  const float* ln2g = (const float*)d_in[13];
  const float* ln2b = (const float*)d_in[14];
  const float* W1   = (const float*)d_in[15];
  const float* b1   = (const float*)d_in[16];
  const float* W2   = (const float*)d_in[17];
  const float* b2   = (const float*)d_in[18];
  const float* lnfg = (const float*)d_in[19];
  const float* lnfb = (const float*)d_in[20];
  const float* mW1  = (const float*)d_in[21];
  const float* mb1  = (const float*)d_in[22];
  const float* mW2  = (const float*)d_in[23];
  const float* mb2  = (const float*)d_in[24];
  float* out = (float*)d_out;

  // workspace layout (bytes)
  char* w = (char*)d_ws;
  float* X    = (float*)w;                         w += (size_t)NTOK * 256 * 4;  // 33.5MB
  bf16*  Xb   = (bf16*)w;                          w += (size_t)NTOK * 256 * 2;  // 16.8MB
  bf16*  QKVb = (bf16*)w;                          w += (size_t)NTOK * 768 * 2;  // 50.3MB
  bf16*  Vtg  = (bf16*)w;                          w += (size_t)NTOK * 256 * 2;  // 16.8MB
  bf16*  Ob   = (bf16*)w;                          w += (size_t)NTOK * 256 * 2;  // 16.8MB
  bf16*  Wqkvt= (bf16*)w;                          w += (size_t)4 * 768 * 256 * 2;
  bf16*  Wot  = (bf16*)w;                          w += (size_t)4 * 256 * 256 * 2;
  bf16*  W1t  = (bf16*)w;                          w += (size_t)4 * 1024 * 256 * 2;
  bf16*  W2t  = (bf16*)w;                          w += (size_t)4 * 256 * 1024 * 2;
  float* feat = (float*)w;                         w += (size_t)64 * 768 * 4;
  bf16*  Hb   = QKVb;   // aliases [QKVb, Vtg] = 67.1MB >= 32768*1024*2

  tcast_kernel<<<dim3(24, 8, 4), 256, 0, stream>>>(Wqkv, Wqkvt, 256, 768);
  tcast_kernel<<<dim3(8, 8, 4), 256, 0, stream>>>(Wo, Wot, 256, 256);
  tcast_kernel<<<dim3(32, 8, 4), 256, 0, stream>>>(W1, W1t, 256, 1024);
  tcast_kernel<<<dim3(8, 32, 4), 256, 0, stream>>>(W2, W2t, 1024, 256);

  embed_kernel<<<8192, 256, 0, stream>>>(input_ids, emb, X, Xb);

  for (int l = 0; l < 4; ++l) {
    const bf16* Wqkvt_l = Wqkvt + (size_t)l * 768 * 256;
    const bf16* Wot_l   = Wot + (size_t)l * 256 * 256;
    const bf16* W1t_l   = W1t + (size_t)l * 1024 * 256;
    const bf16* W2t_l   = W2t + (size_t)l * 256 * 1024;

    hgemm_kernel<2, false><<<dim3(6, 256), 256, 0, stream>>>(
        Xb, Wqkvt_l, bqkv + (size_t)l * 768, nullptr, QKVb, Vtg, NTOK, 768, 256);
    attn_mfma_kernel<<<dim3(8, 8, 64), 256, 0, stream>>>(QKVb, Vtg, amask, Ob);
    hgemm_ln_kernel<<<512, 256, 0, stream>>>(
        Ob, Wot_l, bo + (size_t)l * 256, X, Xb,
        ln1g + l * 256, ln1b + l * 256, 256);
    hgemm_kernel<1, true><<<dim3(8, 256), 256, 0, stream>>>(
        Xb, W1t_l, b1 + (size_t)l * 1024, nullptr, Hb, nullptr, NTOK, 1024, 256);
    hgemm_ln_kernel<<<512, 256, 0, stream>>>(
        Hb, W2t_l, b2 + (size_t)l * 256, X, Xb,
        ln2g + l * 256, ln2b + l * 256, 1024);
  }
  lnf_kernel<<<8192, 256, 0, stream>>>(X, lnfg, lnfb);
  pool_kernel<<<64, 1024, 0, stream>>>(X, amask, sub_idx, sub_cnt,
                                       obj_idx, obj_cnt, feat);
  cls_kernel<<<64, 256, 0, stream>>>(feat, mW1, mb1, mW2, mb2, out);
}

// Round 5
// 885.920 us; speedup vs baseline: 5.3262x; 1.0697x over previous
//
#include <hip/hip_runtime.h>
#include <hip/hip_bf16.h>

// ---------------------------------------------------------------------------
// CLUTRR transformer: B=64 S=512 H=256 L=4 NH=8 DH=32 F=1024 V=50265 K=8 R=25
// Round 5: prefix-mask tile skipping in attention (exact: masked tiles give
// p == 0.0 in fp32), mask-FMA only on boundary tile. Rest unchanged from R4.
// ---------------------------------------------------------------------------

typedef __hip_bfloat16 bf16;
typedef __attribute__((ext_vector_type(8))) short short8;
typedef __attribute__((ext_vector_type(4))) float f32x4;

#define S_LEN 512
#define H_DIM 256
#define NTOK  32768      // B*S

__device__ __forceinline__ void gload_lds16(const void* g, void* l) {
  __builtin_amdgcn_global_load_lds(
      (const __attribute__((address_space(1))) unsigned int*)g,
      (__attribute__((address_space(3))) unsigned int*)l, 16, 0, 0);
}

__device__ __forceinline__ unsigned short f2bu(float x) {
  bf16 t = __float2bfloat16(x);
  return *reinterpret_cast<unsigned short*>(&t);
}

// ---------------- per-batch valid-tile count: ntiles[b] = ceil(len/64) ------
__global__ __launch_bounds__(64) void lens_kernel(
    const int* __restrict__ amask, int* __restrict__ ntiles) {
  const int b = blockIdx.x, t = threadIdx.x;
  int c = 0;
#pragma unroll
  for (int i = 0; i < 8; ++i) c += amask[b * S_LEN + t + i * 64];
#pragma unroll
  for (int off = 1; off < 64; off <<= 1) c += __shfl_xor(c, off);
  if (t == 0) ntiles[b] = (c + 63) >> 6;
}

// ---------------- weight cast + transpose: out[N][K] = bf16(in[K][N]) -------
__global__ __launch_bounds__(256) void tcast_kernel(
    const float* __restrict__ in, bf16* __restrict__ out, int K, int N) {
  const int l = blockIdx.z;
  in  += (size_t)l * K * N;
  out += (size_t)l * K * N;
  __shared__ float t[32][33];
  const int n0 = blockIdx.x * 32, k0 = blockIdx.y * 32;
  const int c = threadIdx.x & 31, r = threadIdx.x >> 5;
#pragma unroll
  for (int rr = r; rr < 32; rr += 8)
    t[rr][c] = in[(size_t)(k0 + rr) * N + n0 + c];
  __syncthreads();
#pragma unroll
  for (int rr = r; rr < 32; rr += 8)
    out[(size_t)(n0 + rr) * K + k0 + c] = __float2bfloat16(t[c][rr]);
}

// ---------------- embedding gather: X fp32 + Xb bf16 ----------------
__global__ __launch_bounds__(256) void embed_kernel(
    const int* __restrict__ ids, const float* __restrict__ emb,
    float* __restrict__ X, bf16* __restrict__ Xb) {
  size_t i4 = (size_t)blockIdx.x * 256 + threadIdx.x;   // float4 index
  int tok = (int)(i4 >> 6);
  int d4  = (int)(i4 & 63);
  float4 v = *(const float4*)&emb[(size_t)ids[tok] * H_DIM + d4 * 4];
  *(float4*)&X[i4 * 4] = v;
  ushort4 pk;
  pk.x = f2bu(v.x); pk.y = f2bu(v.y); pk.z = f2bu(v.z); pk.w = f2bu(v.w);
  *(ushort4*)&Xb[i4 * 4] = pk;
}

// ---------------- bf16 MFMA GEMM: C = A[M,K] @ Bt[N,K]^T + bias -------------
// MODE 1: bf16 out Cb (w/ optional relu);
// MODE 2: QKV split — n<512 -> Cb[m][768], n>=512 -> Vt[b,h,d,s^swz] bf16.
template<int MODE, bool RELU>
__global__ __launch_bounds__(256) void hgemm_kernel(
    const bf16* __restrict__ A, const bf16* __restrict__ Bt,
    const float* __restrict__ bias, float* __restrict__ Cf,
    bf16* __restrict__ Cb, bf16* __restrict__ Vt,
    int M, int N, int K) {
  __shared__ __align__(16) bf16 As[4096];   // [128][32]
  __shared__ __align__(16) bf16 Bs[4096];   // [128][32]
  const int tid = threadIdx.x;
  const int wv = tid >> 6, ln = tid & 63;
  const int fr = ln & 15, g4 = ln >> 4;
  const int wr = wv >> 1, wc = wv & 1;
  const int m0 = blockIdx.y * 128, n0 = blockIdx.x * 128;
  const int lr = tid >> 2, lk = (tid & 3) * 8;   // staging row / k-offset

  f32x4 acc[4][4];
#pragma unroll
  for (int i = 0; i < 4; ++i)
#pragma unroll
    for (int j = 0; j < 4; ++j)
      acc[i][j] = (f32x4){0.f, 0.f, 0.f, 0.f};

  for (int k0 = 0; k0 < K; k0 += 32) {
    gload_lds16(A  + (size_t)(m0 + lr) * K + k0 + lk,       &As[wv * 512]);
    gload_lds16(A  + (size_t)(m0 + 64 + lr) * K + k0 + lk,  &As[2048 + wv * 512]);
    gload_lds16(Bt + (size_t)(n0 + lr) * K + k0 + lk,       &Bs[wv * 512]);
    gload_lds16(Bt + (size_t)(n0 + 64 + lr) * K + k0 + lk,  &Bs[2048 + wv * 512]);
    __syncthreads();
    short8 af[4], bfv[4];
#pragma unroll
    for (int i = 0; i < 4; ++i)
      af[i] = *(const short8*)&As[(wr * 64 + i * 16 + fr) * 32 + g4 * 8];
#pragma unroll
    for (int j = 0; j < 4; ++j)
      bfv[j] = *(const short8*)&Bs[(wc * 64 + j * 16 + fr) * 32 + g4 * 8];
#pragma unroll
    for (int i = 0; i < 4; ++i)
#pragma unroll
      for (int j = 0; j < 4; ++j)
        acc[i][j] = __builtin_amdgcn_mfma_f32_16x16x32_bf16(
            af[i], bfv[j], acc[i][j], 0, 0, 0);
    __syncthreads();
  }

  const int crow = g4 * 4, ccol = fr;
#pragma unroll
  for (int j = 0; j < 4; ++j) {
    const int n = n0 + wc * 64 + j * 16 + ccol;
    const float bv = bias[n];
#pragma unroll
    for (int i = 0; i < 4; ++i) {
      const int mbase = m0 + wr * 64 + i * 16 + crow;
#pragma unroll
      for (int r = 0; r < 4; ++r) {
        float o = acc[i][j][r] + bv;
        if (RELU) o = fmaxf(o, 0.f);
        const int m = mbase + r;
        if (MODE == 1) {
          Cb[(size_t)m * N + n] = __float2bfloat16(o);
        } else {
          if (n < 512) {
            Cb[(size_t)m * 768 + n] = __float2bfloat16(o);
          } else {
            const int hd = n - 512, hh = hd >> 5, dd = hd & 31;
            const int bb = m >> 9, ss = m & 511;
            const int ssw = (ss & ~63) | ((ss & 63) ^ ((dd & 7) << 3));
            Vt[(((size_t)bb * 8 + hh) * 32 + dd) * 512 + ssw] =
                __float2bfloat16(o);
          }
        }
      }
    }
  }
}

// ---------------- fused GEMM + bias + residual + LayerNorm + bf16 ----------
__global__ __launch_bounds__(256) void hgemm_ln_kernel(
    const bf16* __restrict__ A, const bf16* __restrict__ Bt,
    const float* __restrict__ bias, float* __restrict__ X,
    bf16* __restrict__ Xb, const float* __restrict__ g,
    const float* __restrict__ bt, int K) {
  __shared__ __align__(16) bf16 As[2048];   // [64][32]
  __shared__ __align__(16) bf16 Bs[8192];   // [256][32]
  __shared__ float rsum[4][64];
  __shared__ float rsq[4][64];
  const int tid = threadIdx.x;
  const int wv = tid >> 6;
  const int ln = tid & 63;
  const int fr = ln & 15, g4 = ln >> 4;
  const int m0 = blockIdx.x * 64;

  f32x4 acc[4][4];   // [row frag i][col frag j]
#pragma unroll
  for (int i = 0; i < 4; ++i)
#pragma unroll
    for (int j = 0; j < 4; ++j)
      acc[i][j] = (f32x4){0.f, 0.f, 0.f, 0.f};

  for (int k0 = 0; k0 < K; k0 += 32) {
    gload_lds16(A + (size_t)(m0 + (tid >> 2)) * K + k0 + (tid & 3) * 8,
                &As[wv * 512]);
#pragma unroll
    for (int e = 0; e < 4; ++e) {
      const int vt = e * 256 + tid;
      gload_lds16(Bt + (size_t)(vt >> 2) * K + k0 + (vt & 3) * 8,
                  &Bs[e * 2048 + wv * 512]);
    }
    __syncthreads();
    short8 af[4], bfv[4];
#pragma unroll
    for (int i = 0; i < 4; ++i)
      af[i] = *(const short8*)&As[(i * 16 + fr) * 32 + g4 * 8];
#pragma unroll
    for (int j = 0; j < 4; ++j)
      bfv[j] = *(const short8*)&Bs[(wv * 64 + j * 16 + fr) * 32 + g4 * 8];
#pragma unroll
    for (int i = 0; i < 4; ++i)
#pragma unroll
      for (int j = 0; j < 4; ++j)
        acc[i][j] = __builtin_amdgcn_mfma_f32_16x16x32_bf16(
            af[i], bfv[j], acc[i][j], 0, 0, 0);
    __syncthreads();
  }

  float gj[4], bj[4], bsj[4];
#pragma unroll
  for (int j = 0; j < 4; ++j) {
    const int n = wv * 64 + j * 16 + fr;
    gj[j] = g[n]; bj[j] = bt[n]; bsj[j] = bias[n];
  }
#pragma unroll
  for (int i = 0; i < 4; ++i) {
#pragma unroll
    for (int r = 0; r < 4; ++r) {
      const int m = m0 + i * 16 + g4 * 4 + r;
#pragma unroll
      for (int j = 0; j < 4; ++j)
        acc[i][j][r] += bsj[j] + X[(size_t)m * 256 + wv * 64 + j * 16 + fr];
    }
  }
#pragma unroll
  for (int i = 0; i < 4; ++i) {
#pragma unroll
    for (int r = 0; r < 4; ++r) {
      float sp = acc[i][0][r] + acc[i][1][r] + acc[i][2][r] + acc[i][3][r];
      float qp = acc[i][0][r] * acc[i][0][r] + acc[i][1][r] * acc[i][1][r] +
                 acc[i][2][r] * acc[i][2][r] + acc[i][3][r] * acc[i][3][r];
#pragma unroll
      for (int off = 1; off < 16; off <<= 1) {
        sp += __shfl_xor(sp, off);
        qp += __shfl_xor(qp, off);
      }
      if (fr == 0) {
        const int ri = i * 16 + g4 * 4 + r;
        rsum[wv][ri] = sp;
        rsq[wv][ri] = qp;
      }
    }
  }
  __syncthreads();
#pragma unroll
  for (int i = 0; i < 4; ++i) {
#pragma unroll
    for (int r = 0; r < 4; ++r) {
      const int ri = i * 16 + g4 * 4 + r;
      const float tot = rsum[0][ri] + rsum[1][ri] + rsum[2][ri] + rsum[3][ri];
      const float tq = rsq[0][ri] + rsq[1][ri] + rsq[2][ri] + rsq[3][ri];
      const float mu = tot * (1.0f / 256.0f);
      const float var = tq * (1.0f / 256.0f) - mu * mu;
      const float rstd = rsqrtf(var + 1e-5f);
      const int m = m0 + ri;
#pragma unroll
      for (int j = 0; j < 4; ++j) {
        const float o = (acc[i][j][r] - mu) * rstd * gj[j] + bj[j];
        const size_t idx = (size_t)m * 256 + wv * 64 + j * 16 + fr;
        X[idx] = o;
        Xb[idx] = __float2bfloat16(o);
      }
    }
  }
}

// ---------------- bf16 MFMA flash attention (swapped QK^T, tile skip) -------
// QKVb: [32768][768] bf16 (Q cols 0-255, K cols 256-511)
// Vt:   [(b*8+h)*32+d][512] bf16, s pre-swizzled: s' = s ^ ((d&7)<<3) in 64-blk
// Ob:   [32768][256] bf16
// Prefix mask: only ntiles[b] k-tiles contribute; masked tiles give p == 0
// exactly in fp32, so skipping them is bit-equivalent. Mask bias applied only
// on the last (boundary) tile; earlier tiles are fully valid.
__global__ __launch_bounds__(256) void attn_mfma_kernel(
    const bf16* __restrict__ QKVb, const bf16* __restrict__ Vt,
    const int* __restrict__ amask, const int* __restrict__ ntiles,
    bf16* __restrict__ Ob) {
  const int b = blockIdx.z, h = blockIdx.y, q0 = blockIdx.x * 64;
  const int tid = threadIdx.x;
  const int wv = tid >> 6, ln = tid & 63;
  const int fr = ln & 15, g4 = ln >> 4;
  const int f8 = (fr & 7) << 3;
  const int bh32 = (b * 8 + h) * 32;
  __shared__ __align__(16) bf16 Qs[2048];   // [64][32]
  __shared__ __align__(16) bf16 Ks[2048];   // [64][32]
  __shared__ __align__(16) bf16 Vs[2048];   // [32 d][64 k] (swizzled)
  __shared__ __align__(16) bf16 Ps[4096];   // per-wave [16 q][64 k] (swizzled)
  __shared__ __align__(16) float Ms[64];

  gload_lds16(QKVb + (size_t)(b * S_LEN + q0 + (tid >> 2)) * 768 + h * 32 +
                  (tid & 3) * 8,
              &Qs[wv * 512]);
  __syncthreads();
  // B-operand fragment of Q^T: lane holds col q=fr, d-rows g4*8..+7. Hoisted.
  const short8 qb = *(const short8*)&Qs[(wv * 16 + fr) * 32 + g4 * 8];

  f32x4 accO[2];
  accO[0] = (f32x4){0.f, 0.f, 0.f, 0.f};
  accO[1] = (f32x4){0.f, 0.f, 0.f, 0.f};
  float mrun = -1e30f, lrun = 0.f;   // per-lane state for q = fr (log2 domain)
  // 1/sqrt(32) * log2(e)
  const float SC2 = 0.17677669529663687f * 1.4426950408889634f;
  const int srcq = 20 * g4;   // shfl src base: lane 16*g4 + (4*g4 + rr)
  const int nt = ntiles[b];

  for (int kt = 0; kt < nt; ++kt) {
    const int k0 = kt * 64;
    const bool bnd = (kt == nt - 1);
    gload_lds16(QKVb + (size_t)(b * S_LEN + k0 + (tid >> 2)) * 768 + 256 +
                    h * 32 + (tid & 3) * 8,
                &Ks[wv * 512]);
    gload_lds16(Vt + (size_t)(bh32 + (tid >> 3)) * 512 + k0 + (tid & 7) * 8,
                &Vs[wv * 512]);
    if (bnd && tid < 64)
      Ms[tid] = (amask[b * S_LEN + k0 + tid] != 0) ? 0.f : -1e9f;
    __syncthreads();

    // S^T = K @ Q^T : 4 MFMAs cover 64 k x 16 q
    f32x4 st[4];
#pragma unroll
    for (int kb = 0; kb < 4; ++kb) {
      const short8 kf = *(const short8*)&Ks[(kb * 16 + fr) * 32 + g4 * 8];
      f32x4 z = (f32x4){0.f, 0.f, 0.f, 0.f};
      st[kb] = __builtin_amdgcn_mfma_f32_16x16x32_bf16(kf, qb, z, 0, 0, 0);
    }

    // scale (+ mask on boundary tile only), in-lane max over 16
    float p[16];
    float mx = -1e30f;
    if (bnd) {
#pragma unroll
      for (int kb = 0; kb < 4; ++kb) {
        const f32x4 mv = ((const f32x4*)Ms)[kb * 4 + g4];
#pragma unroll
        for (int rr = 0; rr < 4; ++rr) {
          const float v = st[kb][rr] * SC2 + mv[rr];
          p[kb * 4 + rr] = v;
          mx = fmaxf(mx, v);
        }
      }
    } else {
#pragma unroll
      for (int kb = 0; kb < 4; ++kb) {
#pragma unroll
        for (int rr = 0; rr < 4; ++rr) {
          const float v = st[kb][rr] * SC2;
          p[kb * 4 + rr] = v;
          mx = fmaxf(mx, v);
        }
      }
    }
    mx = fmaxf(mx, __shfl_xor(mx, 16));
    mx = fmaxf(mx, __shfl_xor(mx, 32));
    const float mnew = fmaxf(mrun, mx);
    const float corr = exp2f(mrun - mnew);
    float ps = 0.f;
#pragma unroll
    for (int i = 0; i < 16; ++i) {
      const float e = exp2f(p[i] - mnew);
      p[i] = e;
      ps += e;
    }
    ps += __shfl_xor(ps, 16);
    ps += __shfl_xor(ps, 32);
    lrun = lrun * corr + ps;
    mrun = mnew;

    // redistribute corr (q=fr layout) to accumulator layout (q = 4*g4+rr)
#pragma unroll
    for (int rr = 0; rr < 4; ++rr) {
      const float cs = __shfl(corr, srcq + rr);
      accO[0][rr] *= cs;
      accO[1][rr] *= cs;
    }

    // write P rows: lane writes 4 shorts per kb at k = kb*16 + g4*4, XOR-swz
#pragma unroll
    for (int kb = 0; kb < 4; ++kb) {
      ushort4 w4;
      w4.x = f2bu(p[kb * 4 + 0]);
      w4.y = f2bu(p[kb * 4 + 1]);
      w4.z = f2bu(p[kb * 4 + 2]);
      w4.w = f2bu(p[kb * 4 + 3]);
      *(ushort4*)&Ps[wv * 1024 + fr * 64 + ((kb * 16 + g4 * 4) ^ f8)] = w4;
    }

    // PV: O[q][d] += P[16q x 32k] @ V[32k x 16d], per-wave (no barrier)
#pragma unroll
    for (int kk = 0; kk < 2; ++kk) {
      const short8 pa = *(const short8*)
          &Ps[wv * 1024 + fr * 64 + ((kk * 32 + g4 * 8) ^ f8)];
#pragma unroll
      for (int df = 0; df < 2; ++df) {
        const short8 vb = *(const short8*)
            &Vs[(df * 16 + fr) * 64 + ((kk * 32 + g4 * 8) ^ f8)];
        accO[df] = __builtin_amdgcn_mfma_f32_16x16x32_bf16(
            pa, vb, accO[df], 0, 0, 0);
      }
    }
    __syncthreads();
  }

  const float inv = 1.0f / lrun;   // q = fr layout
#pragma unroll
  for (int rr = 0; rr < 4; ++rr) {
    const float iv = __shfl(inv, srcq + rr);
    const int q = q0 + wv * 16 + g4 * 4 + rr;
    const size_t orow = ((size_t)b * S_LEN + q) * H_DIM + h * 32;
    Ob[orow + fr]      = __float2bfloat16(accO[0][rr] * iv);
    Ob[orow + 16 + fr] = __float2bfloat16(accO[1][rr] * iv);
  }
}

// ---------------- final layernorm (no residual, fp32 only) ----------------
__global__ __launch_bounds__(256) void lnf_kernel(
    float* __restrict__ X, const float* __restrict__ g,
    const float* __restrict__ bt) {
  const int tid = threadIdx.x, wv = tid >> 6, ln = tid & 63;
  const size_t tok = (size_t)blockIdx.x * 4 + wv;
  float4 v = ((const float4*)X)[tok * 64 + ln];
  float s = v.x + v.y + v.z + v.w;
#pragma unroll
  for (int off = 1; off < 64; off <<= 1) s += __shfl_xor(s, off);
  const float mu = s * (1.0f / 256.0f);
  const float dx = v.x - mu, dy = v.y - mu, dz = v.z - mu, dw = v.w - mu;
  float sq = dx * dx + dy * dy + dz * dz + dw * dw;
#pragma unroll
  for (int off = 1; off < 64; off <<= 1) sq += __shfl_xor(sq, off);
  const float rstd = rsqrtf(sq * (1.0f / 256.0f) + 1e-5f);
  const float4 gg = ((const float4*)g)[ln];
  const float4 bb = ((const float4*)bt)[ln];
  float4 o;
  o.x = dx * rstd * gg.x + bb.x;
  o.y = dy * rstd * gg.y + bb.y;
  o.z = dz * rstd * gg.z + bb.z;
  o.w = dw * rstd * gg.w + bb.w;
  ((float4*)X)[tok * 64 + ln] = o;
}

// ---------------- pooling: 1024 threads, s-loop split 4 ways ---------------
__global__ __launch_bounds__(1024) void pool_kernel(
    const float* __restrict__ X, const int* __restrict__ amask,
    const int* __restrict__ sub_idx, const int* __restrict__ sub_cnt,
    const int* __restrict__ obj_idx, const int* __restrict__ obj_cnt,
    float* __restrict__ feat) {
  const int b = blockIdx.x;
  const int tid = threadIdx.x;
  const int c = tid & 255, sl = tid >> 8;   // channel, s-slice
  const float* xb = X + (size_t)b * S_LEN * H_DIM;
  __shared__ float part[4][256];
  __shared__ int cnts[4];
  float s = 0.f;
  int cnt = 0;
  for (int k = sl * 128; k < sl * 128 + 128; ++k) {
    if (amask[b * S_LEN + k]) {
      s += xb[(size_t)k * H_DIM + c];
      ++cnt;
    }
  }
  part[sl][c] = s;
  if (c == 0) cnts[sl] = cnt;
  __syncthreads();
  if (sl == 0) {
    const float tot = part[0][c] + part[1][c] + part[2][c] + part[3][c];
    const float len = (float)(cnts[0] + cnts[1] + cnts[2] + cnts[3]);
    feat[(size_t)b * 768 + 512 + c] = tot / len;   // lengths >= 16
  } else if (sl == 1) {
    const int cc = sub_cnt[b];
    float s2 = 0.f;
    for (int j = 0; j < cc; ++j)
      s2 += xb[(size_t)sub_idx[b * 8 + j] * H_DIM + c];
    feat[(size_t)b * 768 + c] = (cc > 0) ? s2 / (float)cc : 0.f;
  } else if (sl == 2) {
    const int cc = obj_cnt[b];
    float s2 = 0.f;
    for (int j = 0; j < cc; ++j)
      s2 += xb[(size_t)obj_idx[b * 8 + j] * H_DIM + c];
    feat[(size_t)b * 768 + 256 + c] = (cc > 0) ? s2 / (float)cc : 0.f;
  }
}

// ---------------- classifier ----------------
__global__ __launch_bounds__(256) void cls_kernel(
    const float* __restrict__ feat, const float* __restrict__ mW1,
    const float* __restrict__ mb1, const float* __restrict__ mW2,
    const float* __restrict__ mb2, float* __restrict__ out) {
  const int b = blockIdx.x, t = threadIdx.x;
  __shared__ float fs[768];
  __shared__ float hid[256];
#pragma unroll
  for (int e = 0; e < 3; ++e) fs[t + e * 256] = feat[(size_t)b * 768 + t + e * 256];
  __syncthreads();
  float acc = mb1[t];
  for (int k = 0; k < 768; ++k) acc += fs[k] * mW1[(size_t)k * 256 + t];
  hid[t] = fmaxf(acc, 0.f);
  __syncthreads();
  if (t < 25) {
    float o = mb2[t];
    for (int j = 0; j < 256; ++j) o += hid[j] * mW2[j * 25 + t];
    out[b * 25 + t] = o;
  }
}

// ---------------------------------------------------------------------------
extern "C" void kernel_launch(void* const* d_in, const int* in_sizes, int n_in,
                              void* d_out, int out_size, void* d_ws, size_t ws_size,
                              hipStream_t stream) {
  const int*   input_ids = (const int*)d_in[0];
  const int*   amask     = (const int*)d_in[1];
  const int*   sub_idx   = (const int*)d_in[2];
  const int*   sub_cnt   = (const int*)d_in[3];
  const int*   obj_idx   = (const int*)d_in[4];
  const int*   obj_cnt   = (const int*)d_in[5];
  const float* emb  = (const float*)d_in[6];
  const float* Wqkv = (const float*)d_in[7];
  const float* bqkv = (const float*)d_in[8];
  const float* Wo   = (const float*)d_in[9];
  const float* bo   = (const float*)d_in[10];
  const float* ln1g = (const float*)d_in[11];
  const float* ln1b = (const float*)d_in[12];
  const float* ln2g = (const float*)d_in[13];
  const float* ln2b = (const float*)d_in[14];
  const float* W1   = (const float*)d_in[15];
  const float* b1   = (const float*)d_in[16];
  const float* W2   = (const float*)d_in[17];
  const float* b2   = (const float*)d_in[18];
  const float* lnfg = (const float*)d_in[19];
  const float* lnfb = (const float*)d_in[20];
  const float* mW1  = (const float*)d_in[21];
  const float* mb1  = (const float*)d_in[22];
  const float* mW2  = (const float*)d_in[23];
  const float* mb2  = (const float*)d_in[24];
  float* out = (float*)d_out;

  // workspace layout (bytes)
  char* w = (char*)d_ws;
  float* X    = (float*)w;                         w += (size_t)NTOK * 256 * 4;  // 33.5MB
  bf16*  Xb   = (bf16*)w;                          w += (size_t)NTOK * 256 * 2;  // 16.8MB
  bf16*  QKVb = (bf16*)w;                          w += (size_t)NTOK * 768 * 2;  // 50.3MB
  bf16*  Vtg  = (bf16*)w;                          w += (size_t)NTOK * 256 * 2;  // 16.8MB
  bf16*  Ob   = (bf16*)w;                          w += (size_t)NTOK * 256 * 2;  // 16.8MB
  bf16*  Wqkvt= (bf16*)w;                          w += (size_t)4 * 768 * 256 * 2;
  bf16*  Wot  = (bf16*)w;                          w += (size_t)4 * 256 * 256 * 2;
  bf16*  W1t  = (bf16*)w;                          w += (size_t)4 * 1024 * 256 * 2;
  bf16*  W2t  = (bf16*)w;                          w += (size_t)4 * 256 * 1024 * 2;
  float* feat = (float*)w;                         w += (size_t)64 * 768 * 4;
  int*   ntiles = (int*)w;                         w += 256;
  bf16*  Hb   = QKVb;   // aliases [QKVb, Vtg] = 67.1MB >= 32768*1024*2

  lens_kernel<<<64, 64, 0, stream>>>(amask, ntiles);
  tcast_kernel<<<dim3(24, 8, 4), 256, 0, stream>>>(Wqkv, Wqkvt, 256, 768);
  tcast_kernel<<<dim3(8, 8, 4), 256, 0, stream>>>(Wo, Wot, 256, 256);
  tcast_kernel<<<dim3(32, 8, 4), 256, 0, stream>>>(W1, W1t, 256, 1024);
  tcast_kernel<<<dim3(8, 32, 4), 256, 0, stream>>>(W2, W2t, 1024, 256);

  embed_kernel<<<8192, 256, 0, stream>>>(input_ids, emb, X, Xb);

  for (int l = 0; l < 4; ++l) {
    const bf16* Wqkvt_l = Wqkvt + (size_t)l * 768 * 256;
    const bf16* Wot_l   = Wot + (size_t)l * 256 * 256;
    const bf16* W1t_l   = W1t + (size_t)l * 1024 * 256;
    const bf16* W2t_l   = W2t + (size_t)l * 256 * 1024;

    hgemm_kernel<2, false><<<dim3(6, 256), 256, 0, stream>>>(
        Xb, Wqkvt_l, bqkv + (size_t)l * 768, nullptr, QKVb, Vtg, NTOK, 768, 256);
    attn_mfma_kernel<<<dim3(8, 8, 64), 256, 0, stream>>>(
        QKVb, Vtg, amask, ntiles, Ob);
    hgemm_ln_kernel<<<512, 256, 0, stream>>>(
        Ob, Wot_l, bo + (size_t)l * 256, X, Xb,
        ln1g + l * 256, ln1b + l * 256, 256);
    hgemm_kernel<1, true><<<dim3(8, 256), 256, 0, stream>>>(
        Xb, W1t_l, b1 + (size_t)l * 1024, nullptr, Hb, nullptr, NTOK, 1024, 256);
    hgemm_ln_kernel<<<512, 256, 0, stream>>>(
        Hb, W2t_l, b2 + (size_t)l * 256, X, Xb,
        ln2g + l * 256, ln2b + l * 256, 1024);
  }
  lnf_kernel<<<8192, 256, 0, stream>>>(X, lnfg, lnfb);
  pool_kernel<<<64, 1024, 0, stream>>>(X, amask, sub_idx, sub_cnt,
                                       obj_idx, obj_cnt, feat);
  cls_kernel<<<64, 256, 0, stream>>>(feat, mW1, mb1, mW2, mb2, out);
}

// Round 6
// 828.415 us; speedup vs baseline: 5.6959x; 1.0694x over previous
//
#include <hip/hip_runtime.h>
#include <hip/hip_bf16.h>

// ---------------------------------------------------------------------------
// CLUTRR transformer: B=64 S=512 H=256 L=4 NH=8 DH=32 F=1024 V=50265 K=8 R=25
// Round 6: fused finalLN+story-pool stage1 (+combine), 2-phase double-buffered
// LDS pipelines in GEMMs and attention (1 barrier per K-step).
// ---------------------------------------------------------------------------

typedef __hip_bfloat16 bf16;
typedef __attribute__((ext_vector_type(8))) short short8;
typedef __attribute__((ext_vector_type(4))) float f32x4;

#define S_LEN 512
#define H_DIM 256
#define NTOK  32768      // B*S

__device__ __forceinline__ void gload_lds16(const void* g, void* l) {
  __builtin_amdgcn_global_load_lds(
      (const __attribute__((address_space(1))) unsigned int*)g,
      (__attribute__((address_space(3))) unsigned int*)l, 16, 0, 0);
}

__device__ __forceinline__ unsigned short f2bu(float x) {
  bf16 t = __float2bfloat16(x);
  return *reinterpret_cast<unsigned short*>(&t);
}

// -------- per-batch: exact valid length + tile count --------
__global__ __launch_bounds__(64) void lens_kernel(
    const int* __restrict__ amask, int* __restrict__ ntiles,
    int* __restrict__ lenb) {
  const int b = blockIdx.x, t = threadIdx.x;
  int c = 0;
#pragma unroll
  for (int i = 0; i < 8; ++i) c += amask[b * S_LEN + t + i * 64];
#pragma unroll
  for (int off = 1; off < 64; off <<= 1) c += __shfl_xor(c, off);
  if (t == 0) {
    lenb[b] = c;
    ntiles[b] = (c + 63) >> 6;
  }
}

// -------- weight cast + transpose: out[N][K] = bf16(in[K][N]) --------
__global__ __launch_bounds__(256) void tcast_kernel(
    const float* __restrict__ in, bf16* __restrict__ out, int K, int N) {
  const int l = blockIdx.z;
  in  += (size_t)l * K * N;
  out += (size_t)l * K * N;
  __shared__ float t[32][33];
  const int n0 = blockIdx.x * 32, k0 = blockIdx.y * 32;
  const int c = threadIdx.x & 31, r = threadIdx.x >> 5;
#pragma unroll
  for (int rr = r; rr < 32; rr += 8)
    t[rr][c] = in[(size_t)(k0 + rr) * N + n0 + c];
  __syncthreads();
#pragma unroll
  for (int rr = r; rr < 32; rr += 8)
    out[(size_t)(n0 + rr) * K + k0 + c] = __float2bfloat16(t[c][rr]);
}

// -------- embedding gather: X fp32 + Xb bf16 --------
__global__ __launch_bounds__(256) void embed_kernel(
    const int* __restrict__ ids, const float* __restrict__ emb,
    float* __restrict__ X, bf16* __restrict__ Xb) {
  size_t i4 = (size_t)blockIdx.x * 256 + threadIdx.x;   // float4 index
  int tok = (int)(i4 >> 6);
  int d4  = (int)(i4 & 63);
  float4 v = *(const float4*)&emb[(size_t)ids[tok] * H_DIM + d4 * 4];
  *(float4*)&X[i4 * 4] = v;
  ushort4 pk;
  pk.x = f2bu(v.x); pk.y = f2bu(v.y); pk.z = f2bu(v.z); pk.w = f2bu(v.w);
  *(ushort4*)&Xb[i4 * 4] = pk;
}

// -------- bf16 MFMA GEMM, 2-phase dbuf: C = A[M,K] @ Bt[N,K]^T + bias ------
// MODE 1: bf16 out Cb (w/ optional relu);
// MODE 2: QKV split — n<512 -> Cb[m][768], n>=512 -> Vt[b,h,d,s^swz] bf16.
template<int MODE, bool RELU>
__global__ __launch_bounds__(256) void hgemm_kernel(
    const bf16* __restrict__ A, const bf16* __restrict__ Bt,
    const float* __restrict__ bias, float* __restrict__ Cf,
    bf16* __restrict__ Cb, bf16* __restrict__ Vt,
    int M, int N, int K) {
  __shared__ __align__(16) bf16 As[2][4096];   // [buf][128][32]
  __shared__ __align__(16) bf16 Bs[2][4096];
  const int tid = threadIdx.x;
  const int wv = tid >> 6, ln = tid & 63;
  const int fr = ln & 15, g4 = ln >> 4;
  const int wr = wv >> 1, wc = wv & 1;
  const int m0 = blockIdx.y * 128, n0 = blockIdx.x * 128;
  const int lr = tid >> 2, lk = (tid & 3) * 8;   // staging row / k-offset

#define STAGE_G(buf, kk) do {                                                  \
    const int kof_ = (kk) * 32;                                                \
    gload_lds16(A  + (size_t)(m0 + lr) * K + kof_ + lk,                        \
                &As[(buf)][wv * 512]);                                         \
    gload_lds16(A  + (size_t)(m0 + 64 + lr) * K + kof_ + lk,                   \
                &As[(buf)][2048 + wv * 512]);                                  \
    gload_lds16(Bt + (size_t)(n0 + lr) * K + kof_ + lk,                        \
                &Bs[(buf)][wv * 512]);                                         \
    gload_lds16(Bt + (size_t)(n0 + 64 + lr) * K + kof_ + lk,                   \
                &Bs[(buf)][2048 + wv * 512]);                                  \
  } while (0)

  f32x4 acc[4][4];
#pragma unroll
  for (int i = 0; i < 4; ++i)
#pragma unroll
    for (int j = 0; j < 4; ++j)
      acc[i][j] = (f32x4){0.f, 0.f, 0.f, 0.f};

  const int NT = K >> 5;
  STAGE_G(0, 0);
  __syncthreads();
  int cur = 0;
  for (int kt = 0; kt < NT; ++kt) {
    if (kt + 1 < NT) STAGE_G(cur ^ 1, kt + 1);
    short8 af[4], bfv[4];
#pragma unroll
    for (int i = 0; i < 4; ++i)
      af[i] = *(const short8*)&As[cur][(wr * 64 + i * 16 + fr) * 32 + g4 * 8];
#pragma unroll
    for (int j = 0; j < 4; ++j)
      bfv[j] = *(const short8*)&Bs[cur][(wc * 64 + j * 16 + fr) * 32 + g4 * 8];
#pragma unroll
    for (int i = 0; i < 4; ++i)
#pragma unroll
      for (int j = 0; j < 4; ++j)
        acc[i][j] = __builtin_amdgcn_mfma_f32_16x16x32_bf16(
            af[i], bfv[j], acc[i][j], 0, 0, 0);
    __syncthreads();
    cur ^= 1;
  }
#undef STAGE_G

  const int crow = g4 * 4, ccol = fr;
#pragma unroll
  for (int j = 0; j < 4; ++j) {
    const int n = n0 + wc * 64 + j * 16 + ccol;
    const float bv = bias[n];
#pragma unroll
    for (int i = 0; i < 4; ++i) {
      const int mbase = m0 + wr * 64 + i * 16 + crow;
#pragma unroll
      for (int r = 0; r < 4; ++r) {
        float o = acc[i][j][r] + bv;
        if (RELU) o = fmaxf(o, 0.f);
        const int m = mbase + r;
        if (MODE == 1) {
          Cb[(size_t)m * N + n] = __float2bfloat16(o);
        } else {
          if (n < 512) {
            Cb[(size_t)m * 768 + n] = __float2bfloat16(o);
          } else {
            const int hd = n - 512, hh = hd >> 5, dd = hd & 31;
            const int bb = m >> 9, ss = m & 511;
            const int ssw = (ss & ~63) | ((ss & 63) ^ ((dd & 7) << 3));
            Vt[(((size_t)bb * 8 + hh) * 32 + dd) * 512 + ssw] =
                __float2bfloat16(o);
          }
        }
      }
    }
  }
}

// -------- fused GEMM + bias + residual + LayerNorm + bf16, 2-phase dbuf ----
__global__ __launch_bounds__(256) void hgemm_ln_kernel(
    const bf16* __restrict__ A, const bf16* __restrict__ Bt,
    const float* __restrict__ bias, float* __restrict__ X,
    bf16* __restrict__ Xb, const float* __restrict__ g,
    const float* __restrict__ bt, int K) {
  __shared__ __align__(16) bf16 As[2][2048];   // [buf][64][32]
  __shared__ __align__(16) bf16 Bs[2][8192];   // [buf][256][32]
  __shared__ float rsum[4][64];
  __shared__ float rsq[4][64];
  const int tid = threadIdx.x;
  const int wv = tid >> 6;
  const int ln = tid & 63;
  const int fr = ln & 15, g4 = ln >> 4;
  const int m0 = blockIdx.x * 64;

#define STAGE_L(buf, kk) do {                                                  \
    const int kof_ = (kk) * 32;                                                \
    gload_lds16(A + (size_t)(m0 + (tid >> 2)) * K + kof_ + (tid & 3) * 8,      \
                &As[(buf)][wv * 512]);                                         \
    _Pragma("unroll")                                                          \
    for (int e = 0; e < 4; ++e) {                                              \
      const int vt = e * 256 + tid;                                            \
      gload_lds16(Bt + (size_t)(vt >> 2) * K + kof_ + (vt & 3) * 8,            \
                  &Bs[(buf)][e * 2048 + wv * 512]);                            \
    }                                                                          \
  } while (0)

  f32x4 acc[4][4];   // [row frag i][col frag j]
#pragma unroll
  for (int i = 0; i < 4; ++i)
#pragma unroll
    for (int j = 0; j < 4; ++j)
      acc[i][j] = (f32x4){0.f, 0.f, 0.f, 0.f};

  const int NT = K >> 5;
  STAGE_L(0, 0);
  __syncthreads();
  int cur = 0;
  for (int kt = 0; kt < NT; ++kt) {
    if (kt + 1 < NT) STAGE_L(cur ^ 1, kt + 1);
    short8 af[4], bfv[4];
#pragma unroll
    for (int i = 0; i < 4; ++i)
      af[i] = *(const short8*)&As[cur][(i * 16 + fr) * 32 + g4 * 8];
#pragma unroll
    for (int j = 0; j < 4; ++j)
      bfv[j] = *(const short8*)&Bs[cur][(wv * 64 + j * 16 + fr) * 32 + g4 * 8];
#pragma unroll
    for (int i = 0; i < 4; ++i)
#pragma unroll
      for (int j = 0; j < 4; ++j)
        acc[i][j] = __builtin_amdgcn_mfma_f32_16x16x32_bf16(
            af[i], bfv[j], acc[i][j], 0, 0, 0);
    __syncthreads();
    cur ^= 1;
  }
#undef STAGE_L

  float gj[4], bj[4], bsj[4];
#pragma unroll
  for (int j = 0; j < 4; ++j) {
    const int n = wv * 64 + j * 16 + fr;
    gj[j] = g[n]; bj[j] = bt[n]; bsj[j] = bias[n];
  }
#pragma unroll
  for (int i = 0; i < 4; ++i) {
#pragma unroll
    for (int r = 0; r < 4; ++r) {
      const int m = m0 + i * 16 + g4 * 4 + r;
#pragma unroll
      for (int j = 0; j < 4; ++j)
        acc[i][j][r] += bsj[j] + X[(size_t)m * 256 + wv * 64 + j * 16 + fr];
    }
  }
#pragma unroll
  for (int i = 0; i < 4; ++i) {
#pragma unroll
    for (int r = 0; r < 4; ++r) {
      float sp = acc[i][0][r] + acc[i][1][r] + acc[i][2][r] + acc[i][3][r];
      float qp = acc[i][0][r] * acc[i][0][r] + acc[i][1][r] * acc[i][1][r] +
                 acc[i][2][r] * acc[i][2][r] + acc[i][3][r] * acc[i][3][r];
#pragma unroll
      for (int off = 1; off < 16; off <<= 1) {
        sp += __shfl_xor(sp, off);
        qp += __shfl_xor(qp, off);
      }
      if (fr == 0) {
        const int ri = i * 16 + g4 * 4 + r;
        rsum[wv][ri] = sp;
        rsq[wv][ri] = qp;
      }
    }
  }
  __syncthreads();
#pragma unroll
  for (int i = 0; i < 4; ++i) {
#pragma unroll
    for (int r = 0; r < 4; ++r) {
      const int ri = i * 16 + g4 * 4 + r;
      const float tot = rsum[0][ri] + rsum[1][ri] + rsum[2][ri] + rsum[3][ri];
      const float tq = rsq[0][ri] + rsq[1][ri] + rsq[2][ri] + rsq[3][ri];
      const float mu = tot * (1.0f / 256.0f);
      const float var = tq * (1.0f / 256.0f) - mu * mu;
      const float rstd = rsqrtf(var + 1e-5f);
      const int m = m0 + ri;
#pragma unroll
      for (int j = 0; j < 4; ++j) {
        const float o = (acc[i][j][r] - mu) * rstd * gj[j] + bj[j];
        const size_t idx = (size_t)m * 256 + wv * 64 + j * 16 + fr;
        X[idx] = o;
        Xb[idx] = __float2bfloat16(o);
      }
    }
  }
}

// -------- bf16 MFMA flash attention (swapped QK^T, tile skip, K/V dbuf) -----
__global__ __launch_bounds__(256) void attn_mfma_kernel(
    const bf16* __restrict__ QKVb, const bf16* __restrict__ Vt,
    const int* __restrict__ amask, const int* __restrict__ ntiles,
    bf16* __restrict__ Ob) {
  const int b = blockIdx.z, h = blockIdx.y, q0 = blockIdx.x * 64;
  const int tid = threadIdx.x;
  const int wv = tid >> 6, ln = tid & 63;
  const int fr = ln & 15, g4 = ln >> 4;
  const int f8 = (fr & 7) << 3;
  const int bh32 = (b * 8 + h) * 32;
  __shared__ __align__(16) bf16 Qs[2048];      // [64][32]
  __shared__ __align__(16) bf16 Ks[2][2048];   // [buf][64][32]
  __shared__ __align__(16) bf16 Vs[2][2048];   // [buf][32 d][64 k] swizzled
  __shared__ __align__(16) bf16 Ps[4096];      // per-wave [16 q][64 k] swz
  __shared__ __align__(16) float Ms[64];

  const int nt = ntiles[b];

#define STAGE_A(buf, kt_) do {                                                 \
    const int k0_ = (kt_) * 64;                                                \
    gload_lds16(QKVb + (size_t)(b * S_LEN + k0_ + (tid >> 2)) * 768 + 256 +    \
                    h * 32 + (tid & 3) * 8,                                    \
                &Ks[(buf)][wv * 512]);                                         \
    gload_lds16(Vt + (size_t)(bh32 + (tid >> 3)) * 512 + k0_ + (tid & 7) * 8,  \
                &Vs[(buf)][wv * 512]);                                         \
    if ((kt_) == nt - 1 && tid < 64)                                           \
      Ms[tid] = (amask[b * S_LEN + k0_ + tid] != 0) ? 0.f : -1e9f;             \
  } while (0)

  gload_lds16(QKVb + (size_t)(b * S_LEN + q0 + (tid >> 2)) * 768 + h * 32 +
                  (tid & 3) * 8,
              &Qs[wv * 512]);
  STAGE_A(0, 0);
  __syncthreads();
  // B-operand fragment of Q^T: lane holds col q=fr, d-rows g4*8..+7. Hoisted.
  const short8 qb = *(const short8*)&Qs[(wv * 16 + fr) * 32 + g4 * 8];

  f32x4 accO[2];
  accO[0] = (f32x4){0.f, 0.f, 0.f, 0.f};
  accO[1] = (f32x4){0.f, 0.f, 0.f, 0.f};
  float mrun = -1e30f, lrun = 0.f;   // per-lane state for q = fr (log2 domain)
  const float SC2 = 0.17677669529663687f * 1.4426950408889634f;
  const int srcq = 20 * g4;   // shfl src base: lane 16*g4 + (4*g4 + rr)

  int cur = 0;
  for (int kt = 0; kt < nt; ++kt) {
    if (kt + 1 < nt) STAGE_A(cur ^ 1, kt + 1);
    const bool bnd = (kt == nt - 1);

    // S^T = K @ Q^T : 4 MFMAs cover 64 k x 16 q
    f32x4 st[4];
#pragma unroll
    for (int kb = 0; kb < 4; ++kb) {
      const short8 kf = *(const short8*)&Ks[cur][(kb * 16 + fr) * 32 + g4 * 8];
      f32x4 z = (f32x4){0.f, 0.f, 0.f, 0.f};
      st[kb] = __builtin_amdgcn_mfma_f32_16x16x32_bf16(kf, qb, z, 0, 0, 0);
    }

    // scale (+ mask on boundary tile only), in-lane max over 16
    float p[16];
    float mx = -1e30f;
    if (bnd) {
#pragma unroll
      for (int kb = 0; kb < 4; ++kb) {
        const f32x4 mv = ((const f32x4*)Ms)[kb * 4 + g4];
#pragma unroll
        for (int rr = 0; rr < 4; ++rr) {
          const float v = st[kb][rr] * SC2 + mv[rr];
          p[kb * 4 + rr] = v;
          mx = fmaxf(mx, v);
        }
      }
    } else {
#pragma unroll
      for (int kb = 0; kb < 4; ++kb) {
#pragma unroll
        for (int rr = 0; rr < 4; ++rr) {
          const float v = st[kb][rr] * SC2;
          p[kb * 4 + rr] = v;
          mx = fmaxf(mx, v);
        }
      }
    }
    mx = fmaxf(mx, __shfl_xor(mx, 16));
    mx = fmaxf(mx, __shfl_xor(mx, 32));
    const float mnew = fmaxf(mrun, mx);
    const float corr = exp2f(mrun - mnew);
    float ps = 0.f;
#pragma unroll
    for (int i = 0; i < 16; ++i) {
      const float e = exp2f(p[i] - mnew);
      p[i] = e;
      ps += e;
    }
    ps += __shfl_xor(ps, 16);
    ps += __shfl_xor(ps, 32);
    lrun = lrun * corr + ps;
    mrun = mnew;

    // redistribute corr (q=fr layout) to accumulator layout (q = 4*g4+rr)
#pragma unroll
    for (int rr = 0; rr < 4; ++rr) {
      const float cs = __shfl(corr, srcq + rr);
      accO[0][rr] *= cs;
      accO[1][rr] *= cs;
    }

    // write P rows: lane writes 4 shorts per kb at k = kb*16 + g4*4, XOR-swz
#pragma unroll
    for (int kb = 0; kb < 4; ++kb) {
      ushort4 w4;
      w4.x = f2bu(p[kb * 4 + 0]);
      w4.y = f2bu(p[kb * 4 + 1]);
      w4.z = f2bu(p[kb * 4 + 2]);
      w4.w = f2bu(p[kb * 4 + 3]);
      *(ushort4*)&Ps[wv * 1024 + fr * 64 + ((kb * 16 + g4 * 4) ^ f8)] = w4;
    }

    // PV: O[q][d] += P[16q x 32k] @ V[32k x 16d], per-wave (no barrier)
#pragma unroll
    for (int kk = 0; kk < 2; ++kk) {
      const short8 pa = *(const short8*)
          &Ps[wv * 1024 + fr * 64 + ((kk * 32 + g4 * 8) ^ f8)];
#pragma unroll
      for (int df = 0; df < 2; ++df) {
        const short8 vb = *(const short8*)
            &Vs[cur][(df * 16 + fr) * 64 + ((kk * 32 + g4 * 8) ^ f8)];
        accO[df] = __builtin_amdgcn_mfma_f32_16x16x32_bf16(
            pa, vb, accO[df], 0, 0, 0);
      }
    }
    __syncthreads();
    cur ^= 1;
  }
#undef STAGE_A

  const float inv = 1.0f / lrun;   // q = fr layout
#pragma unroll
  for (int rr = 0; rr < 4; ++rr) {
    const float iv = __shfl(inv, srcq + rr);
    const int q = q0 + wv * 16 + g4 * 4 + rr;
    const size_t orow = ((size_t)b * S_LEN + q) * H_DIM + h * 32;
    Ob[orow + fr]      = __float2bfloat16(accO[0][rr] * iv);
    Ob[orow + 16 + fr] = __float2bfloat16(accO[1][rr] * iv);
  }
}

// -------- fused final-LN + story-pool stage1: grid (64 b, 8 sgroups) -------
__global__ __launch_bounds__(256) void lnf_pool_kernel(
    float* __restrict__ X, const float* __restrict__ g,
    const float* __restrict__ bt, const int* __restrict__ amask,
    float* __restrict__ Pstory) {
  const int b = blockIdx.x, sg = blockIdx.y;
  const int tid = threadIdx.x, wv = tid >> 6, ln = tid & 63;
  const float4 gg = ((const float4*)g)[ln];
  const float4 bb = ((const float4*)bt)[ln];
  float ax = 0.f, ay = 0.f, az = 0.f, aw = 0.f;
  for (int t = wv; t < 64; t += 4) {
    const size_t tok = (size_t)b * S_LEN + sg * 64 + t;
    float4 v = ((const float4*)X)[tok * 64 + ln];
    float s = v.x + v.y + v.z + v.w;
#pragma unroll
    for (int off = 1; off < 64; off <<= 1) s += __shfl_xor(s, off);
    const float mu = s * (1.0f / 256.0f);
    const float dx = v.x - mu, dy = v.y - mu, dz = v.z - mu, dw = v.w - mu;
    float sq = dx * dx + dy * dy + dz * dz + dw * dw;
#pragma unroll
    for (int off = 1; off < 64; off <<= 1) sq += __shfl_xor(sq, off);
    const float rstd = rsqrtf(sq * (1.0f / 256.0f) + 1e-5f);
    float4 o;
    o.x = dx * rstd * gg.x + bb.x;
    o.y = dy * rstd * gg.y + bb.y;
    o.z = dz * rstd * gg.z + bb.z;
    o.w = dw * rstd * gg.w + bb.w;
    ((float4*)X)[tok * 64 + ln] = o;
    if (amask[tok]) { ax += o.x; ay += o.y; az += o.z; aw += o.w; }
  }
  __shared__ float part[4][256];
  part[wv][ln * 4 + 0] = ax;
  __syncthreads();   // (ensure no bank-write overlap ordering issues)
  part[wv][ln * 4 + 0] = ax;
  part[wv][ln * 4 + 1] = ay;
  part[wv][ln * 4 + 2] = az;
  part[wv][ln * 4 + 3] = aw;
  __syncthreads();
  // 256 threads: each sums one channel across the 4 waves
  const float tot = part[0][tid] + part[1][tid] + part[2][tid] + part[3][tid];
  Pstory[((size_t)b * 8 + sg) * 256 + tid] = tot;
}

// -------- pool combine: story mean + sub/obj gathers --------
__global__ __launch_bounds__(256) void poolc_kernel(
    const float* __restrict__ X, const float* __restrict__ Pstory,
    const int* __restrict__ lenb,
    const int* __restrict__ sub_idx, const int* __restrict__ sub_cnt,
    const int* __restrict__ obj_idx, const int* __restrict__ obj_cnt,
    float* __restrict__ feat) {
  const int b = blockIdx.x, c = threadIdx.x;
  float s = 0.f;
#pragma unroll
  for (int i = 0; i < 8; ++i) s += Pstory[((size_t)b * 8 + i) * 256 + c];
  feat[(size_t)b * 768 + 512 + c] = s / (float)lenb[b];   // len >= 16
  const float* xb = X + (size_t)b * S_LEN * H_DIM;
  {
    const int cc = sub_cnt[b];
    float s2 = 0.f;
    for (int j = 0; j < cc; ++j)
      s2 += xb[(size_t)sub_idx[b * 8 + j] * H_DIM + c];
    feat[(size_t)b * 768 + c] = (cc > 0) ? s2 / (float)cc : 0.f;
  }
  {
    const int cc = obj_cnt[b];
    float s2 = 0.f;
    for (int j = 0; j < cc; ++j)
      s2 += xb[(size_t)obj_idx[b * 8 + j] * H_DIM + c];
    feat[(size_t)b * 768 + 256 + c] = (cc > 0) ? s2 / (float)cc : 0.f;
  }
}

// -------- classifier --------
__global__ __launch_bounds__(256) void cls_kernel(
    const float* __restrict__ feat, const float* __restrict__ mW1,
    const float* __restrict__ mb1, const float* __restrict__ mW2,
    const float* __restrict__ mb2, float* __restrict__ out) {
  const int b = blockIdx.x, t = threadIdx.x;
  __shared__ float fs[768];
  __shared__ float hid[256];
#pragma unroll
  for (int e = 0; e < 3; ++e) fs[t + e * 256] = feat[(size_t)b * 768 + t + e * 256];
  __syncthreads();
  float acc = mb1[t];
  for (int k = 0; k < 768; ++k) acc += fs[k] * mW1[(size_t)k * 256 + t];
  hid[t] = fmaxf(acc, 0.f);
  __syncthreads();
  if (t < 25) {
    float o = mb2[t];
    for (int j = 0; j < 256; ++j) o += hid[j] * mW2[j * 25 + t];
    out[b * 25 + t] = o;
  }
}

// ---------------------------------------------------------------------------
extern "C" void kernel_launch(void* const* d_in, const int* in_sizes, int n_in,
                              void* d_out, int out_size, void* d_ws, size_t ws_size,
                              hipStream_t stream) {
  const int*   input_ids = (const int*)d_in[0];
  const int*   amask     = (const int*)d_in[1];
  const int*   sub_idx   = (const int*)d_in[2];
  const int*   sub_cnt   = (const int*)d_in[3];
  const int*   obj_idx   = (const int*)d_in[4];
  const int*   obj_cnt   = (const int*)d_in[5];
  const float* emb  = (const float*)d_in[6];
  const float* Wqkv = (const float*)d_in[7];
  const float* bqkv = (const float*)d_in[8];
  const float* Wo   = (const float*)d_in[9];
  const float* bo   = (const float*)d_in[10];
  const float* ln1g = (const float*)d_in[11];
  const float* ln1b = (const float*)d_in[12];
  const float* ln2g = (const float*)d_in[13];
  const float* ln2b = (const float*)d_in[14];
  const float* W1   = (const float*)d_in[15];
  const float* b1   = (const float*)d_in[16];
  const float* W2   = (const float*)d_in[17];
  const float* b2   = (const float*)d_in[18];
  const float* lnfg = (const float*)d_in[19];
  const float* lnfb = (const float*)d_in[20];
  const float* mW1  = (const float*)d_in[21];
  const float* mb1  = (const float*)d_in[22];
  const float* mW2  = (const float*)d_in[23];
  const float* mb2  = (const float*)d_in[24];
  float* out = (float*)d_out;

  // workspace layout (bytes)
  char* w = (char*)d_ws;
  float* X    = (float*)w;                         w += (size_t)NTOK * 256 * 4;  // 33.5MB
  bf16*  Xb   = (bf16*)w;                          w += (size_t)NTOK * 256 * 2;  // 16.8MB
  bf16*  QKVb = (bf16*)w;                          w += (size_t)NTOK * 768 * 2;  // 50.3MB
  bf16*  Vtg  = (bf16*)w;                          w += (size_t)NTOK * 256 * 2;  // 16.8MB
  bf16*  Ob   = (bf16*)w;                          w += (size_t)NTOK * 256 * 2;  // 16.8MB
  bf16*  Wqkvt= (bf16*)w;                          w += (size_t)4 * 768 * 256 * 2;
  bf16*  Wot  = (bf16*)w;                          w += (size_t)4 * 256 * 256 * 2;
  bf16*  W1t  = (bf16*)w;                          w += (size_t)4 * 1024 * 256 * 2;
  bf16*  W2t  = (bf16*)w;                          w += (size_t)4 * 256 * 1024 * 2;
  float* feat = (float*)w;                         w += (size_t)64 * 768 * 4;
  float* Pstory = (float*)w;                       w += (size_t)64 * 8 * 256 * 4;
  int*   ntiles = (int*)w;                         w += 256;
  int*   lenb   = (int*)w;                         w += 256;
  bf16*  Hb   = QKVb;   // aliases [QKVb, Vtg] = 67.1MB >= 32768*1024*2

  lens_kernel<<<64, 64, 0, stream>>>(amask, ntiles, lenb);
  tcast_kernel<<<dim3(24, 8, 4), 256, 0, stream>>>(Wqkv, Wqkvt, 256, 768);
  tcast_kernel<<<dim3(8, 8, 4), 256, 0, stream>>>(Wo, Wot, 256, 256);
  tcast_kernel<<<dim3(32, 8, 4), 256, 0, stream>>>(W1, W1t, 256, 1024);
  tcast_kernel<<<dim3(8, 32, 4), 256, 0, stream>>>(W2, W2t, 1024, 256);

  embed_kernel<<<8192, 256, 0, stream>>>(input_ids, emb, X, Xb);

  for (int l = 0; l < 4; ++l) {
    const bf16* Wqkvt_l = Wqkvt + (size_t)l * 768 * 256;
    const bf16* Wot_l   = Wot + (size_t)l * 256 * 256;
    const bf16* W1t_l   = W1t + (size_t)l * 1024 * 256;
    const bf16* W2t_l   = W2t + (size_t)l * 256 * 1024;

    hgemm_kernel<2, false><<<dim3(6, 256), 256, 0, stream>>>(
        Xb, Wqkvt_l, bqkv + (size_t)l * 768, nullptr, QKVb, Vtg, NTOK, 768, 256);
    attn_mfma_kernel<<<dim3(8, 8, 64), 256, 0, stream>>>(
        QKVb, Vtg, amask, ntiles, Ob);
    hgemm_ln_kernel<<<512, 256, 0, stream>>>(
        Ob, Wot_l, bo + (size_t)l * 256, X, Xb,
        ln1g + l * 256, ln1b + l * 256, 256);
    hgemm_kernel<1, true><<<dim3(8, 256), 256, 0, stream>>>(
        Xb, W1t_l, b1 + (size_t)l * 1024, nullptr, Hb, nullptr, NTOK, 1024, 256);
    hgemm_ln_kernel<<<512, 256, 0, stream>>>(
        Hb, W2t_l, b2 + (size_t)l * 256, X, Xb,
        ln2g + l * 256, ln2b + l * 256, 1024);
  }
  lnf_pool_kernel<<<dim3(64, 8), 256, 0, stream>>>(X, lnfg, lnfb, amask, Pstory);
  poolc_kernel<<<64, 256, 0, stream>>>(X, Pstory, lenb, sub_idx, sub_cnt,
                                       obj_idx, obj_cnt, feat);
  cls_kernel<<<64, 256, 0, stream>>>(feat, mW1, mb1, mW2, mb2, out);
}

// Round 7
// 809.043 us; speedup vs baseline: 5.8323x; 1.0239x over previous
//
#include <hip/hip_runtime.h>
#include <hip/hip_bf16.h>

// ---------------------------------------------------------------------------
// CLUTRR transformer: B=64 S=512 H=256 L=4 NH=8 DH=32 F=1024 V=50265 K=8 R=25
// Round 7: attn micro-opts — prescaled Q (scale*log2e folded at QKV epilogue),
// max3/tree reductions, defer-max (T13), Q staged via Ps (LDS 29->25KB),
// longest-batch-first dispatch order; pool+cls merged.
// ---------------------------------------------------------------------------

typedef __hip_bfloat16 bf16;
typedef __attribute__((ext_vector_type(8))) short short8;
typedef __attribute__((ext_vector_type(4))) float f32x4;

#define S_LEN 512
#define H_DIM 256
#define NTOK  32768      // B*S
#define QSCALE 0.25503488f   // (1/sqrt(32)) * log2(e)

__device__ __forceinline__ void gload_lds16(const void* g, void* l) {
  __builtin_amdgcn_global_load_lds(
      (const __attribute__((address_space(1))) unsigned int*)g,
      (__attribute__((address_space(3))) unsigned int*)l, 16, 0, 0);
}

__device__ __forceinline__ unsigned short f2bu(float x) {
  bf16 t = __float2bfloat16(x);
  return *reinterpret_cast<unsigned short*>(&t);
}

// -------- per-batch: exact valid length + tile count --------
__global__ __launch_bounds__(64) void lens_kernel(
    const int* __restrict__ amask, int* __restrict__ ntiles,
    int* __restrict__ lenb) {
  const int b = blockIdx.x, t = threadIdx.x;
  int c = 0;
#pragma unroll
  for (int i = 0; i < 8; ++i) c += amask[b * S_LEN + t + i * 64];
#pragma unroll
  for (int off = 1; off < 64; off <<= 1) c += __shfl_xor(c, off);
  if (t == 0) {
    lenb[b] = c;
    ntiles[b] = (c + 63) >> 6;
  }
}

// -------- rank-sort batches by tile count (descending) --------
__global__ __launch_bounds__(64) void order_kernel(
    const int* __restrict__ ntiles, int* __restrict__ ordb) {
  const int b = threadIdx.x;
  const int ntb = ntiles[b];
  int rank = 0;
  for (int j = 0; j < 64; ++j) {
    const int ntj = __shfl(ntb, j);
    rank += (ntj > ntb) || (ntj == ntb && j < b);
  }
  ordb[rank] = b;
}

// -------- weight cast + transpose: out[N][K] = bf16(in[K][N]) --------
__global__ __launch_bounds__(256) void tcast_kernel(
    const float* __restrict__ in, bf16* __restrict__ out, int K, int N) {
  const int l = blockIdx.z;
  in  += (size_t)l * K * N;
  out += (size_t)l * K * N;
  __shared__ float t[32][33];
  const int n0 = blockIdx.x * 32, k0 = blockIdx.y * 32;
  const int c = threadIdx.x & 31, r = threadIdx.x >> 5;
#pragma unroll
  for (int rr = r; rr < 32; rr += 8)
    t[rr][c] = in[(size_t)(k0 + rr) * N + n0 + c];
  __syncthreads();
#pragma unroll
  for (int rr = r; rr < 32; rr += 8)
    out[(size_t)(n0 + rr) * K + k0 + c] = __float2bfloat16(t[c][rr]);
}

// -------- embedding gather: X fp32 + Xb bf16 --------
__global__ __launch_bounds__(256) void embed_kernel(
    const int* __restrict__ ids, const float* __restrict__ emb,
    float* __restrict__ X, bf16* __restrict__ Xb) {
  size_t i4 = (size_t)blockIdx.x * 256 + threadIdx.x;   // float4 index
  int tok = (int)(i4 >> 6);
  int d4  = (int)(i4 & 63);
  float4 v = *(const float4*)&emb[(size_t)ids[tok] * H_DIM + d4 * 4];
  *(float4*)&X[i4 * 4] = v;
  ushort4 pk;
  pk.x = f2bu(v.x); pk.y = f2bu(v.y); pk.z = f2bu(v.z); pk.w = f2bu(v.w);
  *(ushort4*)&Xb[i4 * 4] = pk;
}

// -------- bf16 MFMA GEMM, 2-phase dbuf: C = A[M,K] @ Bt[N,K]^T + bias ------
// MODE 1: bf16 out Cb (w/ optional relu);
// MODE 2: QKV split — n<256 -> Q prescaled by QSCALE into Cb[m][768];
//         256<=n<512 -> Cb; n>=512 -> Vt[b,h,d,s^swz] bf16.
template<int MODE, bool RELU>
__global__ __launch_bounds__(256) void hgemm_kernel(
    const bf16* __restrict__ A, const bf16* __restrict__ Bt,
    const float* __restrict__ bias, float* __restrict__ Cf,
    bf16* __restrict__ Cb, bf16* __restrict__ Vt,
    int M, int N, int K) {
  __shared__ __align__(16) bf16 As[2][4096];   // [buf][128][32]
  __shared__ __align__(16) bf16 Bs[2][4096];
  const int tid = threadIdx.x;
  const int wv = tid >> 6, ln = tid & 63;
  const int fr = ln & 15, g4 = ln >> 4;
  const int wr = wv >> 1, wc = wv & 1;
  const int m0 = blockIdx.y * 128, n0 = blockIdx.x * 128;
  const int lr = tid >> 2, lk = (tid & 3) * 8;   // staging row / k-offset

#define STAGE_G(buf, kk) do {                                                  \
    const int kof_ = (kk) * 32;                                                \
    gload_lds16(A  + (size_t)(m0 + lr) * K + kof_ + lk,                        \
                &As[(buf)][wv * 512]);                                         \
    gload_lds16(A  + (size_t)(m0 + 64 + lr) * K + kof_ + lk,                   \
                &As[(buf)][2048 + wv * 512]);                                  \
    gload_lds16(Bt + (size_t)(n0 + lr) * K + kof_ + lk,                        \
                &Bs[(buf)][wv * 512]);                                         \
    gload_lds16(Bt + (size_t)(n0 + 64 + lr) * K + kof_ + lk,                   \
                &Bs[(buf)][2048 + wv * 512]);                                  \
  } while (0)

  f32x4 acc[4][4];
#pragma unroll
  for (int i = 0; i < 4; ++i)
#pragma unroll
    for (int j = 0; j < 4; ++j)
      acc[i][j] = (f32x4){0.f, 0.f, 0.f, 0.f};

  const int NT = K >> 5;
  STAGE_G(0, 0);
  __syncthreads();
  int cur = 0;
  for (int kt = 0; kt < NT; ++kt) {
    if (kt + 1 < NT) STAGE_G(cur ^ 1, kt + 1);
    short8 af[4], bfv[4];
#pragma unroll
    for (int i = 0; i < 4; ++i)
      af[i] = *(const short8*)&As[cur][(wr * 64 + i * 16 + fr) * 32 + g4 * 8];
#pragma unroll
    for (int j = 0; j < 4; ++j)
      bfv[j] = *(const short8*)&Bs[cur][(wc * 64 + j * 16 + fr) * 32 + g4 * 8];
#pragma unroll
    for (int i = 0; i < 4; ++i)
#pragma unroll
      for (int j = 0; j < 4; ++j)
        acc[i][j] = __builtin_amdgcn_mfma_f32_16x16x32_bf16(
            af[i], bfv[j], acc[i][j], 0, 0, 0);
    __syncthreads();
    cur ^= 1;
  }
#undef STAGE_G

  const int crow = g4 * 4, ccol = fr;
#pragma unroll
  for (int j = 0; j < 4; ++j) {
    const int n = n0 + wc * 64 + j * 16 + ccol;
    const float bv = bias[n];
#pragma unroll
    for (int i = 0; i < 4; ++i) {
      const int mbase = m0 + wr * 64 + i * 16 + crow;
#pragma unroll
      for (int r = 0; r < 4; ++r) {
        float o = acc[i][j][r] + bv;
        if (RELU) o = fmaxf(o, 0.f);
        const int m = mbase + r;
        if (MODE == 1) {
          Cb[(size_t)m * N + n] = __float2bfloat16(o);
        } else {
          if (n < 512) {
            const float oo = (n < 256) ? o * QSCALE : o;  // prescale Q
            Cb[(size_t)m * 768 + n] = __float2bfloat16(oo);
          } else {
            const int hd = n - 512, hh = hd >> 5, dd = hd & 31;
            const int bb = m >> 9, ss = m & 511;
            const int ssw = (ss & ~63) | ((ss & 63) ^ ((dd & 7) << 3));
            Vt[(((size_t)bb * 8 + hh) * 32 + dd) * 512 + ssw] =
                __float2bfloat16(o);
          }
        }
      }
    }
  }
}

// -------- fused GEMM + bias + residual + LayerNorm + bf16, 2-phase dbuf ----
__global__ __launch_bounds__(256) void hgemm_ln_kernel(
    const bf16* __restrict__ A, const bf16* __restrict__ Bt,
    const float* __restrict__ bias, float* __restrict__ X,
    bf16* __restrict__ Xb, const float* __restrict__ g,
    const float* __restrict__ bt, int K) {
  __shared__ __align__(16) bf16 As[2][2048];   // [buf][64][32]
  __shared__ __align__(16) bf16 Bs[2][8192];   // [buf][256][32]
  __shared__ float rsum[4][64];
  __shared__ float rsq[4][64];
  const int tid = threadIdx.x;
  const int wv = tid >> 6;
  const int ln = tid & 63;
  const int fr = ln & 15, g4 = ln >> 4;
  const int m0 = blockIdx.x * 64;

#define STAGE_L(buf, kk) do {                                                  \
    const int kof_ = (kk) * 32;                                                \
    gload_lds16(A + (size_t)(m0 + (tid >> 2)) * K + kof_ + (tid & 3) * 8,      \
                &As[(buf)][wv * 512]);                                         \
    _Pragma("unroll")                                                          \
    for (int e = 0; e < 4; ++e) {                                              \
      const int vt = e * 256 + tid;                                            \
      gload_lds16(Bt + (size_t)(vt >> 2) * K + kof_ + (vt & 3) * 8,            \
                  &Bs[(buf)][e * 2048 + wv * 512]);                            \
    }                                                                          \
  } while (0)

  f32x4 acc[4][4];   // [row frag i][col frag j]
#pragma unroll
  for (int i = 0; i < 4; ++i)
#pragma unroll
    for (int j = 0; j < 4; ++j)
      acc[i][j] = (f32x4){0.f, 0.f, 0.f, 0.f};

  const int NT = K >> 5;
  STAGE_L(0, 0);
  __syncthreads();
  int cur = 0;
  for (int kt = 0; kt < NT; ++kt) {
    if (kt + 1 < NT) STAGE_L(cur ^ 1, kt + 1);
    short8 af[4], bfv[4];
#pragma unroll
    for (int i = 0; i < 4; ++i)
      af[i] = *(const short8*)&As[cur][(i * 16 + fr) * 32 + g4 * 8];
#pragma unroll
    for (int j = 0; j < 4; ++j)
      bfv[j] = *(const short8*)&Bs[cur][(wv * 64 + j * 16 + fr) * 32 + g4 * 8];
#pragma unroll
    for (int i = 0; i < 4; ++i)
#pragma unroll
      for (int j = 0; j < 4; ++j)
        acc[i][j] = __builtin_amdgcn_mfma_f32_16x16x32_bf16(
            af[i], bfv[j], acc[i][j], 0, 0, 0);
    __syncthreads();
    cur ^= 1;
  }
#undef STAGE_L

  float gj[4], bj[4], bsj[4];
#pragma unroll
  for (int j = 0; j < 4; ++j) {
    const int n = wv * 64 + j * 16 + fr;
    gj[j] = g[n]; bj[j] = bt[n]; bsj[j] = bias[n];
  }
#pragma unroll
  for (int i = 0; i < 4; ++i) {
#pragma unroll
    for (int r = 0; r < 4; ++r) {
      const int m = m0 + i * 16 + g4 * 4 + r;
#pragma unroll
      for (int j = 0; j < 4; ++j)
        acc[i][j][r] += bsj[j] + X[(size_t)m * 256 + wv * 64 + j * 16 + fr];
    }
  }
#pragma unroll
  for (int i = 0; i < 4; ++i) {
#pragma unroll
    for (int r = 0; r < 4; ++r) {
      float sp = acc[i][0][r] + acc[i][1][r] + acc[i][2][r] + acc[i][3][r];
      float qp = acc[i][0][r] * acc[i][0][r] + acc[i][1][r] * acc[i][1][r] +
                 acc[i][2][r] * acc[i][2][r] + acc[i][3][r] * acc[i][3][r];
#pragma unroll
      for (int off = 1; off < 16; off <<= 1) {
        sp += __shfl_xor(sp, off);
        qp += __shfl_xor(qp, off);
      }
      if (fr == 0) {
        const int ri = i * 16 + g4 * 4 + r;
        rsum[wv][ri] = sp;
        rsq[wv][ri] = qp;
      }
    }
  }
  __syncthreads();
#pragma unroll
  for (int i = 0; i < 4; ++i) {
#pragma unroll
    for (int r = 0; r < 4; ++r) {
      const int ri = i * 16 + g4 * 4 + r;
      const float tot = rsum[0][ri] + rsum[1][ri] + rsum[2][ri] + rsum[3][ri];
      const float tq = rsq[0][ri] + rsq[1][ri] + rsq[2][ri] + rsq[3][ri];
      const float mu = tot * (1.0f / 256.0f);
      const float var = tq * (1.0f / 256.0f) - mu * mu;
      const float rstd = rsqrtf(var + 1e-5f);
      const int m = m0 + ri;
#pragma unroll
      for (int j = 0; j < 4; ++j) {
        const float o = (acc[i][j][r] - mu) * rstd * gj[j] + bj[j];
        const size_t idx = (size_t)m * 256 + wv * 64 + j * 16 + fr;
        X[idx] = o;
        Xb[idx] = __float2bfloat16(o);
      }
    }
  }
}

// -------- bf16 MFMA flash attention --------
// Swapped QK^T (lane-local rows), prescaled Q (log2-domain scores), tile skip,
// K/V dbuf, defer-max, max3/tree reductions, Q staged via Ps, sorted batches.
__global__ __launch_bounds__(256) void attn_mfma_kernel(
    const bf16* __restrict__ QKVb, const bf16* __restrict__ Vt,
    const int* __restrict__ amask, const int* __restrict__ ntiles,
    const int* __restrict__ ordb, bf16* __restrict__ Ob) {
  const int b = ordb[blockIdx.z];
  const int h = blockIdx.y, q0 = blockIdx.x * 64;
  const int tid = threadIdx.x;
  const int wv = tid >> 6, ln = tid & 63;
  const int fr = ln & 15, g4 = ln >> 4;
  const int f8 = (fr & 7) << 3;
  const int bh32 = (b * 8 + h) * 32;
  __shared__ __align__(16) bf16 Ks[2][2048];   // [buf][64][32]
  __shared__ __align__(16) bf16 Vs[2][2048];   // [buf][32 d][64 k] swizzled
  __shared__ __align__(16) bf16 Ps[4096];      // per-wave P; Q staging early
  __shared__ __align__(16) float Ms[64];

  const int nt = ntiles[b];

#define STAGE_A(buf, kt_) do {                                                 \
    const int k0_ = (kt_) * 64;                                                \
    gload_lds16(QKVb + (size_t)(b * S_LEN + k0_ + (tid >> 2)) * 768 + 256 +    \
                    h * 32 + (tid & 3) * 8,                                    \
                &Ks[(buf)][wv * 512]);                                         \
    gload_lds16(Vt + (size_t)(bh32 + (tid >> 3)) * 512 + k0_ + (tid & 7) * 8,  \
                &Vs[(buf)][wv * 512]);                                         \
    if ((kt_) == nt - 1 && tid < 64)                                           \
      Ms[tid] = (amask[b * S_LEN + k0_ + tid] != 0) ? 0.f : -1e9f;             \
  } while (0)

  // stage Q through the Ps buffer (dead after the fragment read below)
  gload_lds16(QKVb + (size_t)(b * S_LEN + q0 + (tid >> 2)) * 768 + h * 32 +
                  (tid & 3) * 8,
              &Ps[wv * 512]);
  STAGE_A(0, 0);
  __syncthreads();
  const short8 qb = *(const short8*)&Ps[(wv * 16 + fr) * 32 + g4 * 8];
  __syncthreads();   // all Q-frag reads done before any P write

  f32x4 accO[2];
  accO[0] = (f32x4){0.f, 0.f, 0.f, 0.f};
  accO[1] = (f32x4){0.f, 0.f, 0.f, 0.f};
  float mrun = -1e30f, lrun = 0.f;   // per-lane state for q = fr (log2 domain)
  const int srcq = 20 * g4;   // shfl src base: lane 16*g4 + (4*g4 + rr)

  int cur = 0;
  for (int kt = 0; kt < nt; ++kt) {
    if (kt + 1 < nt) STAGE_A(cur ^ 1, kt + 1);
    const bool bnd = (kt == nt - 1);

    // S^T = K @ Q^T : 4 MFMAs cover 64 k x 16 q (already log2-scaled via Q)
    f32x4 st[4];
#pragma unroll
    for (int kb = 0; kb < 4; ++kb) {
      const short8 kf = *(const short8*)&Ks[cur][(kb * 16 + fr) * 32 + g4 * 8];
      f32x4 z = (f32x4){0.f, 0.f, 0.f, 0.f};
      st[kb] = __builtin_amdgcn_mfma_f32_16x16x32_bf16(kf, qb, z, 0, 0, 0);
    }

    float p[16];
    if (bnd) {
#pragma unroll
      for (int kb = 0; kb < 4; ++kb) {
        const f32x4 mv = ((const f32x4*)Ms)[kb * 4 + g4];
#pragma unroll
        for (int rr = 0; rr < 4; ++rr) p[kb * 4 + rr] = st[kb][rr] + mv[rr];
      }
    } else {
#pragma unroll
      for (int kb = 0; kb < 4; ++kb)
#pragma unroll
        for (int rr = 0; rr < 4; ++rr) p[kb * 4 + rr] = st[kb][rr];
    }

    // max: v_max3 tree (depth 3) + 2 cross-lane
    const float a0 = fmaxf(fmaxf(p[0], p[1]), p[2]);
    const float a1 = fmaxf(fmaxf(p[3], p[4]), p[5]);
    const float a2 = fmaxf(fmaxf(p[6], p[7]), p[8]);
    const float a3 = fmaxf(fmaxf(p[9], p[10]), p[11]);
    const float a4 = fmaxf(fmaxf(p[12], p[13]), p[14]);
    float mx = fmaxf(fmaxf(fmaxf(a0, a1), fmaxf(a2, a3)), fmaxf(a4, p[15]));
    mx = fmaxf(mx, __shfl_xor(mx, 16));
    mx = fmaxf(mx, __shfl_xor(mx, 32));

    // defer-max (T13): rescale only when the row max grew by > 8 (log2)
    float corr = 1.f;
    if (!__all(mx <= mrun + 8.f)) {
      const float mnew = fmaxf(mrun, mx);
      corr = exp2f(mrun - mnew);
      mrun = mnew;
#pragma unroll
      for (int rr = 0; rr < 4; ++rr) {
        const float cs = __shfl(corr, srcq + rr);
        accO[0][rr] *= cs;
        accO[1][rr] *= cs;
      }
    }

#pragma unroll
    for (int i = 0; i < 16; ++i) p[i] = exp2f(p[i] - mrun);
    // pairwise-tree sum (depth 4) + 2 cross-lane
    const float b0 = p[0] + p[1], b1 = p[2] + p[3], b2 = p[4] + p[5],
                b3 = p[6] + p[7], b4 = p[8] + p[9], b5 = p[10] + p[11],
                b6 = p[12] + p[13], b7 = p[14] + p[15];
    float ps = ((b0 + b1) + (b2 + b3)) + ((b4 + b5) + (b6 + b7));
    ps += __shfl_xor(ps, 16);
    ps += __shfl_xor(ps, 32);
    lrun = lrun * corr + ps;

    // write P rows: lane writes 4 shorts per kb at k = kb*16 + g4*4, XOR-swz
#pragma unroll
    for (int kb = 0; kb < 4; ++kb) {
      ushort4 w4;
      w4.x = f2bu(p[kb * 4 + 0]);
      w4.y = f2bu(p[kb * 4 + 1]);
      w4.z = f2bu(p[kb * 4 + 2]);
      w4.w = f2bu(p[kb * 4 + 3]);
      *(ushort4*)&Ps[wv * 1024 + fr * 64 + ((kb * 16 + g4 * 4) ^ f8)] = w4;
    }

    // PV: O[q][d] += P[16q x 32k] @ V[32k x 16d], per-wave (no barrier)
#pragma unroll
    for (int kk = 0; kk < 2; ++kk) {
      const short8 pa = *(const short8*)
          &Ps[wv * 1024 + fr * 64 + ((kk * 32 + g4 * 8) ^ f8)];
#pragma unroll
      for (int df = 0; df < 2; ++df) {
        const short8 vb = *(const short8*)
            &Vs[cur][(df * 16 + fr) * 64 + ((kk * 32 + g4 * 8) ^ f8)];
        accO[df] = __builtin_amdgcn_mfma_f32_16x16x32_bf16(
            pa, vb, accO[df], 0, 0, 0);
      }
    }
    __syncthreads();
    cur ^= 1;
  }
#undef STAGE_A

  const float inv = 1.0f / lrun;   // q = fr layout
#pragma unroll
  for (int rr = 0; rr < 4; ++rr) {
    const float iv = __shfl(inv, srcq + rr);
    const int q = q0 + wv * 16 + g4 * 4 + rr;
    const size_t orow = ((size_t)b * S_LEN + q) * H_DIM + h * 32;
    Ob[orow + fr]      = __float2bfloat16(accO[0][rr] * iv);
    Ob[orow + 16 + fr] = __float2bfloat16(accO[1][rr] * iv);
  }
}

// -------- fused final-LN + story-pool stage1: grid (64 b, 8 sgroups) -------
__global__ __launch_bounds__(256) void lnf_pool_kernel(
    float* __restrict__ X, const float* __restrict__ g,
    const float* __restrict__ bt, const int* __restrict__ amask,
    float* __restrict__ Pstory) {
  const int b = blockIdx.x, sg = blockIdx.y;
  const int tid = threadIdx.x, wv = tid >> 6, ln = tid & 63;
  const float4 gg = ((const float4*)g)[ln];
  const float4 bb = ((const float4*)bt)[ln];
  float ax = 0.f, ay = 0.f, az = 0.f, aw = 0.f;
  for (int t = wv; t < 64; t += 4) {
    const size_t tok = (size_t)b * S_LEN + sg * 64 + t;
    float4 v = ((const float4*)X)[tok * 64 + ln];
    float s = v.x + v.y + v.z + v.w;
#pragma unroll
    for (int off = 1; off < 64; off <<= 1) s += __shfl_xor(s, off);
    const float mu = s * (1.0f / 256.0f);
    const float dx = v.x - mu, dy = v.y - mu, dz = v.z - mu, dw = v.w - mu;
    float sq = dx * dx + dy * dy + dz * dz + dw * dw;
#pragma unroll
    for (int off = 1; off < 64; off <<= 1) sq += __shfl_xor(sq, off);
    const float rstd = rsqrtf(sq * (1.0f / 256.0f) + 1e-5f);
    float4 o;
    o.x = dx * rstd * gg.x + bb.x;
    o.y = dy * rstd * gg.y + bb.y;
    o.z = dz * rstd * gg.z + bb.z;
    o.w = dw * rstd * gg.w + bb.w;
    ((float4*)X)[tok * 64 + ln] = o;
    if (amask[tok]) { ax += o.x; ay += o.y; az += o.z; aw += o.w; }
  }
  __shared__ float part[4][256];
  part[wv][ln * 4 + 0] = ax;
  part[wv][ln * 4 + 1] = ay;
  part[wv][ln * 4 + 2] = az;
  part[wv][ln * 4 + 3] = aw;
  __syncthreads();
  const float tot = part[0][tid] + part[1][tid] + part[2][tid] + part[3][tid];
  Pstory[((size_t)b * 8 + sg) * 256 + tid] = tot;
}

// -------- pool combine + classifier (merged) --------
__global__ __launch_bounds__(256) void poolcls_kernel(
    const float* __restrict__ X, const float* __restrict__ Pstory,
    const int* __restrict__ lenb,
    const int* __restrict__ sub_idx, const int* __restrict__ sub_cnt,
    const int* __restrict__ obj_idx, const int* __restrict__ obj_cnt,
    const float* __restrict__ mW1, const float* __restrict__ mb1,
    const float* __restrict__ mW2, const float* __restrict__ mb2,
    float* __restrict__ out) {
  const int b = blockIdx.x, t = threadIdx.x;
  __shared__ float fs[768];
  __shared__ float hid[256];
  const float* xb = X + (size_t)b * S_LEN * H_DIM;
  {
    float s = 0.f;
#pragma unroll
    for (int i = 0; i < 8; ++i) s += Pstory[((size_t)b * 8 + i) * 256 + t];
    fs[512 + t] = s / (float)lenb[b];   // len >= 16
  }
  {
    const int cc = sub_cnt[b];
    float s2 = 0.f;
    for (int j = 0; j < cc; ++j)
      s2 += xb[(size_t)sub_idx[b * 8 + j] * H_DIM + t];
    fs[t] = (cc > 0) ? s2 / (float)cc : 0.f;
  }
  {
    const int cc = obj_cnt[b];
    float s2 = 0.f;
    for (int j = 0; j < cc; ++j)
      s2 += xb[(size_t)obj_idx[b * 8 + j] * H_DIM + t];
    fs[256 + t] = (cc > 0) ? s2 / (float)cc : 0.f;
  }
  __syncthreads();
  float acc = mb1[t];
  for (int k = 0; k < 768; ++k) acc += fs[k] * mW1[(size_t)k * 256 + t];
  hid[t] = fmaxf(acc, 0.f);
  __syncthreads();
  if (t < 25) {
    float o = mb2[t];
    for (int j = 0; j < 256; ++j) o += hid[j] * mW2[j * 25 + t];
    out[b * 25 + t] = o;
  }
}

// ---------------------------------------------------------------------------
extern "C" void kernel_launch(void* const* d_in, const int* in_sizes, int n_in,
                              void* d_out, int out_size, void* d_ws, size_t ws_size,
                              hipStream_t stream) {
  const int*   input_ids = (const int*)d_in[0];
  const int*   amask     = (const int*)d_in[1];
  const int*   sub_idx   = (const int*)d_in[2];
  const int*   sub_cnt   = (const int*)d_in[3];
  const int*   obj_idx   = (const int*)d_in[4];
  const int*   obj_cnt   = (const int*)d_in[5];
  const float* emb  = (const float*)d_in[6];
  const float* Wqkv = (const float*)d_in[7];
  const float* bqkv = (const float*)d_in[8];
  const float* Wo   = (const float*)d_in[9];
  const float* bo   = (const float*)d_in[10];
  const float* ln1g = (const float*)d_in[11];
  const float* ln1b = (const float*)d_in[12];
  const float* ln2g = (const float*)d_in[13];
  const float* ln2b = (const float*)d_in[14];
  const float* W1   = (const float*)d_in[15];
  const float* b1   = (const float*)d_in[16];
  const float* W2   = (const float*)d_in[17];
  const float* b2   = (const float*)d_in[18];
  const float* lnfg = (const float*)d_in[19];
  const float* lnfb = (const float*)d_in[20];
  const float* mW1  = (const float*)d_in[21];
  const float* mb1  = (const float*)d_in[22];
  const float* mW2  = (const float*)d_in[23];
  const float* mb2  = (const float*)d_in[24];
  float* out = (float*)d_out;

  // workspace layout (bytes)
  char* w = (char*)d_ws;
  float* X    = (float*)w;                         w += (size_t)NTOK * 256 * 4;  // 33.5MB
  bf16*  Xb   = (bf16*)w;                          w += (size_t)NTOK * 256 * 2;  // 16.8MB
  bf16*  QKVb = (bf16*)w;                          w += (size_t)NTOK * 768 * 2;  // 50.3MB
  bf16*  Vtg  = (bf16*)w;                          w += (size_t)NTOK * 256 * 2;  // 16.8MB
  bf16*  Ob   = (bf16*)w;                          w += (size_t)NTOK * 256 * 2;  // 16.8MB
  bf16*  Wqkvt= (bf16*)w;                          w += (size_t)4 * 768 * 256 * 2;
  bf16*  Wot  = (bf16*)w;                          w += (size_t)4 * 256 * 256 * 2;
  bf16*  W1t  = (bf16*)w;                          w += (size_t)4 * 1024 * 256 * 2;
  bf16*  W2t  = (bf16*)w;                          w += (size_t)4 * 256 * 1024 * 2;
  float* Pstory = (float*)w;                       w += (size_t)64 * 8 * 256 * 4;
  int*   ntiles = (int*)w;                         w += 256;
  int*   lenb   = (int*)w;                         w += 256;
  int*   ordb   = (int*)w;                         w += 256;
  bf16*  Hb   = QKVb;   // aliases [QKVb, Vtg] = 67.1MB >= 32768*1024*2

  lens_kernel<<<64, 64, 0, stream>>>(amask, ntiles, lenb);
  order_kernel<<<1, 64, 0, stream>>>(ntiles, ordb);
  tcast_kernel<<<dim3(24, 8, 4), 256, 0, stream>>>(Wqkv, Wqkvt, 256, 768);
  tcast_kernel<<<dim3(8, 8, 4), 256, 0, stream>>>(Wo, Wot, 256, 256);
  tcast_kernel<<<dim3(32, 8, 4), 256, 0, stream>>>(W1, W1t, 256, 1024);
  tcast_kernel<<<dim3(8, 32, 4), 256, 0, stream>>>(W2, W2t, 1024, 256);

  embed_kernel<<<8192, 256, 0, stream>>>(input_ids, emb, X, Xb);

  for (int l = 0; l < 4; ++l) {
    const bf16* Wqkvt_l = Wqkvt + (size_t)l * 768 * 256;
    const bf16* Wot_l   = Wot + (size_t)l * 256 * 256;
    const bf16* W1t_l   = W1t + (size_t)l * 1024 * 256;
    const bf16* W2t_l   = W2t + (size_t)l * 256 * 1024;

    hgemm_kernel<2, false><<<dim3(6, 256), 256, 0, stream>>>(
        Xb, Wqkvt_l, bqkv + (size_t)l * 768, nullptr, QKVb, Vtg, NTOK, 768, 256);
    attn_mfma_kernel<<<dim3(8, 8, 64), 256, 0, stream>>>(
        QKVb, Vtg, amask, ntiles, ordb, Ob);
    hgemm_ln_kernel<<<512, 256, 0, stream>>>(
        Ob, Wot_l, bo + (size_t)l * 256, X, Xb,
        ln1g + l * 256, ln1b + l * 256, 256);
    hgemm_kernel<1, true><<<dim3(8, 256), 256, 0, stream>>>(
        Xb, W1t_l, b1 + (size_t)l * 1024, nullptr, Hb, nullptr, NTOK, 1024, 256);
    hgemm_ln_kernel<<<512, 256, 0, stream>>>(
        Hb, W2t_l, b2 + (size_t)l * 256, X, Xb,
        ln2g + l * 256, ln2b + l * 256, 1024);
  }
  lnf_pool_kernel<<<dim3(64, 8), 256, 0, stream>>>(X, lnfg, lnfb, amask, Pstory);
  poolcls_kernel<<<64, 256, 0, stream>>>(X, Pstory, lenb, sub_idx, sub_cnt,
                                         obj_idx, obj_cnt, mW1, mb1, mW2, mb2,
                                         out);
}

// Round 8
// 791.093 us; speedup vs baseline: 5.9646x; 1.0227x over previous
//
#include <hip/hip_runtime.h>
#include <hip/hip_bf16.h>

// ---------------------------------------------------------------------------
// CLUTRR transformer: B=64 S=512 H=256 L=4 NH=8 DH=32 F=1024 V=50265 K=8 R=25
// Round 8: XCD-friendly GEMM grid (m-tile fastest -> A-panel sharers on same
// XCD L2), bank-quad-injective LDS chunk swizzle (src-swizzled global +
// swizzled ds_read, linear LDS dest) in GEMMs + attention K/Q.
// ---------------------------------------------------------------------------

typedef __hip_bfloat16 bf16;
typedef __attribute__((ext_vector_type(8))) short short8;
typedef __attribute__((ext_vector_type(4))) float f32x4;

#define S_LEN 512
#define H_DIM 256
#define NTOK  32768      // B*S
#define QSCALE 0.25503488f   // (1/sqrt(32)) * log2(e)

__device__ __forceinline__ void gload_lds16(const void* g, void* l) {
  __builtin_amdgcn_global_load_lds(
      (const __attribute__((address_space(1))) unsigned int*)g,
      (__attribute__((address_space(3))) unsigned int*)l, 16, 0, 0);
}

__device__ __forceinline__ unsigned short f2bu(float x) {
  bf16 t = __float2bfloat16(x);
  return *reinterpret_cast<unsigned short*>(&t);
}

// -------- per-batch: exact valid length + tile count --------
__global__ __launch_bounds__(64) void lens_kernel(
    const int* __restrict__ amask, int* __restrict__ ntiles,
    int* __restrict__ lenb) {
  const int b = blockIdx.x, t = threadIdx.x;
  int c = 0;
#pragma unroll
  for (int i = 0; i < 8; ++i) c += amask[b * S_LEN + t + i * 64];
#pragma unroll
  for (int off = 1; off < 64; off <<= 1) c += __shfl_xor(c, off);
  if (t == 0) {
    lenb[b] = c;
    ntiles[b] = (c + 63) >> 6;
  }
}

// -------- rank-sort batches by tile count (descending) --------
__global__ __launch_bounds__(64) void order_kernel(
    const int* __restrict__ ntiles, int* __restrict__ ordb) {
  const int b = threadIdx.x;
  const int ntb = ntiles[b];
  int rank = 0;
  for (int j = 0; j < 64; ++j) {
    const int ntj = __shfl(ntb, j);
    rank += (ntj > ntb) || (ntj == ntb && j < b);
  }
  ordb[rank] = b;
}

// -------- weight cast + transpose: out[N][K] = bf16(in[K][N]) --------
__global__ __launch_bounds__(256) void tcast_kernel(
    const float* __restrict__ in, bf16* __restrict__ out, int K, int N) {
  const int l = blockIdx.z;
  in  += (size_t)l * K * N;
  out += (size_t)l * K * N;
  __shared__ float t[32][33];
  const int n0 = blockIdx.x * 32, k0 = blockIdx.y * 32;
  const int c = threadIdx.x & 31, r = threadIdx.x >> 5;
#pragma unroll
  for (int rr = r; rr < 32; rr += 8)
    t[rr][c] = in[(size_t)(k0 + rr) * N + n0 + c];
  __syncthreads();
#pragma unroll
  for (int rr = r; rr < 32; rr += 8)
    out[(size_t)(n0 + rr) * K + k0 + c] = __float2bfloat16(t[c][rr]);
}

// -------- embedding gather: X fp32 + Xb bf16 --------
__global__ __launch_bounds__(256) void embed_kernel(
    const int* __restrict__ ids, const float* __restrict__ emb,
    float* __restrict__ X, bf16* __restrict__ Xb) {
  size_t i4 = (size_t)blockIdx.x * 256 + threadIdx.x;   // float4 index
  int tok = (int)(i4 >> 6);
  int d4  = (int)(i4 & 63);
  float4 v = *(const float4*)&emb[(size_t)ids[tok] * H_DIM + d4 * 4];
  *(float4*)&X[i4 * 4] = v;
  ushort4 pk;
  pk.x = f2bu(v.x); pk.y = f2bu(v.y); pk.z = f2bu(v.z); pk.w = f2bu(v.w);
  *(ushort4*)&Xb[i4 * 4] = pk;
}

// Staging-source chunk swizzle: lane tid stages 8 elems; LDS pos (tid&3),
// global chunk (tid&3)^((tid>>3)&3). Read side: chunk = g4 ^ ((fr>>1)&3).
#define SRC_CHUNK(tid_) (((tid_) & 3) ^ (((tid_) >> 3) & 3))

// -------- bf16 MFMA GEMM, 2-phase dbuf: C = A[M,K] @ Bt[N,K]^T + bias ------
// Grid: x = m-tile (fastest -> same-XCD A-panel sharing), y = n-tile.
// MODE 1: bf16 out Cb (w/ optional relu);
// MODE 2: QKV split — n<256 -> Q prescaled; <512 -> K; >=512 -> Vt swizzled.
template<int MODE, bool RELU>
__global__ __launch_bounds__(256) void hgemm_kernel(
    const bf16* __restrict__ A, const bf16* __restrict__ Bt,
    const float* __restrict__ bias, float* __restrict__ Cf,
    bf16* __restrict__ Cb, bf16* __restrict__ Vt,
    int M, int N, int K) {
  __shared__ __align__(16) bf16 As[2][4096];   // [buf][128][32], chunk-swz
  __shared__ __align__(16) bf16 Bs[2][4096];
  const int tid = threadIdx.x;
  const int wv = tid >> 6, ln = tid & 63;
  const int fr = ln & 15, g4 = ln >> 4;
  const int wr = wv >> 1, wc = wv & 1;
  const int m0 = blockIdx.x * 128, n0 = blockIdx.y * 128;
  const int lr = tid >> 2;                     // staging row
  const int lk = SRC_CHUNK(tid) * 8;           // swizzled source k-offset
  const int rc = (g4 ^ ((fr >> 1) & 3)) * 8;   // swizzled read chunk (elems)

#define STAGE_G(buf, kk) do {                                                  \
    const int kof_ = (kk) * 32;                                                \
    gload_lds16(A  + (size_t)(m0 + lr) * K + kof_ + lk,                        \
                &As[(buf)][wv * 512]);                                         \
    gload_lds16(A  + (size_t)(m0 + 64 + lr) * K + kof_ + lk,                   \
                &As[(buf)][2048 + wv * 512]);                                  \
    gload_lds16(Bt + (size_t)(n0 + lr) * K + kof_ + lk,                        \
                &Bs[(buf)][wv * 512]);                                         \
    gload_lds16(Bt + (size_t)(n0 + 64 + lr) * K + kof_ + lk,                   \
                &Bs[(buf)][2048 + wv * 512]);                                  \
  } while (0)

  f32x4 acc[4][4];
#pragma unroll
  for (int i = 0; i < 4; ++i)
#pragma unroll
    for (int j = 0; j < 4; ++j)
      acc[i][j] = (f32x4){0.f, 0.f, 0.f, 0.f};

  const int NT = K >> 5;
  STAGE_G(0, 0);
  __syncthreads();
  int cur = 0;
  for (int kt = 0; kt < NT; ++kt) {
    if (kt + 1 < NT) STAGE_G(cur ^ 1, kt + 1);
    short8 af[4], bfv[4];
#pragma unroll
    for (int i = 0; i < 4; ++i)
      af[i] = *(const short8*)&As[cur][(wr * 64 + i * 16 + fr) * 32 + rc];
#pragma unroll
    for (int j = 0; j < 4; ++j)
      bfv[j] = *(const short8*)&Bs[cur][(wc * 64 + j * 16 + fr) * 32 + rc];
#pragma unroll
    for (int i = 0; i < 4; ++i)
#pragma unroll
      for (int j = 0; j < 4; ++j)
        acc[i][j] = __builtin_amdgcn_mfma_f32_16x16x32_bf16(
            af[i], bfv[j], acc[i][j], 0, 0, 0);
    __syncthreads();
    cur ^= 1;
  }
#undef STAGE_G

  const int crow = g4 * 4, ccol = fr;
#pragma unroll
  for (int j = 0; j < 4; ++j) {
    const int n = n0 + wc * 64 + j * 16 + ccol;
    const float bv = bias[n];
#pragma unroll
    for (int i = 0; i < 4; ++i) {
      const int mbase = m0 + wr * 64 + i * 16 + crow;
#pragma unroll
      for (int r = 0; r < 4; ++r) {
        float o = acc[i][j][r] + bv;
        if (RELU) o = fmaxf(o, 0.f);
        const int m = mbase + r;
        if (MODE == 1) {
          Cb[(size_t)m * N + n] = __float2bfloat16(o);
        } else {
          if (n < 512) {
            const float oo = (n < 256) ? o * QSCALE : o;  // prescale Q
            Cb[(size_t)m * 768 + n] = __float2bfloat16(oo);
          } else {
            const int hd = n - 512, hh = hd >> 5, dd = hd & 31;
            const int bb = m >> 9, ss = m & 511;
            const int ssw = (ss & ~63) | ((ss & 63) ^ ((dd & 7) << 3));
            Vt[(((size_t)bb * 8 + hh) * 32 + dd) * 512 + ssw] =
                __float2bfloat16(o);
          }
        }
      }
    }
  }
}

// -------- fused GEMM + bias + residual + LayerNorm + bf16, 2-phase dbuf ----
__global__ __launch_bounds__(256) void hgemm_ln_kernel(
    const bf16* __restrict__ A, const bf16* __restrict__ Bt,
    const float* __restrict__ bias, float* __restrict__ X,
    bf16* __restrict__ Xb, const float* __restrict__ g,
    const float* __restrict__ bt, int K) {
  __shared__ __align__(16) bf16 As[2][2048];   // [buf][64][32], chunk-swz
  __shared__ __align__(16) bf16 Bs[2][8192];   // [buf][256][32], chunk-swz
  __shared__ float rsum[4][64];
  __shared__ float rsq[4][64];
  const int tid = threadIdx.x;
  const int wv = tid >> 6;
  const int ln = tid & 63;
  const int fr = ln & 15, g4 = ln >> 4;
  const int m0 = blockIdx.x * 64;
  const int rc = (g4 ^ ((fr >> 1) & 3)) * 8;

#define STAGE_L(buf, kk) do {                                                  \
    const int kof_ = (kk) * 32;                                                \
    gload_lds16(A + (size_t)(m0 + (tid >> 2)) * K + kof_ +                     \
                    SRC_CHUNK(tid) * 8,                                        \
                &As[(buf)][wv * 512]);                                         \
    _Pragma("unroll")                                                          \
    for (int e = 0; e < 4; ++e) {                                              \
      const int vt = e * 256 + tid;                                            \
      gload_lds16(Bt + (size_t)(vt >> 2) * K + kof_ + SRC_CHUNK(vt) * 8,       \
                  &Bs[(buf)][e * 2048 + wv * 512]);                            \
    }                                                                          \
  } while (0)

  f32x4 acc[4][4];   // [row frag i][col frag j]
#pragma unroll
  for (int i = 0; i < 4; ++i)
#pragma unroll
    for (int j = 0; j < 4; ++j)
      acc[i][j] = (f32x4){0.f, 0.f, 0.f, 0.f};

  const int NT = K >> 5;
  STAGE_L(0, 0);
  __syncthreads();
  int cur = 0;
  for (int kt = 0; kt < NT; ++kt) {
    if (kt + 1 < NT) STAGE_L(cur ^ 1, kt + 1);
    short8 af[4], bfv[4];
#pragma unroll
    for (int i = 0; i < 4; ++i)
      af[i] = *(const short8*)&As[cur][(i * 16 + fr) * 32 + rc];
#pragma unroll
    for (int j = 0; j < 4; ++j)
      bfv[j] = *(const short8*)&Bs[cur][(wv * 64 + j * 16 + fr) * 32 + rc];
#pragma unroll
    for (int i = 0; i < 4; ++i)
#pragma unroll
      for (int j = 0; j < 4; ++j)
        acc[i][j] = __builtin_amdgcn_mfma_f32_16x16x32_bf16(
            af[i], bfv[j], acc[i][j], 0, 0, 0);
    __syncthreads();
    cur ^= 1;
  }
#undef STAGE_L

  float gj[4], bj[4], bsj[4];
#pragma unroll
  for (int j = 0; j < 4; ++j) {
    const int n = wv * 64 + j * 16 + fr;
    gj[j] = g[n]; bj[j] = bt[n]; bsj[j] = bias[n];
  }
#pragma unroll
  for (int i = 0; i < 4; ++i) {
#pragma unroll
    for (int r = 0; r < 4; ++r) {
      const int m = m0 + i * 16 + g4 * 4 + r;
#pragma unroll
      for (int j = 0; j < 4; ++j)
        acc[i][j][r] += bsj[j] + X[(size_t)m * 256 + wv * 64 + j * 16 + fr];
    }
  }
#pragma unroll
  for (int i = 0; i < 4; ++i) {
#pragma unroll
    for (int r = 0; r < 4; ++r) {
      float sp = acc[i][0][r] + acc[i][1][r] + acc[i][2][r] + acc[i][3][r];
      float qp = acc[i][0][r] * acc[i][0][r] + acc[i][1][r] * acc[i][1][r] +
                 acc[i][2][r] * acc[i][2][r] + acc[i][3][r] * acc[i][3][r];
#pragma unroll
      for (int off = 1; off < 16; off <<= 1) {
        sp += __shfl_xor(sp, off);
        qp += __shfl_xor(qp, off);
      }
      if (fr == 0) {
        const int ri = i * 16 + g4 * 4 + r;
        rsum[wv][ri] = sp;
        rsq[wv][ri] = qp;
      }
    }
  }
  __syncthreads();
#pragma unroll
  for (int i = 0; i < 4; ++i) {
#pragma unroll
    for (int r = 0; r < 4; ++r) {
      const int ri = i * 16 + g4 * 4 + r;
      const float tot = rsum[0][ri] + rsum[1][ri] + rsum[2][ri] + rsum[3][ri];
      const float tq = rsq[0][ri] + rsq[1][ri] + rsq[2][ri] + rsq[3][ri];
      const float mu = tot * (1.0f / 256.0f);
      const float var = tq * (1.0f / 256.0f) - mu * mu;
      const float rstd = rsqrtf(var + 1e-5f);
      const int m = m0 + ri;
#pragma unroll
      for (int j = 0; j < 4; ++j) {
        const float o = (acc[i][j][r] - mu) * rstd * gj[j] + bj[j];
        const size_t idx = (size_t)m * 256 + wv * 64 + j * 16 + fr;
        X[idx] = o;
        Xb[idx] = __float2bfloat16(o);
      }
    }
  }
}

// -------- bf16 MFMA flash attention --------
// Swapped QK^T (lane-local rows), prescaled Q (log2-domain), tile skip,
// K/V dbuf, defer-max, chunk-swizzled K/Q staging, sorted batches.
__global__ __launch_bounds__(256) void attn_mfma_kernel(
    const bf16* __restrict__ QKVb, const bf16* __restrict__ Vt,
    const int* __restrict__ amask, const int* __restrict__ ntiles,
    const int* __restrict__ ordb, bf16* __restrict__ Ob) {
  const int b = ordb[blockIdx.z];
  const int h = blockIdx.y, q0 = blockIdx.x * 64;
  const int tid = threadIdx.x;
  const int wv = tid >> 6, ln = tid & 63;
  const int fr = ln & 15, g4 = ln >> 4;
  const int f8 = (fr & 7) << 3;
  const int rc = (g4 ^ ((fr >> 1) & 3)) * 8;   // swizzled K/Q read chunk
  const int bh32 = (b * 8 + h) * 32;
  __shared__ __align__(16) bf16 Ks[2][2048];   // [buf][64][32], chunk-swz
  __shared__ __align__(16) bf16 Vs[2][2048];   // [buf][32 d][64 k] swizzled
  __shared__ __align__(16) bf16 Ps[4096];      // per-wave P; Q staging early
  __shared__ __align__(16) float Ms[64];

  const int nt = ntiles[b];

#define STAGE_A(buf, kt_) do {                                                 \
    const int k0_ = (kt_) * 64;                                                \
    gload_lds16(QKVb + (size_t)(b * S_LEN + k0_ + (tid >> 2)) * 768 + 256 +    \
                    h * 32 + SRC_CHUNK(tid) * 8,                               \
                &Ks[(buf)][wv * 512]);                                         \
    gload_lds16(Vt + (size_t)(bh32 + (tid >> 3)) * 512 + k0_ + (tid & 7) * 8,  \
                &Vs[(buf)][wv * 512]);                                         \
    if ((kt_) == nt - 1 && tid < 64)                                           \
      Ms[tid] = (amask[b * S_LEN + k0_ + tid] != 0) ? 0.f : -1e9f;             \
  } while (0)

  // stage Q through the Ps buffer (dead after the fragment read below)
  gload_lds16(QKVb + (size_t)(b * S_LEN + q0 + (tid >> 2)) * 768 + h * 32 +
                  SRC_CHUNK(tid) * 8,
              &Ps[wv * 512]);
  STAGE_A(0, 0);
  __syncthreads();
  const short8 qb = *(const short8*)&Ps[(wv * 16 + fr) * 32 + rc];
  __syncthreads();   // all Q-frag reads done before any P write

  f32x4 accO[2];
  accO[0] = (f32x4){0.f, 0.f, 0.f, 0.f};
  accO[1] = (f32x4){0.f, 0.f, 0.f, 0.f};
  float mrun = -1e30f, lrun = 0.f;   // per-lane state for q = fr (log2 domain)
  const int srcq = 20 * g4;   // shfl src base: lane 16*g4 + (4*g4 + rr)

  int cur = 0;
  for (int kt = 0; kt < nt; ++kt) {
    if (kt + 1 < nt) STAGE_A(cur ^ 1, kt + 1);
    const bool bnd = (kt == nt - 1);

    // S^T = K @ Q^T : 4 MFMAs cover 64 k x 16 q (already log2-scaled via Q)
    f32x4 st[4];
#pragma unroll
    for (int kb = 0; kb < 4; ++kb) {
      const short8 kf = *(const short8*)&Ks[cur][(kb * 16 + fr) * 32 + rc];
      f32x4 z = (f32x4){0.f, 0.f, 0.f, 0.f};
      st[kb] = __builtin_amdgcn_mfma_f32_16x16x32_bf16(kf, qb, z, 0, 0, 0);
    }

    float p[16];
    if (bnd) {
#pragma unroll
      for (int kb = 0; kb < 4; ++kb) {
        const f32x4 mv = ((const f32x4*)Ms)[kb * 4 + g4];
#pragma unroll
        for (int rr = 0; rr < 4; ++rr) p[kb * 4 + rr] = st[kb][rr] + mv[rr];
      }
    } else {
#pragma unroll
      for (int kb = 0; kb < 4; ++kb)
#pragma unroll
        for (int rr = 0; rr < 4; ++rr) p[kb * 4 + rr] = st[kb][rr];
    }

    // max: v_max3 tree (depth 3) + 2 cross-lane
    const float a0 = fmaxf(fmaxf(p[0], p[1]), p[2]);
    const float a1 = fmaxf(fmaxf(p[3], p[4]), p[5]);
    const float a2 = fmaxf(fmaxf(p[6], p[7]), p[8]);
    const float a3 = fmaxf(fmaxf(p[9], p[10]), p[11]);
    const float a4 = fmaxf(fmaxf(p[12], p[13]), p[14]);
    float mx = fmaxf(fmaxf(fmaxf(a0, a1), fmaxf(a2, a3)), fmaxf(a4, p[15]));
    mx = fmaxf(mx, __shfl_xor(mx, 16));
    mx = fmaxf(mx, __shfl_xor(mx, 32));

    // defer-max (T13): rescale only when the row max grew by > 8 (log2)
    float corr = 1.f;
    if (!__all(mx <= mrun + 8.f)) {
      const float mnew = fmaxf(mrun, mx);
      corr = exp2f(mrun - mnew);
      mrun = mnew;
#pragma unroll
      for (int rr = 0; rr < 4; ++rr) {
        const float cs = __shfl(corr, srcq + rr);
        accO[0][rr] *= cs;
        accO[1][rr] *= cs;
      }
    }

#pragma unroll
    for (int i = 0; i < 16; ++i) p[i] = exp2f(p[i] - mrun);
    // pairwise-tree sum (depth 4) + 2 cross-lane
    const float b0 = p[0] + p[1], b1 = p[2] + p[3], b2 = p[4] + p[5],
                b3 = p[6] + p[7], b4 = p[8] + p[9], b5 = p[10] + p[11],
                b6 = p[12] + p[13], b7 = p[14] + p[15];
    float ps = ((b0 + b1) + (b2 + b3)) + ((b4 + b5) + (b6 + b7));
    ps += __shfl_xor(ps, 16);
    ps += __shfl_xor(ps, 32);
    lrun = lrun * corr + ps;

    // write P rows: lane writes 4 shorts per kb at k = kb*16 + g4*4, XOR-swz
#pragma unroll
    for (int kb = 0; kb < 4; ++kb) {
      ushort4 w4;
      w4.x = f2bu(p[kb * 4 + 0]);
      w4.y = f2bu(p[kb * 4 + 1]);
      w4.z = f2bu(p[kb * 4 + 2]);
      w4.w = f2bu(p[kb * 4 + 3]);
      *(ushort4*)&Ps[wv * 1024 + fr * 64 + ((kb * 16 + g4 * 4) ^ f8)] = w4;
    }

    // PV: O[q][d] += P[16q x 32k] @ V[32k x 16d], per-wave (no barrier)
#pragma unroll
    for (int kk = 0; kk < 2; ++kk) {
      const short8 pa = *(const short8*)
          &Ps[wv * 1024 + fr * 64 + ((kk * 32 + g4 * 8) ^ f8)];
#pragma unroll
      for (int df = 0; df < 2; ++df) {
        const short8 vb = *(const short8*)
            &Vs[cur][(df * 16 + fr) * 64 + ((kk * 32 + g4 * 8) ^ f8)];
        accO[df] = __builtin_amdgcn_mfma_f32_16x16x32_bf16(
            pa, vb, accO[df], 0, 0, 0);
      }
    }
    __syncthreads();
    cur ^= 1;
  }
#undef STAGE_A

  const float inv = 1.0f / lrun;   // q = fr layout
#pragma unroll
  for (int rr = 0; rr < 4; ++rr) {
    const float iv = __shfl(inv, srcq + rr);
    const int q = q0 + wv * 16 + g4 * 4 + rr;
    const size_t orow = ((size_t)b * S_LEN + q) * H_DIM + h * 32;
    Ob[orow + fr]      = __float2bfloat16(accO[0][rr] * iv);
    Ob[orow + 16 + fr] = __float2bfloat16(accO[1][rr] * iv);
  }
}

// -------- fused final-LN + story-pool stage1: grid (64 b, 8 sgroups) -------
__global__ __launch_bounds__(256) void lnf_pool_kernel(
    float* __restrict__ X, const float* __restrict__ g,
    const float* __restrict__ bt, const int* __restrict__ amask,
    float* __restrict__ Pstory) {
  const int b = blockIdx.x, sg = blockIdx.y;
  const int tid = threadIdx.x, wv = tid >> 6, ln = tid & 63;
  const float4 gg = ((const float4*)g)[ln];
  const float4 bb = ((const float4*)bt)[ln];
  float ax = 0.f, ay = 0.f, az = 0.f, aw = 0.f;
  for (int t = wv; t < 64; t += 4) {
    const size_t tok = (size_t)b * S_LEN + sg * 64 + t;
    float4 v = ((const float4*)X)[tok * 64 + ln];
    float s = v.x + v.y + v.z + v.w;
#pragma unroll
    for (int off = 1; off < 64; off <<= 1) s += __shfl_xor(s, off);
    const float mu = s * (1.0f / 256.0f);
    const float dx = v.x - mu, dy = v.y - mu, dz = v.z - mu, dw = v.w - mu;
    float sq = dx * dx + dy * dy + dz * dz + dw * dw;
#pragma unroll
    for (int off = 1; off < 64; off <<= 1) sq += __shfl_xor(sq, off);
    const float rstd = rsqrtf(sq * (1.0f / 256.0f) + 1e-5f);
    float4 o;
    o.x = dx * rstd * gg.x + bb.x;
    o.y = dy * rstd * gg.y + bb.y;
    o.z = dz * rstd * gg.z + bb.z;
    o.w = dw * rstd * gg.w + bb.w;
    ((float4*)X)[tok * 64 + ln] = o;
    if (amask[tok]) { ax += o.x; ay += o.y; az += o.z; aw += o.w; }
  }
  __shared__ float part[4][256];
  part[wv][ln * 4 + 0] = ax;
  part[wv][ln * 4 + 1] = ay;
  part[wv][ln * 4 + 2] = az;
  part[wv][ln * 4 + 3] = aw;
  __syncthreads();
  const float tot = part[0][tid] + part[1][tid] + part[2][tid] + part[3][tid];
  Pstory[((size_t)b * 8 + sg) * 256 + tid] = tot;
}

// -------- pool combine + classifier (merged) --------
__global__ __launch_bounds__(256) void poolcls_kernel(
    const float* __restrict__ X, const float* __restrict__ Pstory,
    const int* __restrict__ lenb,
    const int* __restrict__ sub_idx, const int* __restrict__ sub_cnt,
    const int* __restrict__ obj_idx, const int* __restrict__ obj_cnt,
    const float* __restrict__ mW1, const float* __restrict__ mb1,
    const float* __restrict__ mW2, const float* __restrict__ mb2,
    float* __restrict__ out) {
  const int b = blockIdx.x, t = threadIdx.x;
  __shared__ float fs[768];
  __shared__ float hid[256];
  const float* xb = X + (size_t)b * S_LEN * H_DIM;
  {
    float s = 0.f;
#pragma unroll
    for (int i = 0; i < 8; ++i) s += Pstory[((size_t)b * 8 + i) * 256 + t];
    fs[512 + t] = s / (float)lenb[b];   // len >= 16
  }
  {
    const int cc = sub_cnt[b];
    float s2 = 0.f;
    for (int j = 0; j < cc; ++j)
      s2 += xb[(size_t)sub_idx[b * 8 + j] * H_DIM + t];
    fs[t] = (cc > 0) ? s2 / (float)cc : 0.f;
  }
  {
    const int cc = obj_cnt[b];
    float s2 = 0.f;
    for (int j = 0; j < cc; ++j)
      s2 += xb[(size_t)obj_idx[b * 8 + j] * H_DIM + t];
    fs[256 + t] = (cc > 0) ? s2 / (float)cc : 0.f;
  }
  __syncthreads();
  float acc = mb1[t];
  for (int k = 0; k < 768; ++k) acc += fs[k] * mW1[(size_t)k * 256 + t];
  hid[t] = fmaxf(acc, 0.f);
  __syncthreads();
  if (t < 25) {
    float o = mb2[t];
    for (int j = 0; j < 256; ++j) o += hid[j] * mW2[j * 25 + t];
    out[b * 25 + t] = o;
  }
}

// ---------------------------------------------------------------------------
extern "C" void kernel_launch(void* const* d_in, const int* in_sizes, int n_in,
                              void* d_out, int out_size, void* d_ws, size_t ws_size,
                              hipStream_t stream) {
  const int*   input_ids = (const int*)d_in[0];
  const int*   amask     = (const int*)d_in[1];
  const int*   sub_idx   = (const int*)d_in[2];
  const int*   sub_cnt   = (const int*)d_in[3];
  const int*   obj_idx   = (const int*)d_in[4];
  const int*   obj_cnt   = (const int*)d_in[5];
  const float* emb  = (const float*)d_in[6];
  const float* Wqkv = (const float*)d_in[7];
  const float* bqkv = (const float*)d_in[8];
  const float* Wo   = (const float*)d_in[9];
  const float* bo   = (const float*)d_in[10];
  const float* ln1g = (const float*)d_in[11];
  const float* ln1b = (const float*)d_in[12];
  const float* ln2g = (const float*)d_in[13];
  const float* ln2b = (const float*)d_in[14];
  const float* W1   = (const float*)d_in[15];
  const float* b1   = (const float*)d_in[16];
  const float* W2   = (const float*)d_in[17];
  const float* b2   = (const float*)d_in[18];
  const float* lnfg = (const float*)d_in[19];
  const float* lnfb = (const float*)d_in[20];
  const float* mW1  = (const float*)d_in[21];
  const float* mb1  = (const float*)d_in[22];
  const float* mW2  = (const float*)d_in[23];
  const float* mb2  = (const float*)d_in[24];
  float* out = (float*)d_out;

  // workspace layout (bytes)
  char* w = (char*)d_ws;
  float* X    = (float*)w;                         w += (size_t)NTOK * 256 * 4;  // 33.5MB
  bf16*  Xb   = (bf16*)w;                          w += (size_t)NTOK * 256 * 2;  // 16.8MB
  bf16*  QKVb = (bf16*)w;                          w += (size_t)NTOK * 768 * 2;  // 50.3MB
  bf16*  Vtg  = (bf16*)w;                          w += (size_t)NTOK * 256 * 2;  // 16.8MB
  bf16*  Ob   = (bf16*)w;                          w += (size_t)NTOK * 256 * 2;  // 16.8MB
  bf16*  Wqkvt= (bf16*)w;                          w += (size_t)4 * 768 * 256 * 2;
  bf16*  Wot  = (bf16*)w;                          w += (size_t)4 * 256 * 256 * 2;
  bf16*  W1t  = (bf16*)w;                          w += (size_t)4 * 1024 * 256 * 2;
  bf16*  W2t  = (bf16*)w;                          w += (size_t)4 * 256 * 1024 * 2;
  float* Pstory = (float*)w;                       w += (size_t)64 * 8 * 256 * 4;
  int*   ntiles = (int*)w;                         w += 256;
  int*   lenb   = (int*)w;                         w += 256;
  int*   ordb   = (int*)w;                         w += 256;
  bf16*  Hb   = QKVb;   // aliases [QKVb, Vtg] = 67.1MB >= 32768*1024*2

  lens_kernel<<<64, 64, 0, stream>>>(amask, ntiles, lenb);
  order_kernel<<<1, 64, 0, stream>>>(ntiles, ordb);
  tcast_kernel<<<dim3(24, 8, 4), 256, 0, stream>>>(Wqkv, Wqkvt, 256, 768);
  tcast_kernel<<<dim3(8, 8, 4), 256, 0, stream>>>(Wo, Wot, 256, 256);
  tcast_kernel<<<dim3(32, 8, 4), 256, 0, stream>>>(W1, W1t, 256, 1024);
  tcast_kernel<<<dim3(8, 32, 4), 256, 0, stream>>>(W2, W2t, 1024, 256);

  embed_kernel<<<8192, 256, 0, stream>>>(input_ids, emb, X, Xb);

  for (int l = 0; l < 4; ++l) {
    const bf16* Wqkvt_l = Wqkvt + (size_t)l * 768 * 256;
    const bf16* Wot_l   = Wot + (size_t)l * 256 * 256;
    const bf16* W1t_l   = W1t + (size_t)l * 1024 * 256;
    const bf16* W2t_l   = W2t + (size_t)l * 256 * 1024;

    hgemm_kernel<2, false><<<dim3(256, 6), 256, 0, stream>>>(
        Xb, Wqkvt_l, bqkv + (size_t)l * 768, nullptr, QKVb, Vtg, NTOK, 768, 256);
    attn_mfma_kernel<<<dim3(8, 8, 64), 256, 0, stream>>>(
        QKVb, Vtg, amask, ntiles, ordb, Ob);
    hgemm_ln_kernel<<<512, 256, 0, stream>>>(
        Ob, Wot_l, bo + (size_t)l * 256, X, Xb,
        ln1g + l * 256, ln1b + l * 256, 256);
    hgemm_kernel<1, true><<<dim3(256, 8), 256, 0, stream>>>(
        Xb, W1t_l, b1 + (size_t)l * 1024, nullptr, Hb, nullptr, NTOK, 1024, 256);
    hgemm_ln_kernel<<<512, 256, 0, stream>>>(
        Hb, W2t_l, b2 + (size_t)l * 256, X, Xb,
        ln2g + l * 256, ln2b + l * 256, 1024);
  }
  lnf_pool_kernel<<<dim3(64, 8), 256, 0, stream>>>(X, lnfg, lnfb, amask, Pstory);
  poolcls_kernel<<<64, 256, 0, stream>>>(X, Pstory, lenb, sub_idx, sub_cnt,
                                         obj_idx, obj_cnt, mW1, mb1, mW2, mb2,
                                         out);
}